// Round 2
// 1046.154 us; speedup vs baseline: 1.4553x; 1.4553x over previous
//
#include <hip/hip_runtime.h>
#include <hip/hip_bf16.h>

// TTAGN: LSTM(edge,node) -> GAT x2 + GCN x2 -> classifier.
// Inputs fp32, internal fp32, OUTPUT fp32.
// d_out = concat(out[N,4], x_gcn[N,64], x_gat[N,64]) as fp32.
// Scratch in __device__ globals.
//
// R12: MFMA LSTM, take 2. R11 (f16 builtin + _Float16 vecs + cvt_pkrtz)
// hit an untraceable device-side compile error; this version uses ONLY the
// env-verified MFMA combination: short8 ext-vectors +
// __builtin_amdgcn_mfma_f32_32x32x16_bf16 (C/D layout per m74/m101:
// col=lane&31, row=(reg&3)+8*(reg>>2)+4*(lane>>5)).
// Precision: split-bf16 (hi + lo residual) with compensation chains:
//   G^T = Whh_hi@h_hi + Whh_lo@h_hi + Whh_hi@h_lo          (6 mfma)
//       + [Wih_hi,b_hi,Wih_hi,Wih_lo,b_lo]@[x_hi,1,x_lo,x_hi,1]  (2 mfma)
// => residual ~2^-18, numerically == fp32 scalar path.
// Each lane holds all 4 gates of 8 units of ONE seq; activations lane-local;
// h exchange = 8 unconditional shfl_xor(32)/step. Node+edge in one launch.

typedef unsigned int u32;

#define NN 50000
#define EE 400000

__device__ float g_nodeF[NN * 16];
__device__ float g_esc[EE];
__device__ float g_P1[NN * 64];
__device__ float g_P2[NN * 64];
__device__ float g_alpha[NN * 8];
__device__ float g_amax[NN * 8];
__device__ float g_rinv[NN * 8];
__device__ float g_dinv[NN];
__device__ int   g_cnt[NN];
__device__ int   g_rs[NN + 1];
__device__ int   g_cur[NN];
__device__ int   g_csrc[EE];
__device__ float g_cesc[EE];

__device__ __forceinline__ float rcpf(float x) { return __builtin_amdgcn_rcpf(x); }
__device__ __forceinline__ float sigf(float x) { return rcpf(1.0f + __expf(-x)); }
__device__ __forceinline__ float tanh_fast(float x) {
    return 1.0f - 2.0f * rcpf(__expf(2.0f * x) + 1.0f);
}

// ---------------- fused LSTM (bf16 MFMA, split-precision) ----------------
typedef short short8 __attribute__((ext_vector_type(8)));
typedef float f32x16 __attribute__((ext_vector_type(16)));

union S8U { short8 v; unsigned u[4]; };

// pack two floats as bf16 pair (truncation; lo-chains compensate the error)
__device__ __forceinline__ unsigned pk_hi(float a, float b) {
    return (__float_as_uint(a) >> 16) | (__float_as_uint(b) & 0xFFFF0000u);
}
__device__ __forceinline__ float bftrunc(float a) {
    return __uint_as_float(__float_as_uint(a) & 0xFFFF0000u);
}
__device__ __forceinline__ float lo_res(float a) { return a - bftrunc(a); }
__device__ __forceinline__ unsigned sx32(unsigned v) {
    return (unsigned)__shfl_xor((int)v, 32, 64);
}

// One wave = 32 sequences (lanes l and l+32 share seq col=l&31).
// Lane (col,hi) owns units U[j] = (j&3) + 8*(j>>2) + 4*hi, j=0..7, of its seq.
// Block = 256 threads = 4 independent waves = 128 seqs.
__global__ void __launch_bounds__(256, 3) lstm_fused_kernel(
    const float* __restrict__ nseq, const int* __restrict__ nlen,
    const float* __restrict__ eseq, const int* __restrict__ elen,
    const float* __restrict__ Wih, const float* __restrict__ Whh,
    const float* __restrict__ bias,
    const float* __restrict__ dnnW, const float* __restrict__ dnnb,
    float* __restrict__ nodeF, float* __restrict__ esc, int nNodeBlk)
{
    const int lane = threadIdx.x & 63;
    const int col  = lane & 31;
    const int hi   = lane >> 5;
    const bool isLo = (hi == 0);
    const int wave = threadIdx.x >> 6;

    const bool edgeMode = (int)blockIdx.x >= nNodeBlk;
    const float* seq = edgeMode ? eseq : nseq;
    const int*  lens = edgeMode ? elen : nlen;
    const int limit  = edgeMode ? EE : NN;
    const int bbase  = edgeMode ? ((int)blockIdx.x - nNodeBlk) : (int)blockIdx.x;
    const int s  = bbase * 128 + wave * 32 + col;
    const int sc = s < limit ? s : limit - 1;

    // ---- A fragments. Layout: lane(row=col [+32 tile1], k=8*hi+j, j=0..7).
    const int row0 = col, row1 = col + 32;
    const int ko = hi * 8;
    S8U ahh0, ahh1, ahl0, ahl1, ax0, ax1;
    {
        const float* w0 = Whh + row0 * 16 + ko;
        const float* w1 = Whh + row1 * 16 + ko;
#pragma unroll
        for (int r = 0; r < 4; ++r) {
            float a0 = w0[2 * r], b0 = w0[2 * r + 1];
            float a1 = w1[2 * r], b1 = w1[2 * r + 1];
            ahh0.u[r] = pk_hi(a0, b0);
            ahh1.u[r] = pk_hi(a1, b1);
            ahl0.u[r] = pk_hi(lo_res(a0), lo_res(b0));
            ahl1.u[r] = pk_hi(lo_res(a1), lo_res(b1));
        }
        // x-chain A (k slots, lo lanes only; hi lanes all-zero):
        // k0,k1=Wih_hi ; k2=bias_hi ; k3,k4=Wih_hi (for x_lo) ;
        // k5,k6=Wih_lo ; k7=bias_lo
#pragma unroll
        for (int r = 0; r < 4; ++r) { ax0.u[r] = 0u; ax1.u[r] = 0u; }
        if (isLo) {
            float wa0 = Wih[row0 * 2], wb0 = Wih[row0 * 2 + 1], bb0 = bias[row0];
            float wa1 = Wih[row1 * 2], wb1 = Wih[row1 * 2 + 1], bb1 = bias[row1];
            ax0.u[0] = pk_hi(wa0, wb0);
            ax0.u[1] = pk_hi(bb0, wa0);
            ax0.u[2] = pk_hi(wb0, lo_res(wa0));
            ax0.u[3] = pk_hi(lo_res(wb0), lo_res(bb0));
            ax1.u[0] = pk_hi(wa1, wb1);
            ax1.u[1] = pk_hi(bb1, wa1);
            ax1.u[2] = pk_hi(wb1, lo_res(wa1));
            ax1.u[3] = pk_hi(lo_res(wb1), lo_res(bb1));
        }
    }

    const f32x16 zc = {0.f, 0.f, 0.f, 0.f, 0.f, 0.f, 0.f, 0.f,
                       0.f, 0.f, 0.f, 0.f, 0.f, 0.f, 0.f, 0.f};
    const unsigned bxmask = isLo ? 0xFFFFFFFFu : 0u;
    const unsigned one_bf = 0x3F80u;  // bf16(1.0) in low half

    float cst[8], hlast[8];
#pragma unroll
    for (int j = 0; j < 8; ++j) { cst[j] = 0.f; hlast[j] = 0.f; }
    unsigned ph[4], pl[4];  // packed h (hi/lo), own units
#pragma unroll
    for (int r = 0; r < 4; ++r) { ph[r] = 0u; pl[r] = 0u; }

    const float4* sp = (const float4*)seq + (size_t)sc * 8;  // 32 floats/seq
    const int lenm1 = lens[sc] - 1;                          // in [0,15]

    float4 q = sp[0];
#pragma unroll 1
    for (int i = 0; i < 8; ++i) {
        float4 qn = sp[(i + 1) & 7];  // prefetch (wraps last iter; in-bounds)
#pragma unroll
        for (int hf = 0; hf < 2; ++hf) {
            const int t = 2 * i + hf;
            const float x0 = hf ? q.z : q.x;
            const float x1 = hf ? q.w : q.y;

            // B h-fragments: B[k=8*hi+j][col]; exchange halves via shfl.
            S8U bhh, bhl, bx;
            {
                unsigned t0 = sx32(ph[0]), t1 = sx32(ph[1]);
                unsigned t2 = sx32(ph[2]), t3 = sx32(ph[3]);
                bhh.u[0] = isLo ? ph[0] : t2;
                bhh.u[1] = isLo ? ph[1] : t3;
                bhh.u[2] = isLo ? t0 : ph[2];
                bhh.u[3] = isLo ? t1 : ph[3];
                unsigned s0 = sx32(pl[0]), s1 = sx32(pl[1]);
                unsigned s2 = sx32(pl[2]), s3 = sx32(pl[3]);
                bhl.u[0] = isLo ? pl[0] : s2;
                bhl.u[1] = isLo ? pl[1] : s3;
                bhl.u[2] = isLo ? s0 : pl[2];
                bhl.u[3] = isLo ? s1 : pl[3];
            }
            // B x-fragment: k0,k1=x_hi ; k2=1 ; k3,k4=x_lo ; k5,k6=x_hi ; k7=1
            {
                float xl0 = lo_res(x0), xl1 = lo_res(x1);
                bx.u[0] = pk_hi(x0, x1) & bxmask;
                bx.u[1] = (one_bf | (__float_as_uint(xl0) & 0xFFFF0000u)) & bxmask;
                bx.u[2] = pk_hi(xl1, x0) & bxmask;
                bx.u[3] = ((__float_as_uint(x1) >> 16) | (one_bf << 16)) & bxmask;
            }

            f32x16 d0 = __builtin_amdgcn_mfma_f32_32x32x16_bf16(ax0.v, bx.v, zc, 0, 0, 0);
            f32x16 d1 = __builtin_amdgcn_mfma_f32_32x32x16_bf16(ax1.v, bx.v, zc, 0, 0, 0);
            d0 = __builtin_amdgcn_mfma_f32_32x32x16_bf16(ahh0.v, bhh.v, d0, 0, 0, 0);
            d1 = __builtin_amdgcn_mfma_f32_32x32x16_bf16(ahh1.v, bhh.v, d1, 0, 0, 0);
            d0 = __builtin_amdgcn_mfma_f32_32x32x16_bf16(ahl0.v, bhh.v, d0, 0, 0, 0);
            d1 = __builtin_amdgcn_mfma_f32_32x32x16_bf16(ahl1.v, bhh.v, d1, 0, 0, 0);
            d0 = __builtin_amdgcn_mfma_f32_32x32x16_bf16(ahh0.v, bhl.v, d0, 0, 0, 0);
            d1 = __builtin_amdgcn_mfma_f32_32x32x16_bf16(ahh1.v, bhl.v, d1, 0, 0, 0);

            // d0[j]=i_U[j], d0[8+j]=f_U[j], d1[j]=g_U[j], d1[8+j]=o_U[j]
            float hh[8];
#pragma unroll
            for (int j = 0; j < 8; ++j) {
                float ip = d0[j], fp = d0[8 + j], gp = d1[j], op = d1[8 + j];
                float cu = sigf(fp) * cst[j] + sigf(ip) * tanh_fast(gp);
                cst[j] = cu;
                hh[j] = sigf(op) * tanh_fast(cu);
            }
            const bool selm = (t == lenm1);
#pragma unroll
            for (int j = 0; j < 8; ++j) hlast[j] = selm ? hh[j] : hlast[j];
            // repack h (hi + lo residual)
#pragma unroll
            for (int r = 0; r < 4; ++r) {
                float a = hh[2 * r], b = hh[2 * r + 1];
                ph[r] = pk_hi(a, b);
                pl[r] = pk_hi(lo_res(a), lo_res(b));
            }
        }
        q = qn;
    }

    if (edgeMode) {
        // esc[s] = dot(h16, dnnW) + dnnb ; lane holds units {0..3,8..11}+4*hi
        float4 dA = *(const float4*)(dnnW + hi * 4);
        float4 dB = *(const float4*)(dnnW + hi * 4 + 8);
        float part = hlast[0] * dA.x + hlast[1] * dA.y + hlast[2] * dA.z + hlast[3] * dA.w
                   + hlast[4] * dB.x + hlast[5] * dB.y + hlast[6] * dB.z + hlast[7] * dB.w;
        float tot = part + __shfl_xor(part, 32, 64);
        if (isLo && s < limit) esc[s] = tot + dnnb[0];
    } else {
        if (s < limit) {
            float* dst = nodeF + (size_t)s * 16 + hi * 4;
            *(float4*)(dst)     = make_float4(hlast[0], hlast[1], hlast[2], hlast[3]);
            *(float4*)(dst + 8) = make_float4(hlast[4], hlast[5], hlast[6], hlast[7]);
        }
    }
}

// ---------------- CSR build ----------------
__global__ void __launch_bounds__(256) zero_cnt_kernel(int* cnt, int n)
{
    int t = blockIdx.x * 256 + threadIdx.x;
    if (t < n) cnt[t] = 0;
}
__global__ void __launch_bounds__(256) count_kernel(const int* __restrict__ dst,
                                                    int* cnt, int E)
{
    int e = blockIdx.x * 256 + threadIdx.x;
    if (e < E) atomicAdd(&cnt[dst[e]], 1);
}
// single-block exclusive scan; also rowstart[n]=E and cursor copy.
__global__ void __launch_bounds__(256) scan_kernel(const int* __restrict__ cnt,
                                                   int* __restrict__ rs,
                                                   int* __restrict__ cur,
                                                   int n, int E)
{
    __shared__ int part[256];
    int t = threadIdx.x;
    const int CH = (n + 255) / 256;
    int base = t * CH;
    int s = 0;
    for (int i = 0; i < CH; ++i) {
        int idx = base + i;
        if (idx < n) s += cnt[idx];
    }
    part[t] = s;
    __syncthreads();
    if (t == 0) {
        int acc = 0;
        for (int i = 0; i < 256; ++i) { int v = part[i]; part[i] = acc; acc += v; }
    }
    __syncthreads();
    int run = part[t];
    for (int i = 0; i < CH; ++i) {
        int idx = base + i;
        if (idx < n) { rs[idx] = run; cur[idx] = run; run += cnt[idx]; }
    }
    if (t == 0) rs[n] = E;
}
__global__ void __launch_bounds__(256) fill_kernel(const int* __restrict__ src,
                                                   const int* __restrict__ dst,
                                                   const float* __restrict__ esc,
                                                   int* __restrict__ cur,
                                                   int* __restrict__ csrc,
                                                   float* __restrict__ cesc, int E)
{
    int e = blockIdx.x * 256 + threadIdx.x;
    if (e >= E) return;
    int pos = atomicAdd(&cur[dst[e]], 1);
    csrc[pos] = src[e];
    cesc[pos] = esc[e];
}
__global__ void __launch_bounds__(256) dinv_kernel(const int* __restrict__ cnt,
                                                   float* __restrict__ dinv, int n)
{
    int t = blockIdx.x * 256 + threadIdx.x;
    if (t < n) dinv[t] = rsqrtf((float)cnt[t] + 1.0f);
}

// --- C[n,64] = [x(240)|nodeF(16)] @ W[256,64]; 32KB static LDS, 2-phase K ---
__global__ void __launch_bounds__(256) gemmX_kernel(
    const float* __restrict__ x, const float* __restrict__ nodeF,
    const float* __restrict__ W, float* __restrict__ C, int n)
{
    __shared__ float sW[128 * 64];  // 32 KB
    int j = threadIdx.x & 63;
    int node = blockIdx.x * 4 + (threadIdx.x >> 6);
    bool valid = node < n;
    const float4* xr = (const float4*)(x + (size_t)node * 240);
    float acc = 0.f;

    for (int i = threadIdx.x; i < 128 * 64; i += 256) sW[i] = W[i];
    __syncthreads();
    if (valid) {
#pragma unroll 4
        for (int k4 = 0; k4 < 32; ++k4) {
            float4 v = xr[k4];
            const float* wr = sW + k4 * 256 + j;
            acc += v.x * wr[0] + v.y * wr[64] + v.z * wr[128] + v.w * wr[192];
        }
    }
    __syncthreads();
    for (int i = threadIdx.x; i < 128 * 64; i += 256) sW[i] = W[128 * 64 + i];
    __syncthreads();
    if (valid) {
#pragma unroll 4
        for (int k4 = 32; k4 < 60; ++k4) {
            float4 v = xr[k4];
            const float* wr = sW + (k4 - 32) * 256 + j;
            acc += v.x * wr[0] + v.y * wr[64] + v.z * wr[128] + v.w * wr[192];
        }
        const float4* nf = (const float4*)(nodeF + (size_t)node * 16);
#pragma unroll
        for (int k4 = 60; k4 < 64; ++k4) {
            float4 v = nf[k4 - 60];
            const float* wr = sW + (k4 - 32) * 256 + j;
            acc += v.x * wr[0] + v.y * wr[64] + v.z * wr[128] + v.w * wr[192];
        }
        C[(size_t)node * 64 + j] = acc;
    }
}

// ------- C[n,64] = A[n,64] @ W[64,64]; 16KB static LDS -------
__global__ void __launch_bounds__(256) gemm64_kernel(const float* __restrict__ A,
                                                     const float* __restrict__ W,
                                                     float* __restrict__ C, int n)
{
    __shared__ float sW[64 * 64];  // 16 KB
    for (int i = threadIdx.x; i < 64 * 64; i += 256) sW[i] = W[i];
    __syncthreads();
    int j = threadIdx.x & 63;
    int node = blockIdx.x * 4 + (threadIdx.x >> 6);
    if (node >= n) return;
    const float4* a4 = (const float4*)(A + (size_t)node * 64);
    float acc = 0.f;
#pragma unroll 4
    for (int k4 = 0; k4 < 16; ++k4) {
        float4 v = a4[k4];
        const float* wr = sW + k4 * 256 + j;
        acc += v.x * wr[0] + v.y * wr[64] + v.z * wr[128] + v.w * wr[192];
    }
    C[(size_t)node * 64 + j] = acc;
}

// ---------------- GAT ----------------
template <int H, int C>
__global__ void __launch_bounds__(256) alpha_kernel(const float* __restrict__ xh,
                                                    const float* __restrict__ att,
                                                    float* __restrict__ alpha, int n)
{
    int t = blockIdx.x * 256 + threadIdx.x;
    if (t >= n * H) return;
    int h = (H == 1) ? 0 : (t % H);
    int nd = (H == 1) ? t : (t / H);
    const float* row = xh + (size_t)nd * 64 + h * C;
    float s = 0.f;
#pragma unroll
    for (int c = 0; c < C; ++c) s += row[c] * att[h * C + c];
    alpha[t] = s;
}

// per (dst,h): max then sum over in-edges (CSR). Writes amax, rinv=1/sum.
template <int H>
__global__ void __launch_bounds__(256) gat_softmax_csr_kernel(
    const int* __restrict__ rs, const int* __restrict__ csrc,
    const float* __restrict__ alpha,
    float* __restrict__ amax, float* __restrict__ rinv, int n)
{
    int t = blockIdx.x * 256 + threadIdx.x;
    if (t >= n * H) return;
    int h = (H == 1) ? 0 : (t % H);
    int d = (H == 1) ? t : (t / H);
    int k0 = rs[d], k1 = rs[d + 1];
    float m = -INFINITY;
    for (int k = k0; k < k1; ++k) {
        float a = alpha[(size_t)csrc[k] * H + h];
        a = a > 0.f ? a : 0.2f * a;
        m = fmaxf(m, a);
    }
    float s = 0.f;
    for (int k = k0; k < k1; ++k) {
        float a = alpha[(size_t)csrc[k] * H + h];
        a = a > 0.f ? a : 0.2f * a;
        s += __expf(a - m);
    }
    amax[t] = m;
    rinv[t] = rcpf(s);
}

// one wave per dst node (lane = feature col). acc = xh[d]+bias + sum coef*xh[s].
template <int H, bool FILTER>
__global__ void __launch_bounds__(256) gat_gather_kernel(
    const int* __restrict__ rs, const int* __restrict__ csrc,
    const float* __restrict__ cesc,
    const float* __restrict__ xh, const float* __restrict__ alpha,
    const float* __restrict__ amax, const float* __restrict__ rinv,
    const float* __restrict__ bias, float* __restrict__ out, int n)
{
    int j = threadIdx.x & 63;
    int d = blockIdx.x * 4 + (threadIdx.x >> 6);
    if (d >= n) return;
    int h = (H == 8) ? (j >> 3) : 0;
    float m = amax[(size_t)d * H + h];
    float ri = rinv[(size_t)d * H + h];
    float acc = xh[(size_t)d * 64 + j] + bias[j];
    int k1 = rs[d + 1];
#pragma unroll 2
    for (int k = rs[d]; k < k1; ++k) {
        int s = csrc[k];
        float a = alpha[(size_t)s * H + h];
        a = a > 0.f ? a : 0.2f * a;
        float coef = __expf(a - m) * ri + cesc[k];
        acc += xh[(size_t)s * 64 + j] * coef;
    }
    if (FILTER && !__builtin_isfinite(acc)) acc = 0.f;
    out[(size_t)d * 64 + j] = acc;
}

// ---------------- GCN gather (norm + bias + leaky_relu fused) ----------------
__global__ void __launch_bounds__(256) gcn_gather_kernel(
    const int* __restrict__ rs, const int* __restrict__ csrc,
    const float* __restrict__ xw, const float* __restrict__ dinv,
    const float* __restrict__ bias, float* __restrict__ out, int n)
{
    int j = threadIdx.x & 63;
    int d = blockIdx.x * 4 + (threadIdx.x >> 6);
    if (d >= n) return;
    float di = dinv[d];
    float acc = xw[(size_t)d * 64 + j] * di * di + bias[j];
    int k1 = rs[d + 1];
#pragma unroll 2
    for (int k = rs[d]; k < k1; ++k) {
        int s = csrc[k];
        acc += xw[(size_t)s * 64 + j] * (dinv[s] * di);
    }
    out[(size_t)d * 64 + j] = acc > 0.f ? acc : 0.01f * acc;  // leaky_relu(0.01)
}

// ---------------- classifier (fused 320->32->16->4; 43.5KB static LDS) ---------
__global__ void __launch_bounds__(256) cls_kernel(
    const float* __restrict__ x, const float* __restrict__ nodeF,
    const float* __restrict__ xg,
    const float* __restrict__ W1, const float* __restrict__ b1,
    const float* __restrict__ W2, const float* __restrict__ b2,
    const float* __restrict__ W3, const float* __restrict__ b3,
    float* __restrict__ outp, int n)
{
    __shared__ float sW1[320 * 32];
    __shared__ float sW2[32 * 16];
    __shared__ float sW3[16 * 4];
    __shared__ float sb1[32], sb2[16], sb3[4];
    int tid = threadIdx.x;
    for (int i = tid; i < 320 * 32; i += 256) sW1[i] = W1[i];
    for (int i = tid; i < 512; i += 256) sW2[i] = W2[i];
    if (tid < 64) sW3[tid] = W3[tid];
    if (tid < 32) sb1[tid] = b1[tid];
    if (tid < 16) sb2[tid] = b2[tid];
    if (tid < 4)  sb3[tid] = b3[tid];
    __syncthreads();
    int nd = blockIdx.x * 256 + tid;
    if (nd >= n) return;

    float a1[32];
#pragma unroll
    for (int j = 0; j < 32; ++j) a1[j] = sb1[j];
    const float4* xr = (const float4*)(x + (size_t)nd * 240);
#pragma unroll 1
    for (int k4 = 0; k4 < 60; ++k4) {
        float4 v = xr[k4];
        const float* wr = sW1 + k4 * 128;
#pragma unroll
        for (int j = 0; j < 32; ++j)
            a1[j] += v.x * wr[j] + v.y * wr[32 + j] + v.z * wr[64 + j] + v.w * wr[96 + j];
    }
    const float4* nf = (const float4*)(nodeF + (size_t)nd * 16);
#pragma unroll 1
    for (int k4 = 60; k4 < 64; ++k4) {
        float4 v = nf[k4 - 60];
        const float* wr = sW1 + k4 * 128;
#pragma unroll
        for (int j = 0; j < 32; ++j)
            a1[j] += v.x * wr[j] + v.y * wr[32 + j] + v.z * wr[64 + j] + v.w * wr[96 + j];
    }
    const float4* p2 = (const float4*)(xg + (size_t)nd * 64);
#pragma unroll 1
    for (int k4 = 0; k4 < 16; ++k4) {
        float4 v = p2[k4];
        const float* wr = sW1 + 8192 + k4 * 128;  // rows 256 + 4*k4
#pragma unroll
        for (int j = 0; j < 32; ++j)
            a1[j] += v.x * wr[j] + v.y * wr[32 + j] + v.z * wr[64 + j] + v.w * wr[96 + j];
    }
#pragma unroll
    for (int j = 0; j < 32; ++j) { float v = a1[j]; a1[j] = v > 0.f ? v : 0.01f * v; }

    float a2[16];
#pragma unroll
    for (int j = 0; j < 16; ++j) a2[j] = sb2[j];
#pragma unroll
    for (int k = 0; k < 32; ++k) {
        float v = a1[k];
        const float* wr = sW2 + k * 16;
#pragma unroll
        for (int j = 0; j < 16; ++j) a2[j] += v * wr[j];
    }
#pragma unroll
    for (int j = 0; j < 16; ++j) { float v = a2[j]; a2[j] = v > 0.f ? v : 0.01f * v; }

    float a3[4] = {sb3[0], sb3[1], sb3[2], sb3[3]};
#pragma unroll
    for (int k = 0; k < 16; ++k) {
        float v = a2[k];
        const float* wr = sW3 + k * 4;
        a3[0] += v * wr[0]; a3[1] += v * wr[1]; a3[2] += v * wr[2]; a3[3] += v * wr[3];
    }
    float4 o = make_float4(a3[0], a3[1], a3[2], a3[3]);
    *(float4*)(outp + (size_t)nd * 4) = o;
}

// ---------------- launcher ----------------
static inline unsigned nblk(size_t t) { return (unsigned)((t + 255) / 256); }

extern "C" void kernel_launch(void* const* d_in, const int* in_sizes, int n_in,
                              void* d_out, int out_size, void* d_ws, size_t ws_size,
                              hipStream_t stream)
{
    const float* x     = (const float*)d_in[0];
    const float* eseq  = (const float*)d_in[1];
    const float* nseq  = (const float*)d_in[2];
    const float* Wih   = (const float*)d_in[3];
    const float* Whh   = (const float*)d_in[4];
    const float* lb    = (const float*)d_in[5];
    const float* dnnW  = (const float*)d_in[6];
    const float* dnnb  = (const float*)d_in[7];
    const float* g1W   = (const float*)d_in[8];
    const float* g1att = (const float*)d_in[9];
    const float* g1b   = (const float*)d_in[10];
    const float* g2W   = (const float*)d_in[11];
    const float* g2att = (const float*)d_in[12];
    const float* g2b   = (const float*)d_in[13];
    const float* gc1W  = (const float*)d_in[14];
    const float* gc1b  = (const float*)d_in[15];
    const float* gc2W  = (const float*)d_in[16];
    const float* gc2b  = (const float*)d_in[17];
    const float* c1W   = (const float*)d_in[18];
    const float* c1b   = (const float*)d_in[19];
    const float* c2W   = (const float*)d_in[20];
    const float* c2b   = (const float*)d_in[21];
    const float* c3W   = (const float*)d_in[22];
    const float* c3b   = (const float*)d_in[23];
    const int* eidx  = (const int*)d_in[24];
    const int* elen  = (const int*)d_in[25];
    const int* nlen  = (const int*)d_in[26];

    const int N = NN;
    const int E = EE;
    const int* srcp = eidx;
    const int* dstp = eidx + E;

    // device-global scratch
    float *nodeF, *esc, *P1, *P2, *alpha, *amax, *rinv, *dinv, *cesc;
    int *cnt, *rs, *cur, *csrc;
    hipGetSymbolAddress((void**)&nodeF, HIP_SYMBOL(g_nodeF));
    hipGetSymbolAddress((void**)&esc,   HIP_SYMBOL(g_esc));
    hipGetSymbolAddress((void**)&P1,    HIP_SYMBOL(g_P1));
    hipGetSymbolAddress((void**)&P2,    HIP_SYMBOL(g_P2));
    hipGetSymbolAddress((void**)&alpha, HIP_SYMBOL(g_alpha));
    hipGetSymbolAddress((void**)&amax,  HIP_SYMBOL(g_amax));
    hipGetSymbolAddress((void**)&rinv,  HIP_SYMBOL(g_rinv));
    hipGetSymbolAddress((void**)&dinv,  HIP_SYMBOL(g_dinv));
    hipGetSymbolAddress((void**)&cnt,   HIP_SYMBOL(g_cnt));
    hipGetSymbolAddress((void**)&rs,    HIP_SYMBOL(g_rs));
    hipGetSymbolAddress((void**)&cur,   HIP_SYMBOL(g_cur));
    hipGetSymbolAddress((void**)&csrc,  HIP_SYMBOL(g_csrc));
    hipGetSymbolAddress((void**)&cesc,  HIP_SYMBOL(g_cesc));

    float* out0   = (float*)d_out;             // [N,4]
    float* outGcn = out0 + (size_t)N * 4;      // [N,64]
    float* outGat = outGcn + (size_t)N * 64;   // [N,64]

    // ---- temporal branches (node + edge fused; 32 seqs/wave, bf16 MFMA) ----
    const int nNodeBlk = (N + 127) / 128;        // 391
    const int nEdgeBlk = (E + 127) / 128;        // 3125
    lstm_fused_kernel<<<nNodeBlk + nEdgeBlk, 256, 0, stream>>>(
        nseq, nlen, eseq, elen, Wih, Whh, lb, dnnW, dnnb, nodeF, esc, nNodeBlk);

    // ---- CSR build (graph fixed per launch; also yields GCN degrees) ----
    zero_cnt_kernel<<<nblk(N), 256, 0, stream>>>(cnt, N);
    count_kernel<<<nblk(E), 256, 0, stream>>>(dstp, cnt, E);
    scan_kernel<<<1, 256, 0, stream>>>(cnt, rs, cur, N, E);
    fill_kernel<<<nblk(E), 256, 0, stream>>>(srcp, dstp, esc, cur, csrc, cesc, E);
    dinv_kernel<<<nblk(N), 256, 0, stream>>>(cnt, dinv, N);

    // ---- GAT layer 1 (H=8, C=8): P1 = xh1, P2 = gat1 out ----
    gemmX_kernel<<<(N + 3) / 4, 256, 0, stream>>>(x, nodeF, g1W, P1, N);
    alpha_kernel<8, 8><<<nblk((size_t)N * 8), 256, 0, stream>>>(P1, g1att, alpha, N);
    gat_softmax_csr_kernel<8><<<nblk((size_t)N * 8), 256, 0, stream>>>(rs, csrc, alpha, amax, rinv, N);
    gat_gather_kernel<8, false><<<(N + 3) / 4, 256, 0, stream>>>(
        rs, csrc, cesc, P1, alpha, amax, rinv, g1b, P2, N);

    // ---- GAT layer 2 (H=1, C=64): P1 = xh2, output -> outGat ----
    gemm64_kernel<<<(N + 3) / 4, 256, 0, stream>>>(P2, g2W, P1, N);
    alpha_kernel<1, 64><<<nblk(N), 256, 0, stream>>>(P1, g2att, alpha, N);
    gat_softmax_csr_kernel<1><<<nblk(N), 256, 0, stream>>>(rs, csrc, alpha, amax, rinv, N);
    gat_gather_kernel<1, true><<<(N + 3) / 4, 256, 0, stream>>>(
        rs, csrc, cesc, P1, alpha, amax, rinv, g2b, outGat, N);

    // ---- GCN layer 1: P1 = xw1, P2 = lrelu(gcn1) ----
    gemmX_kernel<<<(N + 3) / 4, 256, 0, stream>>>(x, nodeF, gc1W, P1, N);
    gcn_gather_kernel<<<(N + 3) / 4, 256, 0, stream>>>(rs, csrc, P1, dinv, gc1b, P2, N);

    // ---- GCN layer 2: P1 = xw2, output -> outGcn (x_gcn, lrelu fused) ----
    gemm64_kernel<<<(N + 3) / 4, 256, 0, stream>>>(P2, gc2W, P1, N);
    gcn_gather_kernel<<<(N + 3) / 4, 256, 0, stream>>>(rs, csrc, P1, dinv, gc2b, outGcn, N);

    // ---- classifier (reads x_gcn from d_out) ----
    cls_kernel<<<nblk(N), 256, 0, stream>>>(x, nodeF, outGcn, c1W, c1b, c2W, c2b, c3W, c3b, out0, N);
}

// Round 3
// 1032.479 us; speedup vs baseline: 1.4746x; 1.0132x over previous
//
#include <hip/hip_runtime.h>
#include <hip/hip_bf16.h>

// TTAGN: LSTM(edge,node) -> GAT x2 + GCN x2 -> classifier.
// Inputs fp32, internal fp32, OUTPUT fp32.
// d_out = concat(out[N,4], x_gcn[N,64], x_gat[N,64]) as fp32.
// Scratch in __device__ globals.
//
// R13: LSTM length bucketing. R12's MFMA LSTM (171us, VALUBusy 83%) runs
// all 16 steps for every seq though lens are uniform[1,16] (avg 8.5).
// Counting-sort seqs by length (descending, 16 bins) -> waves get uniform
// lengths -> loop bound = wave-max ceil(len/2) float4 iters (56% of work).
// Also: gat_softmax H=8 thread-per-row (1 csrc read + 2 float4 alpha loads
// per edge instead of 8 scalar-gathered passes), scan widened to 1024 thr.
// LSTM math unchanged from R12 (split-bf16 MFMA, 8 mfma/step).

typedef unsigned int u32;

#define NN 50000
#define EE 400000

__device__ float g_nodeF[NN * 16];
__device__ float g_esc[EE];
__device__ float g_P1[NN * 64];
__device__ float g_P2[NN * 64];
__device__ float g_alpha[NN * 8];
__device__ float g_amax[NN * 8];
__device__ float g_rinv[NN * 8];
__device__ float g_dinv[NN];
__device__ int   g_cnt[NN];
__device__ int   g_rs[NN + 1];
__device__ int   g_cur[NN];
__device__ int   g_csrc[EE];
__device__ float g_cesc[EE];
__device__ int   g_bhist[32];   // [0..15] node bins (bin=16-len), [16..31] edge
__device__ int   g_bbase[32];   // exclusive bases -> rolling cursors
__device__ int   g_permN[NN];
__device__ int   g_permE[EE];

__device__ __forceinline__ float rcpf(float x) { return __builtin_amdgcn_rcpf(x); }
__device__ __forceinline__ float sigf(float x) { return rcpf(1.0f + __expf(-x)); }
__device__ __forceinline__ float tanh_fast(float x) {
    return 1.0f - 2.0f * rcpf(__expf(2.0f * x) + 1.0f);
}

// ---------------- fused LSTM (bf16 MFMA, split-precision) ----------------
typedef short short8 __attribute__((ext_vector_type(8)));
typedef float f32x16 __attribute__((ext_vector_type(16)));

union S8U { short8 v; unsigned u[4]; };

// pack two floats as bf16 pair (truncation; lo-chains compensate the error)
__device__ __forceinline__ unsigned pk_hi(float a, float b) {
    return (__float_as_uint(a) >> 16) | (__float_as_uint(b) & 0xFFFF0000u);
}
__device__ __forceinline__ float bftrunc(float a) {
    return __uint_as_float(__float_as_uint(a) & 0xFFFF0000u);
}
__device__ __forceinline__ float lo_res(float a) { return a - bftrunc(a); }
__device__ __forceinline__ unsigned sx32(unsigned v) {
    return (unsigned)__shfl_xor((int)v, 32, 64);
}

// ---------------- length bucketing (counting sort, descending) -------------
__global__ void __launch_bounds__(256) bucket_hist_kernel(
    const int* __restrict__ nlen, const int* __restrict__ elen)
{
    __shared__ int hb[32];
    int t = threadIdx.x;
    if (t < 32) hb[t] = 0;
    __syncthreads();
    int i = blockIdx.x * 256 + t;
    int bin = -1;
    if (i < NN + EE) {
        bin = (i < NN) ? (16 - nlen[i]) : (32 - elen[i - NN]);
    }
    if (bin >= 0) atomicAdd(&hb[bin], 1);
    __syncthreads();
    if (t < 32 && hb[t] > 0) atomicAdd(&g_bhist[t], hb[t]);
}

__global__ void __launch_bounds__(64) bucket_scan_kernel()
{
    if (threadIdx.x == 0) {
        int acc = 0;
        for (int b = 0; b < 16; ++b) { g_bbase[b] = acc; acc += g_bhist[b]; }
        acc = 0;
        for (int b = 16; b < 32; ++b) { g_bbase[b] = acc; acc += g_bhist[b]; }
    }
}

__global__ void __launch_bounds__(256) bucket_scatter_kernel(
    const int* __restrict__ nlen, const int* __restrict__ elen)
{
    __shared__ int hb[32];
    int t = threadIdx.x;
    if (t < 32) hb[t] = 0;
    __syncthreads();
    int i = blockIdx.x * 256 + t;
    int bin = -1, idx = 0;
    if (i < NN + EE) {
        if (i < NN) { idx = i; bin = 16 - nlen[i]; }
        else        { idx = i - NN; bin = 32 - elen[i - NN]; }
    }
    if (bin >= 0) atomicAdd(&hb[bin], 1);
    __syncthreads();
    if (t < 32) {
        int c = hb[t];
        hb[t] = c > 0 ? atomicAdd(&g_bbase[t], c) : 0;
    }
    __syncthreads();
    if (bin >= 0) {
        int pos = atomicAdd(&hb[bin], 1);
        if (i < NN) g_permN[pos] = idx; else g_permE[pos] = idx;
    }
}

// One wave = 32 sequences (lanes l and l+32 share seq col=l&31).
// Lane (col,hi) owns units U[j] = (j&3) + 8*(j>>2) + 4*hi, j=0..7, of its seq.
// Block = 256 threads = 4 independent waves = 128 seqs (perm-bucketed).
__global__ void __launch_bounds__(256, 3) lstm_fused_kernel(
    const float* __restrict__ nseq, const int* __restrict__ nlen,
    const float* __restrict__ eseq, const int* __restrict__ elen,
    const float* __restrict__ Wih, const float* __restrict__ Whh,
    const float* __restrict__ bias,
    const float* __restrict__ dnnW, const float* __restrict__ dnnb,
    const int* __restrict__ permN, const int* __restrict__ permE,
    float* __restrict__ nodeF, float* __restrict__ esc, int nNodeBlk)
{
    const int lane = threadIdx.x & 63;
    const int col  = lane & 31;
    const int hi   = lane >> 5;
    const bool isLo = (hi == 0);
    const int wave = threadIdx.x >> 6;

    const bool edgeMode = (int)blockIdx.x >= nNodeBlk;
    const float* seq = edgeMode ? eseq : nseq;
    const int*  lens = edgeMode ? elen : nlen;
    const int*  perm = edgeMode ? permE : permN;
    const int limit  = edgeMode ? EE : NN;
    const int bbase  = edgeMode ? ((int)blockIdx.x - nNodeBlk) : (int)blockIdx.x;
    const int g  = bbase * 128 + wave * 32 + col;
    const int gc = g < limit ? g : limit - 1;
    const int s  = perm[gc];                 // actual sequence index
    const bool valid = g < limit;

    // ---- A fragments. Layout: lane(row=col [+32 tile1], k=8*hi+j, j=0..7).
    const int row0 = col, row1 = col + 32;
    const int ko = hi * 8;
    S8U ahh0, ahh1, ahl0, ahl1, ax0, ax1;
    {
        const float* w0 = Whh + row0 * 16 + ko;
        const float* w1 = Whh + row1 * 16 + ko;
#pragma unroll
        for (int r = 0; r < 4; ++r) {
            float a0 = w0[2 * r], b0 = w0[2 * r + 1];
            float a1 = w1[2 * r], b1 = w1[2 * r + 1];
            ahh0.u[r] = pk_hi(a0, b0);
            ahh1.u[r] = pk_hi(a1, b1);
            ahl0.u[r] = pk_hi(lo_res(a0), lo_res(b0));
            ahl1.u[r] = pk_hi(lo_res(a1), lo_res(b1));
        }
        // x-chain A (k slots, lo lanes only; hi lanes all-zero):
        // k0,k1=Wih_hi ; k2=bias_hi ; k3,k4=Wih_hi (for x_lo) ;
        // k5,k6=Wih_lo ; k7=bias_lo
#pragma unroll
        for (int r = 0; r < 4; ++r) { ax0.u[r] = 0u; ax1.u[r] = 0u; }
        if (isLo) {
            float wa0 = Wih[row0 * 2], wb0 = Wih[row0 * 2 + 1], bb0 = bias[row0];
            float wa1 = Wih[row1 * 2], wb1 = Wih[row1 * 2 + 1], bb1 = bias[row1];
            ax0.u[0] = pk_hi(wa0, wb0);
            ax0.u[1] = pk_hi(bb0, wa0);
            ax0.u[2] = pk_hi(wb0, lo_res(wa0));
            ax0.u[3] = pk_hi(lo_res(wb0), lo_res(bb0));
            ax1.u[0] = pk_hi(wa1, wb1);
            ax1.u[1] = pk_hi(bb1, wa1);
            ax1.u[2] = pk_hi(wb1, lo_res(wa1));
            ax1.u[3] = pk_hi(lo_res(wb1), lo_res(bb1));
        }
    }

    const f32x16 zc = {0.f, 0.f, 0.f, 0.f, 0.f, 0.f, 0.f, 0.f,
                       0.f, 0.f, 0.f, 0.f, 0.f, 0.f, 0.f, 0.f};
    const unsigned bxmask = isLo ? 0xFFFFFFFFu : 0u;
    const unsigned one_bf = 0x3F80u;  // bf16(1.0) in low half

    float cst[8], hlast[8];
#pragma unroll
    for (int j = 0; j < 8; ++j) { cst[j] = 0.f; hlast[j] = 0.f; }
    unsigned ph[4], pl[4];  // packed h (hi/lo), own units
#pragma unroll
    for (int r = 0; r < 4; ++r) { ph[r] = 0u; pl[r] = 0u; }

    const float4* sp = (const float4*)seq + (size_t)s * 8;  // 32 floats/seq
    const int lenm1 = lens[s] - 1;                          // in [0,15]
    // wave-max length -> float4 iterations needed (bucketed => ~uniform)
    int lm = lenm1;
#pragma unroll
    for (int off = 32; off >= 1; off >>= 1) {
        int o = __shfl_xor(lm, off, 64);
        lm = lm > o ? lm : o;
    }
    const int nIter = (lm >> 1) + 1;   // in [1,8]

    float4 q = sp[0];
#pragma unroll 1
    for (int i = 0; i < nIter; ++i) {
        float4 qn = sp[(i + 1) & 7];  // prefetch (wraps; always in-bounds)
#pragma unroll
        for (int hf = 0; hf < 2; ++hf) {
            const int t = 2 * i + hf;
            const float x0 = hf ? q.z : q.x;
            const float x1 = hf ? q.w : q.y;

            // B h-fragments: B[k=8*hi+j][col]; exchange halves via shfl.
            S8U bhh, bhl, bx;
            {
                unsigned t0 = sx32(ph[0]), t1 = sx32(ph[1]);
                unsigned t2 = sx32(ph[2]), t3 = sx32(ph[3]);
                bhh.u[0] = isLo ? ph[0] : t2;
                bhh.u[1] = isLo ? ph[1] : t3;
                bhh.u[2] = isLo ? t0 : ph[2];
                bhh.u[3] = isLo ? t1 : ph[3];
                unsigned s0 = sx32(pl[0]), s1 = sx32(pl[1]);
                unsigned s2 = sx32(pl[2]), s3 = sx32(pl[3]);
                bhl.u[0] = isLo ? pl[0] : s2;
                bhl.u[1] = isLo ? pl[1] : s3;
                bhl.u[2] = isLo ? s0 : pl[2];
                bhl.u[3] = isLo ? s1 : pl[3];
            }
            // B x-fragment: k0,k1=x_hi ; k2=1 ; k3,k4=x_lo ; k5,k6=x_hi ; k7=1
            {
                float xl0 = lo_res(x0), xl1 = lo_res(x1);
                bx.u[0] = pk_hi(x0, x1) & bxmask;
                bx.u[1] = (one_bf | (__float_as_uint(xl0) & 0xFFFF0000u)) & bxmask;
                bx.u[2] = pk_hi(xl1, x0) & bxmask;
                bx.u[3] = ((__float_as_uint(x1) >> 16) | (one_bf << 16)) & bxmask;
            }

            f32x16 d0 = __builtin_amdgcn_mfma_f32_32x32x16_bf16(ax0.v, bx.v, zc, 0, 0, 0);
            f32x16 d1 = __builtin_amdgcn_mfma_f32_32x32x16_bf16(ax1.v, bx.v, zc, 0, 0, 0);
            d0 = __builtin_amdgcn_mfma_f32_32x32x16_bf16(ahh0.v, bhh.v, d0, 0, 0, 0);
            d1 = __builtin_amdgcn_mfma_f32_32x32x16_bf16(ahh1.v, bhh.v, d1, 0, 0, 0);
            d0 = __builtin_amdgcn_mfma_f32_32x32x16_bf16(ahl0.v, bhh.v, d0, 0, 0, 0);
            d1 = __builtin_amdgcn_mfma_f32_32x32x16_bf16(ahl1.v, bhh.v, d1, 0, 0, 0);
            d0 = __builtin_amdgcn_mfma_f32_32x32x16_bf16(ahh0.v, bhl.v, d0, 0, 0, 0);
            d1 = __builtin_amdgcn_mfma_f32_32x32x16_bf16(ahh1.v, bhl.v, d1, 0, 0, 0);

            // d0[j]=i_U[j], d0[8+j]=f_U[j], d1[j]=g_U[j], d1[8+j]=o_U[j]
            float hh[8];
#pragma unroll
            for (int j = 0; j < 8; ++j) {
                float ip = d0[j], fp = d0[8 + j], gp = d1[j], op = d1[8 + j];
                float cu = sigf(fp) * cst[j] + sigf(ip) * tanh_fast(gp);
                cst[j] = cu;
                hh[j] = sigf(op) * tanh_fast(cu);
            }
            const bool selm = (t == lenm1);
#pragma unroll
            for (int j = 0; j < 8; ++j) hlast[j] = selm ? hh[j] : hlast[j];
            // repack h (hi + lo residual)
#pragma unroll
            for (int r = 0; r < 4; ++r) {
                float a = hh[2 * r], b = hh[2 * r + 1];
                ph[r] = pk_hi(a, b);
                pl[r] = pk_hi(lo_res(a), lo_res(b));
            }
        }
        q = qn;
    }

    if (edgeMode) {
        // esc[s] = dot(h16, dnnW) + dnnb ; lane holds units {0..3,8..11}+4*hi
        float4 dA = *(const float4*)(dnnW + hi * 4);
        float4 dB = *(const float4*)(dnnW + hi * 4 + 8);
        float part = hlast[0] * dA.x + hlast[1] * dA.y + hlast[2] * dA.z + hlast[3] * dA.w
                   + hlast[4] * dB.x + hlast[5] * dB.y + hlast[6] * dB.z + hlast[7] * dB.w;
        float tot = part + __shfl_xor(part, 32, 64);
        if (isLo && valid) esc[s] = tot + dnnb[0];
    } else {
        if (valid) {
            float* dst = nodeF + (size_t)s * 16 + hi * 4;
            *(float4*)(dst)     = make_float4(hlast[0], hlast[1], hlast[2], hlast[3]);
            *(float4*)(dst + 8) = make_float4(hlast[4], hlast[5], hlast[6], hlast[7]);
        }
    }
}

// ---------------- CSR build ----------------
__global__ void __launch_bounds__(256) zero_cnt_kernel(int* cnt, int n)
{
    int t = blockIdx.x * 256 + threadIdx.x;
    if (t < n) cnt[t] = 0;
    if (blockIdx.x == 0 && threadIdx.x < 32) g_bhist[threadIdx.x] = 0;
}
__global__ void __launch_bounds__(256) count_kernel(const int* __restrict__ dst,
                                                    int* cnt, int E)
{
    int e = blockIdx.x * 256 + threadIdx.x;
    if (e < E) atomicAdd(&cnt[dst[e]], 1);
}
// single-block exclusive scan; also rowstart[n]=E and cursor copy.
__global__ void __launch_bounds__(1024) scan_kernel(const int* __restrict__ cnt,
                                                    int* __restrict__ rs,
                                                    int* __restrict__ cur,
                                                    int n, int E)
{
    __shared__ int part[1024];
    int t = threadIdx.x;
    const int CH = (n + 1023) / 1024;
    int base = t * CH;
    int s = 0;
    for (int i = 0; i < CH; ++i) {
        int idx = base + i;
        if (idx < n) s += cnt[idx];
    }
    part[t] = s;
    __syncthreads();
    if (t == 0) {
        int acc = 0;
        for (int i = 0; i < 1024; ++i) { int v = part[i]; part[i] = acc; acc += v; }
    }
    __syncthreads();
    int run = part[t];
    for (int i = 0; i < CH; ++i) {
        int idx = base + i;
        if (idx < n) { rs[idx] = run; cur[idx] = run; run += cnt[idx]; }
    }
    if (t == 0) rs[n] = E;
}
__global__ void __launch_bounds__(256) fill_kernel(const int* __restrict__ src,
                                                   const int* __restrict__ dst,
                                                   const float* __restrict__ esc,
                                                   int* __restrict__ cur,
                                                   int* __restrict__ csrc,
                                                   float* __restrict__ cesc, int E)
{
    int e = blockIdx.x * 256 + threadIdx.x;
    if (e >= E) return;
    int pos = atomicAdd(&cur[dst[e]], 1);
    csrc[pos] = src[e];
    cesc[pos] = esc[e];
}
__global__ void __launch_bounds__(256) dinv_kernel(const int* __restrict__ cnt,
                                                   float* __restrict__ dinv, int n)
{
    int t = blockIdx.x * 256 + threadIdx.x;
    if (t < n) dinv[t] = rsqrtf((float)cnt[t] + 1.0f);
}

// --- C[n,64] = [x(240)|nodeF(16)] @ W[256,64]; 32KB static LDS, 2-phase K ---
__global__ void __launch_bounds__(256) gemmX_kernel(
    const float* __restrict__ x, const float* __restrict__ nodeF,
    const float* __restrict__ W, float* __restrict__ C, int n)
{
    __shared__ float sW[128 * 64];  // 32 KB
    int j = threadIdx.x & 63;
    int node = blockIdx.x * 4 + (threadIdx.x >> 6);
    bool valid = node < n;
    const float4* xr = (const float4*)(x + (size_t)node * 240);
    float acc = 0.f;

    for (int i = threadIdx.x; i < 128 * 64; i += 256) sW[i] = W[i];
    __syncthreads();
    if (valid) {
#pragma unroll 4
        for (int k4 = 0; k4 < 32; ++k4) {
            float4 v = xr[k4];
            const float* wr = sW + k4 * 256 + j;
            acc += v.x * wr[0] + v.y * wr[64] + v.z * wr[128] + v.w * wr[192];
        }
    }
    __syncthreads();
    for (int i = threadIdx.x; i < 128 * 64; i += 256) sW[i] = W[128 * 64 + i];
    __syncthreads();
    if (valid) {
#pragma unroll 4
        for (int k4 = 32; k4 < 60; ++k4) {
            float4 v = xr[k4];
            const float* wr = sW + (k4 - 32) * 256 + j;
            acc += v.x * wr[0] + v.y * wr[64] + v.z * wr[128] + v.w * wr[192];
        }
        const float4* nf = (const float4*)(nodeF + (size_t)node * 16);
#pragma unroll
        for (int k4 = 60; k4 < 64; ++k4) {
            float4 v = nf[k4 - 60];
            const float* wr = sW + (k4 - 32) * 256 + j;
            acc += v.x * wr[0] + v.y * wr[64] + v.z * wr[128] + v.w * wr[192];
        }
        C[(size_t)node * 64 + j] = acc;
    }
}

// ------- C[n,64] = A[n,64] @ W[64,64]; 16KB static LDS -------
__global__ void __launch_bounds__(256) gemm64_kernel(const float* __restrict__ A,
                                                     const float* __restrict__ W,
                                                     float* __restrict__ C, int n)
{
    __shared__ float sW[64 * 64];  // 16 KB
    for (int i = threadIdx.x; i < 64 * 64; i += 256) sW[i] = W[i];
    __syncthreads();
    int j = threadIdx.x & 63;
    int node = blockIdx.x * 4 + (threadIdx.x >> 6);
    if (node >= n) return;
    const float4* a4 = (const float4*)(A + (size_t)node * 64);
    float acc = 0.f;
#pragma unroll 4
    for (int k4 = 0; k4 < 16; ++k4) {
        float4 v = a4[k4];
        const float* wr = sW + k4 * 256 + j;
        acc += v.x * wr[0] + v.y * wr[64] + v.z * wr[128] + v.w * wr[192];
    }
    C[(size_t)node * 64 + j] = acc;
}

// ---------------- GAT ----------------
template <int H, int C>
__global__ void __launch_bounds__(256) alpha_kernel(const float* __restrict__ xh,
                                                    const float* __restrict__ att,
                                                    float* __restrict__ alpha, int n)
{
    int t = blockIdx.x * 256 + threadIdx.x;
    if (t >= n * H) return;
    int h = (H == 1) ? 0 : (t % H);
    int nd = (H == 1) ? t : (t / H);
    const float* row = xh + (size_t)nd * 64 + h * C;
    float s = 0.f;
#pragma unroll
    for (int c = 0; c < C; ++c) s += row[c] * att[h * C + c];
    alpha[t] = s;
}

// H=8 softmax, thread per dst row: 1 csrc read + 2 float4 alpha loads/edge.
__global__ void __launch_bounds__(256) gat_softmax8_row_kernel(
    const int* __restrict__ rs, const int* __restrict__ csrc,
    const float* __restrict__ alpha,
    float* __restrict__ amax, float* __restrict__ rinv, int n)
{
    int d = blockIdx.x * 256 + threadIdx.x;
    if (d >= n) return;
    int k0 = rs[d], k1 = rs[d + 1];
    float m[8];
#pragma unroll
    for (int h = 0; h < 8; ++h) m[h] = -INFINITY;
    for (int k = k0; k < k1; ++k) {
        const float4* ar = (const float4*)(alpha + (size_t)csrc[k] * 8);
        float4 a0 = ar[0], a1 = ar[1];
        float v[8] = {a0.x, a0.y, a0.z, a0.w, a1.x, a1.y, a1.z, a1.w};
#pragma unroll
        for (int h = 0; h < 8; ++h) {
            float a = v[h] > 0.f ? v[h] : 0.2f * v[h];
            m[h] = fmaxf(m[h], a);
        }
    }
    float sm[8];
#pragma unroll
    for (int h = 0; h < 8; ++h) sm[h] = 0.f;
    for (int k = k0; k < k1; ++k) {
        const float4* ar = (const float4*)(alpha + (size_t)csrc[k] * 8);
        float4 a0 = ar[0], a1 = ar[1];
        float v[8] = {a0.x, a0.y, a0.z, a0.w, a1.x, a1.y, a1.z, a1.w};
#pragma unroll
        for (int h = 0; h < 8; ++h) {
            float a = v[h] > 0.f ? v[h] : 0.2f * v[h];
            sm[h] += __expf(a - m[h]);
        }
    }
    float4* mo = (float4*)(amax + (size_t)d * 8);
    mo[0] = make_float4(m[0], m[1], m[2], m[3]);
    mo[1] = make_float4(m[4], m[5], m[6], m[7]);
    float4* ro = (float4*)(rinv + (size_t)d * 8);
    ro[0] = make_float4(rcpf(sm[0]), rcpf(sm[1]), rcpf(sm[2]), rcpf(sm[3]));
    ro[1] = make_float4(rcpf(sm[4]), rcpf(sm[5]), rcpf(sm[6]), rcpf(sm[7]));
}

// per (dst,h): max then sum over in-edges (CSR). Writes amax, rinv=1/sum.
template <int H>
__global__ void __launch_bounds__(256) gat_softmax_csr_kernel(
    const int* __restrict__ rs, const int* __restrict__ csrc,
    const float* __restrict__ alpha,
    float* __restrict__ amax, float* __restrict__ rinv, int n)
{
    int t = blockIdx.x * 256 + threadIdx.x;
    if (t >= n * H) return;
    int h = (H == 1) ? 0 : (t % H);
    int d = (H == 1) ? t : (t / H);
    int k0 = rs[d], k1 = rs[d + 1];
    float m = -INFINITY;
    for (int k = k0; k < k1; ++k) {
        float a = alpha[(size_t)csrc[k] * H + h];
        a = a > 0.f ? a : 0.2f * a;
        m = fmaxf(m, a);
    }
    float s = 0.f;
    for (int k = k0; k < k1; ++k) {
        float a = alpha[(size_t)csrc[k] * H + h];
        a = a > 0.f ? a : 0.2f * a;
        s += __expf(a - m);
    }
    amax[t] = m;
    rinv[t] = rcpf(s);
}

// one wave per dst node (lane = feature col). acc = xh[d]+bias + sum coef*xh[s].
template <int H, bool FILTER>
__global__ void __launch_bounds__(256) gat_gather_kernel(
    const int* __restrict__ rs, const int* __restrict__ csrc,
    const float* __restrict__ cesc,
    const float* __restrict__ xh, const float* __restrict__ alpha,
    const float* __restrict__ amax, const float* __restrict__ rinv,
    const float* __restrict__ bias, float* __restrict__ out, int n)
{
    int j = threadIdx.x & 63;
    int d = blockIdx.x * 4 + (threadIdx.x >> 6);
    if (d >= n) return;
    int h = (H == 8) ? (j >> 3) : 0;
    float m = amax[(size_t)d * H + h];
    float ri = rinv[(size_t)d * H + h];
    float acc = xh[(size_t)d * 64 + j] + bias[j];
    int k1 = rs[d + 1];
#pragma unroll 2
    for (int k = rs[d]; k < k1; ++k) {
        int s = csrc[k];
        float a = alpha[(size_t)s * H + h];
        a = a > 0.f ? a : 0.2f * a;
        float coef = __expf(a - m) * ri + cesc[k];
        acc += xh[(size_t)s * 64 + j] * coef;
    }
    if (FILTER && !__builtin_isfinite(acc)) acc = 0.f;
    out[(size_t)d * 64 + j] = acc;
}

// ---------------- GCN gather (norm + bias + leaky_relu fused) ----------------
__global__ void __launch_bounds__(256) gcn_gather_kernel(
    const int* __restrict__ rs, const int* __restrict__ csrc,
    const float* __restrict__ xw, const float* __restrict__ dinv,
    const float* __restrict__ bias, float* __restrict__ out, int n)
{
    int j = threadIdx.x & 63;
    int d = blockIdx.x * 4 + (threadIdx.x >> 6);
    if (d >= n) return;
    float di = dinv[d];
    float acc = xw[(size_t)d * 64 + j] * di * di + bias[j];
    int k1 = rs[d + 1];
#pragma unroll 2
    for (int k = rs[d]; k < k1; ++k) {
        int s = csrc[k];
        acc += xw[(size_t)s * 64 + j] * (dinv[s] * di);
    }
    out[(size_t)d * 64 + j] = acc > 0.f ? acc : 0.01f * acc;  // leaky_relu(0.01)
}

// ---------------- classifier (fused 320->32->16->4; 43.5KB static LDS) ---------
__global__ void __launch_bounds__(256) cls_kernel(
    const float* __restrict__ x, const float* __restrict__ nodeF,
    const float* __restrict__ xg,
    const float* __restrict__ W1, const float* __restrict__ b1,
    const float* __restrict__ W2, const float* __restrict__ b2,
    const float* __restrict__ W3, const float* __restrict__ b3,
    float* __restrict__ outp, int n)
{
    __shared__ float sW1[320 * 32];
    __shared__ float sW2[32 * 16];
    __shared__ float sW3[16 * 4];
    __shared__ float sb1[32], sb2[16], sb3[4];
    int tid = threadIdx.x;
    for (int i = tid; i < 320 * 32; i += 256) sW1[i] = W1[i];
    for (int i = tid; i < 512; i += 256) sW2[i] = W2[i];
    if (tid < 64) sW3[tid] = W3[tid];
    if (tid < 32) sb1[tid] = b1[tid];
    if (tid < 16) sb2[tid] = b2[tid];
    if (tid < 4)  sb3[tid] = b3[tid];
    __syncthreads();
    int nd = blockIdx.x * 256 + tid;
    if (nd >= n) return;

    float a1[32];
#pragma unroll
    for (int j = 0; j < 32; ++j) a1[j] = sb1[j];
    const float4* xr = (const float4*)(x + (size_t)nd * 240);
#pragma unroll 1
    for (int k4 = 0; k4 < 60; ++k4) {
        float4 v = xr[k4];
        const float* wr = sW1 + k4 * 128;
#pragma unroll
        for (int j = 0; j < 32; ++j)
            a1[j] += v.x * wr[j] + v.y * wr[32 + j] + v.z * wr[64 + j] + v.w * wr[96 + j];
    }
    const float4* nf = (const float4*)(nodeF + (size_t)nd * 16);
#pragma unroll 1
    for (int k4 = 60; k4 < 64; ++k4) {
        float4 v = nf[k4 - 60];
        const float* wr = sW1 + k4 * 128;
#pragma unroll
        for (int j = 0; j < 32; ++j)
            a1[j] += v.x * wr[j] + v.y * wr[32 + j] + v.z * wr[64 + j] + v.w * wr[96 + j];
    }
    const float4* p2 = (const float4*)(xg + (size_t)nd * 64);
#pragma unroll 1
    for (int k4 = 0; k4 < 16; ++k4) {
        float4 v = p2[k4];
        const float* wr = sW1 + 8192 + k4 * 128;  // rows 256 + 4*k4
#pragma unroll
        for (int j = 0; j < 32; ++j)
            a1[j] += v.x * wr[j] + v.y * wr[32 + j] + v.z * wr[64 + j] + v.w * wr[96 + j];
    }
#pragma unroll
    for (int j = 0; j < 32; ++j) { float v = a1[j]; a1[j] = v > 0.f ? v : 0.01f * v; }

    float a2[16];
#pragma unroll
    for (int j = 0; j < 16; ++j) a2[j] = sb2[j];
#pragma unroll
    for (int k = 0; k < 32; ++k) {
        float v = a1[k];
        const float* wr = sW2 + k * 16;
#pragma unroll
        for (int j = 0; j < 16; ++j) a2[j] += v * wr[j];
    }
#pragma unroll
    for (int j = 0; j < 16; ++j) { float v = a2[j]; a2[j] = v > 0.f ? v : 0.01f * v; }

    float a3[4] = {sb3[0], sb3[1], sb3[2], sb3[3]};
#pragma unroll
    for (int k = 0; k < 16; ++k) {
        float v = a2[k];
        const float* wr = sW3 + k * 4;
        a3[0] += v * wr[0]; a3[1] += v * wr[1]; a3[2] += v * wr[2]; a3[3] += v * wr[3];
    }
    float4 o = make_float4(a3[0], a3[1], a3[2], a3[3]);
    *(float4*)(outp + (size_t)nd * 4) = o;
}

// ---------------- launcher ----------------
static inline unsigned nblk(size_t t) { return (unsigned)((t + 255) / 256); }

extern "C" void kernel_launch(void* const* d_in, const int* in_sizes, int n_in,
                              void* d_out, int out_size, void* d_ws, size_t ws_size,
                              hipStream_t stream)
{
    const float* x     = (const float*)d_in[0];
    const float* eseq  = (const float*)d_in[1];
    const float* nseq  = (const float*)d_in[2];
    const float* Wih   = (const float*)d_in[3];
    const float* Whh   = (const float*)d_in[4];
    const float* lb    = (const float*)d_in[5];
    const float* dnnW  = (const float*)d_in[6];
    const float* dnnb  = (const float*)d_in[7];
    const float* g1W   = (const float*)d_in[8];
    const float* g1att = (const float*)d_in[9];
    const float* g1b   = (const float*)d_in[10];
    const float* g2W   = (const float*)d_in[11];
    const float* g2att = (const float*)d_in[12];
    const float* g2b   = (const float*)d_in[13];
    const float* gc1W  = (const float*)d_in[14];
    const float* gc1b  = (const float*)d_in[15];
    const float* gc2W  = (const float*)d_in[16];
    const float* gc2b  = (const float*)d_in[17];
    const float* c1W   = (const float*)d_in[18];
    const float* c1b   = (const float*)d_in[19];
    const float* c2W   = (const float*)d_in[20];
    const float* c2b   = (const float*)d_in[21];
    const float* c3W   = (const float*)d_in[22];
    const float* c3b   = (const float*)d_in[23];
    const int* eidx  = (const int*)d_in[24];
    const int* elen  = (const int*)d_in[25];
    const int* nlen  = (const int*)d_in[26];

    const int N = NN;
    const int E = EE;
    const int* srcp = eidx;
    const int* dstp = eidx + E;

    // device-global scratch
    float *nodeF, *esc, *P1, *P2, *alpha, *amax, *rinv, *dinv, *cesc;
    int *cnt, *rs, *cur, *csrc, *permN, *permE;
    hipGetSymbolAddress((void**)&nodeF, HIP_SYMBOL(g_nodeF));
    hipGetSymbolAddress((void**)&esc,   HIP_SYMBOL(g_esc));
    hipGetSymbolAddress((void**)&P1,    HIP_SYMBOL(g_P1));
    hipGetSymbolAddress((void**)&P2,    HIP_SYMBOL(g_P2));
    hipGetSymbolAddress((void**)&alpha, HIP_SYMBOL(g_alpha));
    hipGetSymbolAddress((void**)&amax,  HIP_SYMBOL(g_amax));
    hipGetSymbolAddress((void**)&rinv,  HIP_SYMBOL(g_rinv));
    hipGetSymbolAddress((void**)&dinv,  HIP_SYMBOL(g_dinv));
    hipGetSymbolAddress((void**)&cnt,   HIP_SYMBOL(g_cnt));
    hipGetSymbolAddress((void**)&rs,    HIP_SYMBOL(g_rs));
    hipGetSymbolAddress((void**)&cur,   HIP_SYMBOL(g_cur));
    hipGetSymbolAddress((void**)&csrc,  HIP_SYMBOL(g_csrc));
    hipGetSymbolAddress((void**)&cesc,  HIP_SYMBOL(g_cesc));
    hipGetSymbolAddress((void**)&permN, HIP_SYMBOL(g_permN));
    hipGetSymbolAddress((void**)&permE, HIP_SYMBOL(g_permE));

    float* out0   = (float*)d_out;             // [N,4]
    float* outGcn = out0 + (size_t)N * 4;      // [N,64]
    float* outGat = outGcn + (size_t)N * 64;   // [N,64]

    // ---- length bucketing (also zeroes cnt for CSR) ----
    zero_cnt_kernel<<<nblk(N), 256, 0, stream>>>(cnt, N);
    bucket_hist_kernel<<<nblk(NN + EE), 256, 0, stream>>>(nlen, elen);
    bucket_scan_kernel<<<1, 64, 0, stream>>>();
    bucket_scatter_kernel<<<nblk(NN + EE), 256, 0, stream>>>(nlen, elen);

    // ---- temporal branches (node + edge fused; 32 seqs/wave, bf16 MFMA) ----
    const int nNodeBlk = (N + 127) / 128;        // 391
    const int nEdgeBlk = (E + 127) / 128;        // 3125
    lstm_fused_kernel<<<nNodeBlk + nEdgeBlk, 256, 0, stream>>>(
        nseq, nlen, eseq, elen, Wih, Whh, lb, dnnW, dnnb, permN, permE,
        nodeF, esc, nNodeBlk);

    // ---- CSR build (graph fixed per launch; also yields GCN degrees) ----
    count_kernel<<<nblk(E), 256, 0, stream>>>(dstp, cnt, E);
    scan_kernel<<<1, 1024, 0, stream>>>(cnt, rs, cur, N, E);
    fill_kernel<<<nblk(E), 256, 0, stream>>>(srcp, dstp, esc, cur, csrc, cesc, E);
    dinv_kernel<<<nblk(N), 256, 0, stream>>>(cnt, dinv, N);

    // ---- GAT layer 1 (H=8, C=8): P1 = xh1, P2 = gat1 out ----
    gemmX_kernel<<<(N + 3) / 4, 256, 0, stream>>>(x, nodeF, g1W, P1, N);
    alpha_kernel<8, 8><<<nblk((size_t)N * 8), 256, 0, stream>>>(P1, g1att, alpha, N);
    gat_softmax8_row_kernel<<<nblk(N), 256, 0, stream>>>(rs, csrc, alpha, amax, rinv, N);
    gat_gather_kernel<8, false><<<(N + 3) / 4, 256, 0, stream>>>(
        rs, csrc, cesc, P1, alpha, amax, rinv, g1b, P2, N);

    // ---- GAT layer 2 (H=1, C=64): P1 = xh2, output -> outGat ----
    gemm64_kernel<<<(N + 3) / 4, 256, 0, stream>>>(P2, g2W, P1, N);
    alpha_kernel<1, 64><<<nblk(N), 256, 0, stream>>>(P1, g2att, alpha, N);
    gat_softmax_csr_kernel<1><<<nblk(N), 256, 0, stream>>>(rs, csrc, alpha, amax, rinv, N);
    gat_gather_kernel<1, true><<<(N + 3) / 4, 256, 0, stream>>>(
        rs, csrc, cesc, P1, alpha, amax, rinv, g2b, outGat, N);

    // ---- GCN layer 1: P1 = xw1, P2 = lrelu(gcn1) ----
    gemmX_kernel<<<(N + 3) / 4, 256, 0, stream>>>(x, nodeF, gc1W, P1, N);
    gcn_gather_kernel<<<(N + 3) / 4, 256, 0, stream>>>(rs, csrc, P1, dinv, gc1b, P2, N);

    // ---- GCN layer 2: P1 = xw2, output -> outGcn (x_gcn, lrelu fused) ----
    gemm64_kernel<<<(N + 3) / 4, 256, 0, stream>>>(P2, gc2W, P1, N);
    gcn_gather_kernel<<<(N + 3) / 4, 256, 0, stream>>>(rs, csrc, P1, dinv, gc2b, outGcn, N);

    // ---- classifier (reads x_gcn from d_out) ----
    cls_kernel<<<nblk(N), 256, 0, stream>>>(x, nodeF, outGcn, c1W, c1b, c2W, c2b, c3W, c3b, out0, N);
}

// Round 4
// 755.599 us; speedup vs baseline: 2.0150x; 1.3664x over previous
//
#include <hip/hip_runtime.h>
#include <hip/hip_bf16.h>

// TTAGN: LSTM(edge,node) -> GAT x2 + GCN x2 -> classifier.
// Inputs fp32, internal fp32, OUTPUT fp32.
// d_out = concat(out[N,4], x_gcn[N,64], x_gat[N,64]) as fp32.
// Scratch in __device__ globals.
//
// R14: MFMA dense GEMMs. R13's gemmX (163us x2, MfmaUtil 0, VALUBusy 35%)
// was a 256-deep DEPENDENT fp32 FMA chain per output -- pure latency.
// Both gemmX ([x|nodeF]@W256x64) and gemm64 (A@W64x64) now use the same
// validated 32x32x16 bf16 MFMA fragments as the LSTM (split-bf16 hi/lo,
// 3 compensation chains => ~1e-3 abs err). W packed once per block into
// LDS as bf16 pairs; each wave computes 32 nodes x 64 cols.
// LSTM (R12 math + R13 length bucketing) unchanged.

typedef unsigned int u32;

#define NN 50000
#define EE 400000

__device__ float g_nodeF[NN * 16];
__device__ float g_esc[EE];
__device__ float g_P1[NN * 64];
__device__ float g_P2[NN * 64];
__device__ float g_alpha[NN * 8];
__device__ float g_amax[NN * 8];
__device__ float g_rinv[NN * 8];
__device__ float g_dinv[NN];
__device__ int   g_cnt[NN];
__device__ int   g_rs[NN + 1];
__device__ int   g_cur[NN];
__device__ int   g_csrc[EE];
__device__ float g_cesc[EE];
__device__ int   g_bhist[32];   // [0..15] node bins (bin=16-len), [16..31] edge
__device__ int   g_bbase[32];   // exclusive bases -> rolling cursors
__device__ int   g_permN[NN];
__device__ int   g_permE[EE];

__device__ __forceinline__ float rcpf(float x) { return __builtin_amdgcn_rcpf(x); }
__device__ __forceinline__ float sigf(float x) { return rcpf(1.0f + __expf(-x)); }
__device__ __forceinline__ float tanh_fast(float x) {
    return 1.0f - 2.0f * rcpf(__expf(2.0f * x) + 1.0f);
}

// ---------------- bf16 MFMA helpers (split precision) ----------------
typedef short short8 __attribute__((ext_vector_type(8)));
typedef float f32x16 __attribute__((ext_vector_type(16)));

union S8U { short8 v; unsigned u[4]; };

// pack two floats as bf16 pair (truncation; lo-chains compensate the error)
__device__ __forceinline__ unsigned pk_hi(float a, float b) {
    return (__float_as_uint(a) >> 16) | (__float_as_uint(b) & 0xFFFF0000u);
}
__device__ __forceinline__ float bftrunc(float a) {
    return __uint_as_float(__float_as_uint(a) & 0xFFFF0000u);
}
__device__ __forceinline__ float lo_res(float a) { return a - bftrunc(a); }
__device__ __forceinline__ unsigned sx32(unsigned v) {
    return (unsigned)__shfl_xor((int)v, 32, 64);
}

// ---------------- length bucketing (counting sort, descending) -------------
__global__ void __launch_bounds__(256) bucket_hist_kernel(
    const int* __restrict__ nlen, const int* __restrict__ elen)
{
    __shared__ int hb[32];
    int t = threadIdx.x;
    if (t < 32) hb[t] = 0;
    __syncthreads();
    int i = blockIdx.x * 256 + t;
    int bin = -1;
    if (i < NN + EE) {
        bin = (i < NN) ? (16 - nlen[i]) : (32 - elen[i - NN]);
    }
    if (bin >= 0) atomicAdd(&hb[bin], 1);
    __syncthreads();
    if (t < 32 && hb[t] > 0) atomicAdd(&g_bhist[t], hb[t]);
}

__global__ void __launch_bounds__(64) bucket_scan_kernel()
{
    if (threadIdx.x == 0) {
        int acc = 0;
        for (int b = 0; b < 16; ++b) { g_bbase[b] = acc; acc += g_bhist[b]; }
        acc = 0;
        for (int b = 16; b < 32; ++b) { g_bbase[b] = acc; acc += g_bhist[b]; }
    }
}

__global__ void __launch_bounds__(256) bucket_scatter_kernel(
    const int* __restrict__ nlen, const int* __restrict__ elen)
{
    __shared__ int hb[32];
    int t = threadIdx.x;
    if (t < 32) hb[t] = 0;
    __syncthreads();
    int i = blockIdx.x * 256 + t;
    int bin = -1, idx = 0;
    if (i < NN + EE) {
        if (i < NN) { idx = i; bin = 16 - nlen[i]; }
        else        { idx = i - NN; bin = 32 - elen[i - NN]; }
    }
    if (bin >= 0) atomicAdd(&hb[bin], 1);
    __syncthreads();
    if (t < 32) {
        int c = hb[t];
        hb[t] = c > 0 ? atomicAdd(&g_bbase[t], c) : 0;
    }
    __syncthreads();
    if (bin >= 0) {
        int pos = atomicAdd(&hb[bin], 1);
        if (i < NN) g_permN[pos] = idx; else g_permE[pos] = idx;
    }
}

// One wave = 32 sequences (lanes l and l+32 share seq col=l&31).
// Lane (col,hi) owns units U[j] = (j&3) + 8*(j>>2) + 4*hi, j=0..7, of its seq.
// Block = 256 threads = 4 independent waves = 128 seqs (perm-bucketed).
__global__ void __launch_bounds__(256, 3) lstm_fused_kernel(
    const float* __restrict__ nseq, const int* __restrict__ nlen,
    const float* __restrict__ eseq, const int* __restrict__ elen,
    const float* __restrict__ Wih, const float* __restrict__ Whh,
    const float* __restrict__ bias,
    const float* __restrict__ dnnW, const float* __restrict__ dnnb,
    const int* __restrict__ permN, const int* __restrict__ permE,
    float* __restrict__ nodeF, float* __restrict__ esc, int nNodeBlk)
{
    const int lane = threadIdx.x & 63;
    const int col  = lane & 31;
    const int hi   = lane >> 5;
    const bool isLo = (hi == 0);
    const int wave = threadIdx.x >> 6;

    const bool edgeMode = (int)blockIdx.x >= nNodeBlk;
    const float* seq = edgeMode ? eseq : nseq;
    const int*  lens = edgeMode ? elen : nlen;
    const int*  perm = edgeMode ? permE : permN;
    const int limit  = edgeMode ? EE : NN;
    const int bbase  = edgeMode ? ((int)blockIdx.x - nNodeBlk) : (int)blockIdx.x;
    const int g  = bbase * 128 + wave * 32 + col;
    const int gc = g < limit ? g : limit - 1;
    const int s  = perm[gc];                 // actual sequence index
    const bool valid = g < limit;

    // ---- A fragments. Layout: lane(row=col [+32 tile1], k=8*hi+j, j=0..7).
    const int row0 = col, row1 = col + 32;
    const int ko = hi * 8;
    S8U ahh0, ahh1, ahl0, ahl1, ax0, ax1;
    {
        const float* w0 = Whh + row0 * 16 + ko;
        const float* w1 = Whh + row1 * 16 + ko;
#pragma unroll
        for (int r = 0; r < 4; ++r) {
            float a0 = w0[2 * r], b0 = w0[2 * r + 1];
            float a1 = w1[2 * r], b1 = w1[2 * r + 1];
            ahh0.u[r] = pk_hi(a0, b0);
            ahh1.u[r] = pk_hi(a1, b1);
            ahl0.u[r] = pk_hi(lo_res(a0), lo_res(b0));
            ahl1.u[r] = pk_hi(lo_res(a1), lo_res(b1));
        }
        // x-chain A (k slots, lo lanes only; hi lanes all-zero):
        // k0,k1=Wih_hi ; k2=bias_hi ; k3,k4=Wih_hi (for x_lo) ;
        // k5,k6=Wih_lo ; k7=bias_lo
#pragma unroll
        for (int r = 0; r < 4; ++r) { ax0.u[r] = 0u; ax1.u[r] = 0u; }
        if (isLo) {
            float wa0 = Wih[row0 * 2], wb0 = Wih[row0 * 2 + 1], bb0 = bias[row0];
            float wa1 = Wih[row1 * 2], wb1 = Wih[row1 * 2 + 1], bb1 = bias[row1];
            ax0.u[0] = pk_hi(wa0, wb0);
            ax0.u[1] = pk_hi(bb0, wa0);
            ax0.u[2] = pk_hi(wb0, lo_res(wa0));
            ax0.u[3] = pk_hi(lo_res(wb0), lo_res(bb0));
            ax1.u[0] = pk_hi(wa1, wb1);
            ax1.u[1] = pk_hi(bb1, wa1);
            ax1.u[2] = pk_hi(wb1, lo_res(wa1));
            ax1.u[3] = pk_hi(lo_res(wb1), lo_res(bb1));
        }
    }

    const f32x16 zc = {0.f, 0.f, 0.f, 0.f, 0.f, 0.f, 0.f, 0.f,
                       0.f, 0.f, 0.f, 0.f, 0.f, 0.f, 0.f, 0.f};
    const unsigned bxmask = isLo ? 0xFFFFFFFFu : 0u;
    const unsigned one_bf = 0x3F80u;  // bf16(1.0) in low half

    float cst[8], hlast[8];
#pragma unroll
    for (int j = 0; j < 8; ++j) { cst[j] = 0.f; hlast[j] = 0.f; }
    unsigned ph[4], pl[4];  // packed h (hi/lo), own units
#pragma unroll
    for (int r = 0; r < 4; ++r) { ph[r] = 0u; pl[r] = 0u; }

    const float4* sp = (const float4*)seq + (size_t)s * 8;  // 32 floats/seq
    const int lenm1 = lens[s] - 1;                          // in [0,15]
    // wave-max length -> float4 iterations needed (bucketed => ~uniform)
    int lm = lenm1;
#pragma unroll
    for (int off = 32; off >= 1; off >>= 1) {
        int o = __shfl_xor(lm, off, 64);
        lm = lm > o ? lm : o;
    }
    const int nIter = (lm >> 1) + 1;   // in [1,8]

    float4 q = sp[0];
#pragma unroll 1
    for (int i = 0; i < nIter; ++i) {
        float4 qn = sp[(i + 1) & 7];  // prefetch (wraps; always in-bounds)
#pragma unroll
        for (int hf = 0; hf < 2; ++hf) {
            const int t = 2 * i + hf;
            const float x0 = hf ? q.z : q.x;
            const float x1 = hf ? q.w : q.y;

            // B h-fragments: B[k=8*hi+j][col]; exchange halves via shfl.
            S8U bhh, bhl, bx;
            {
                unsigned t0 = sx32(ph[0]), t1 = sx32(ph[1]);
                unsigned t2 = sx32(ph[2]), t3 = sx32(ph[3]);
                bhh.u[0] = isLo ? ph[0] : t2;
                bhh.u[1] = isLo ? ph[1] : t3;
                bhh.u[2] = isLo ? t0 : ph[2];
                bhh.u[3] = isLo ? t1 : ph[3];
                unsigned s0 = sx32(pl[0]), s1 = sx32(pl[1]);
                unsigned s2 = sx32(pl[2]), s3 = sx32(pl[3]);
                bhl.u[0] = isLo ? pl[0] : s2;
                bhl.u[1] = isLo ? pl[1] : s3;
                bhl.u[2] = isLo ? s0 : pl[2];
                bhl.u[3] = isLo ? s1 : pl[3];
            }
            // B x-fragment: k0,k1=x_hi ; k2=1 ; k3,k4=x_lo ; k5,k6=x_hi ; k7=1
            {
                float xl0 = lo_res(x0), xl1 = lo_res(x1);
                bx.u[0] = pk_hi(x0, x1) & bxmask;
                bx.u[1] = (one_bf | (__float_as_uint(xl0) & 0xFFFF0000u)) & bxmask;
                bx.u[2] = pk_hi(xl1, x0) & bxmask;
                bx.u[3] = ((__float_as_uint(x1) >> 16) | (one_bf << 16)) & bxmask;
            }

            f32x16 d0 = __builtin_amdgcn_mfma_f32_32x32x16_bf16(ax0.v, bx.v, zc, 0, 0, 0);
            f32x16 d1 = __builtin_amdgcn_mfma_f32_32x32x16_bf16(ax1.v, bx.v, zc, 0, 0, 0);
            d0 = __builtin_amdgcn_mfma_f32_32x32x16_bf16(ahh0.v, bhh.v, d0, 0, 0, 0);
            d1 = __builtin_amdgcn_mfma_f32_32x32x16_bf16(ahh1.v, bhh.v, d1, 0, 0, 0);
            d0 = __builtin_amdgcn_mfma_f32_32x32x16_bf16(ahl0.v, bhh.v, d0, 0, 0, 0);
            d1 = __builtin_amdgcn_mfma_f32_32x32x16_bf16(ahl1.v, bhh.v, d1, 0, 0, 0);
            d0 = __builtin_amdgcn_mfma_f32_32x32x16_bf16(ahh0.v, bhl.v, d0, 0, 0, 0);
            d1 = __builtin_amdgcn_mfma_f32_32x32x16_bf16(ahh1.v, bhl.v, d1, 0, 0, 0);

            // d0[j]=i_U[j], d0[8+j]=f_U[j], d1[j]=g_U[j], d1[8+j]=o_U[j]
            float hh[8];
#pragma unroll
            for (int j = 0; j < 8; ++j) {
                float ip = d0[j], fp = d0[8 + j], gp = d1[j], op = d1[8 + j];
                float cu = sigf(fp) * cst[j] + sigf(ip) * tanh_fast(gp);
                cst[j] = cu;
                hh[j] = sigf(op) * tanh_fast(cu);
            }
            const bool selm = (t == lenm1);
#pragma unroll
            for (int j = 0; j < 8; ++j) hlast[j] = selm ? hh[j] : hlast[j];
            // repack h (hi + lo residual)
#pragma unroll
            for (int r = 0; r < 4; ++r) {
                float a = hh[2 * r], b = hh[2 * r + 1];
                ph[r] = pk_hi(a, b);
                pl[r] = pk_hi(lo_res(a), lo_res(b));
            }
        }
        q = qn;
    }

    if (edgeMode) {
        // esc[s] = dot(h16, dnnW) + dnnb ; lane holds units {0..3,8..11}+4*hi
        float4 dA = *(const float4*)(dnnW + hi * 4);
        float4 dB = *(const float4*)(dnnW + hi * 4 + 8);
        float part = hlast[0] * dA.x + hlast[1] * dA.y + hlast[2] * dA.z + hlast[3] * dA.w
                   + hlast[4] * dB.x + hlast[5] * dB.y + hlast[6] * dB.z + hlast[7] * dB.w;
        float tot = part + __shfl_xor(part, 32, 64);
        if (isLo && valid) esc[s] = tot + dnnb[0];
    } else {
        if (valid) {
            float* dst = nodeF + (size_t)s * 16 + hi * 4;
            *(float4*)(dst)     = make_float4(hlast[0], hlast[1], hlast[2], hlast[3]);
            *(float4*)(dst + 8) = make_float4(hlast[4], hlast[5], hlast[6], hlast[7]);
        }
    }
}

// ---------------- CSR build ----------------
__global__ void __launch_bounds__(256) zero_cnt_kernel(int* cnt, int n)
{
    int t = blockIdx.x * 256 + threadIdx.x;
    if (t < n) cnt[t] = 0;
    if (blockIdx.x == 0 && threadIdx.x < 32) g_bhist[threadIdx.x] = 0;
}
__global__ void __launch_bounds__(256) count_kernel(const int* __restrict__ dst,
                                                    int* cnt, int E)
{
    int e = blockIdx.x * 256 + threadIdx.x;
    if (e < E) atomicAdd(&cnt[dst[e]], 1);
}
// single-block exclusive scan; also rowstart[n]=E and cursor copy.
__global__ void __launch_bounds__(1024) scan_kernel(const int* __restrict__ cnt,
                                                    int* __restrict__ rs,
                                                    int* __restrict__ cur,
                                                    int n, int E)
{
    __shared__ int part[1024];
    int t = threadIdx.x;
    const int CH = (n + 1023) / 1024;
    int base = t * CH;
    int s = 0;
    for (int i = 0; i < CH; ++i) {
        int idx = base + i;
        if (idx < n) s += cnt[idx];
    }
    part[t] = s;
    __syncthreads();
    if (t == 0) {
        int acc = 0;
        for (int i = 0; i < 1024; ++i) { int v = part[i]; part[i] = acc; acc += v; }
    }
    __syncthreads();
    int run = part[t];
    for (int i = 0; i < CH; ++i) {
        int idx = base + i;
        if (idx < n) { rs[idx] = run; cur[idx] = run; run += cnt[idx]; }
    }
    if (t == 0) rs[n] = E;
}
__global__ void __launch_bounds__(256) fill_kernel(const int* __restrict__ src,
                                                   const int* __restrict__ dst,
                                                   const float* __restrict__ esc,
                                                   int* __restrict__ cur,
                                                   int* __restrict__ csrc,
                                                   float* __restrict__ cesc, int E)
{
    int e = blockIdx.x * 256 + threadIdx.x;
    if (e >= E) return;
    int pos = atomicAdd(&cur[dst[e]], 1);
    csrc[pos] = src[e];
    cesc[pos] = esc[e];
}
__global__ void __launch_bounds__(256) dinv_kernel(const int* __restrict__ cnt,
                                                   float* __restrict__ dinv, int n)
{
    int t = blockIdx.x * 256 + threadIdx.x;
    if (t < n) dinv[t] = rsqrtf((float)cnt[t] + 1.0f);
}

// ---- MFMA GEMM: C[n,64] = [x(240)|nodeF(16)] @ W[256,64] ----
// Block: 4 waves x 32 nodes = 128 nodes; each wave does 32 nodes x 64 cols.
// W packed once to LDS as bf16 hi/lo pairs (64 KB). Split-bf16 3-chain.
__global__ void __launch_bounds__(256, 2) gemmX_mfma_kernel(
    const float* __restrict__ x, const float* __restrict__ nodeF,
    const float* __restrict__ W, float* __restrict__ C, int n)
{
    __shared__ unsigned sWhi[128 * 64];  // pk(W[2k][c], W[2k+1][c])
    __shared__ unsigned sWlo[128 * 64];
    const int tid = threadIdx.x;
    for (int i = tid; i < 128 * 64; i += 256) {
        const int kk2 = i >> 6, c = i & 63;
        float a = W[kk2 * 128 + c];
        float b = W[kk2 * 128 + 64 + c];
        sWhi[i] = pk_hi(a, b);
        sWlo[i] = pk_hi(lo_res(a), lo_res(b));
    }
    __syncthreads();

    const int lane = tid & 63;
    const int col  = lane & 31;
    const int hi   = lane >> 5;
    const int wv   = tid >> 6;
    const int nodeBase = blockIdx.x * 128 + wv * 32;
    const int nodeL = nodeBase + col;
    const int nc = nodeL < n ? nodeL : n - 1;

    const f32x16 zc = {0.f, 0.f, 0.f, 0.f, 0.f, 0.f, 0.f, 0.f,
                       0.f, 0.f, 0.f, 0.f, 0.f, 0.f, 0.f, 0.f};
    f32x16 acc0 = zc, acc1 = zc;
    const float* xrow = x + (size_t)nc * 240;
    const float* frow = nodeF + (size_t)nc * 16;

#pragma unroll 1
    for (int ch = 0; ch < 16; ++ch) {
        const float* src = (ch < 15) ? (xrow + ch * 16 + hi * 8) : (frow + hi * 8);
        float4 v0 = *(const float4*)src;
        float4 v1 = *(const float4*)(src + 4);
        S8U xh, xl;
        xh.u[0] = pk_hi(v0.x, v0.y);
        xh.u[1] = pk_hi(v0.z, v0.w);
        xh.u[2] = pk_hi(v1.x, v1.y);
        xh.u[3] = pk_hi(v1.z, v1.w);
        xl.u[0] = pk_hi(lo_res(v0.x), lo_res(v0.y));
        xl.u[1] = pk_hi(lo_res(v0.z), lo_res(v0.w));
        xl.u[2] = pk_hi(lo_res(v1.x), lo_res(v1.y));
        xl.u[3] = pk_hi(lo_res(v1.z), lo_res(v1.w));

        const int rbase = (ch * 8 + hi * 4) * 64 + col;
        S8U wh0, wl0, wh1, wl1;
#pragma unroll
        for (int r = 0; r < 4; ++r) {
            wh0.u[r] = sWhi[rbase + r * 64];
            wl0.u[r] = sWlo[rbase + r * 64];
            wh1.u[r] = sWhi[rbase + r * 64 + 32];
            wl1.u[r] = sWlo[rbase + r * 64 + 32];
        }
        acc0 = __builtin_amdgcn_mfma_f32_32x32x16_bf16(xh.v, wh0.v, acc0, 0, 0, 0);
        acc1 = __builtin_amdgcn_mfma_f32_32x32x16_bf16(xh.v, wh1.v, acc1, 0, 0, 0);
        acc0 = __builtin_amdgcn_mfma_f32_32x32x16_bf16(xl.v, wh0.v, acc0, 0, 0, 0);
        acc1 = __builtin_amdgcn_mfma_f32_32x32x16_bf16(xl.v, wh1.v, acc1, 0, 0, 0);
        acc0 = __builtin_amdgcn_mfma_f32_32x32x16_bf16(xh.v, wl0.v, acc0, 0, 0, 0);
        acc1 = __builtin_amdgcn_mfma_f32_32x32x16_bf16(xh.v, wl1.v, acc1, 0, 0, 0);
    }

#pragma unroll
    for (int r = 0; r < 16; ++r) {
        const int nr = (r & 3) + 8 * (r >> 2) + 4 * hi;
        const int nd = nodeBase + nr;
        if (nd < n) {
            C[(size_t)nd * 64 + col]      = acc0[r];
            C[(size_t)nd * 64 + 32 + col] = acc1[r];
        }
    }
}

// ---- MFMA GEMM: C[n,64] = A[n,64] @ W[64,64] (K=64, 4 chunks) ----
__global__ void __launch_bounds__(256, 2) gemm64_mfma_kernel(
    const float* __restrict__ A, const float* __restrict__ W,
    float* __restrict__ C, int n)
{
    __shared__ unsigned sWhi[32 * 64];
    __shared__ unsigned sWlo[32 * 64];
    const int tid = threadIdx.x;
    for (int i = tid; i < 32 * 64; i += 256) {
        const int kk2 = i >> 6, c = i & 63;
        float a = W[kk2 * 128 + c];
        float b = W[kk2 * 128 + 64 + c];
        sWhi[i] = pk_hi(a, b);
        sWlo[i] = pk_hi(lo_res(a), lo_res(b));
    }
    __syncthreads();

    const int lane = tid & 63;
    const int col  = lane & 31;
    const int hi   = lane >> 5;
    const int wv   = tid >> 6;
    const int nodeBase = blockIdx.x * 128 + wv * 32;
    const int nodeL = nodeBase + col;
    const int nc = nodeL < n ? nodeL : n - 1;

    const f32x16 zc = {0.f, 0.f, 0.f, 0.f, 0.f, 0.f, 0.f, 0.f,
                       0.f, 0.f, 0.f, 0.f, 0.f, 0.f, 0.f, 0.f};
    f32x16 acc0 = zc, acc1 = zc;
    const float* arow = A + (size_t)nc * 64;

#pragma unroll
    for (int ch = 0; ch < 4; ++ch) {
        const float* src = arow + ch * 16 + hi * 8;
        float4 v0 = *(const float4*)src;
        float4 v1 = *(const float4*)(src + 4);
        S8U xh, xl;
        xh.u[0] = pk_hi(v0.x, v0.y);
        xh.u[1] = pk_hi(v0.z, v0.w);
        xh.u[2] = pk_hi(v1.x, v1.y);
        xh.u[3] = pk_hi(v1.z, v1.w);
        xl.u[0] = pk_hi(lo_res(v0.x), lo_res(v0.y));
        xl.u[1] = pk_hi(lo_res(v0.z), lo_res(v0.w));
        xl.u[2] = pk_hi(lo_res(v1.x), lo_res(v1.y));
        xl.u[3] = pk_hi(lo_res(v1.z), lo_res(v1.w));

        const int rbase = (ch * 8 + hi * 4) * 64 + col;
        S8U wh0, wl0, wh1, wl1;
#pragma unroll
        for (int r = 0; r < 4; ++r) {
            wh0.u[r] = sWhi[rbase + r * 64];
            wl0.u[r] = sWlo[rbase + r * 64];
            wh1.u[r] = sWhi[rbase + r * 64 + 32];
            wl1.u[r] = sWlo[rbase + r * 64 + 32];
        }
        acc0 = __builtin_amdgcn_mfma_f32_32x32x16_bf16(xh.v, wh0.v, acc0, 0, 0, 0);
        acc1 = __builtin_amdgcn_mfma_f32_32x32x16_bf16(xh.v, wh1.v, acc1, 0, 0, 0);
        acc0 = __builtin_amdgcn_mfma_f32_32x32x16_bf16(xl.v, wh0.v, acc0, 0, 0, 0);
        acc1 = __builtin_amdgcn_mfma_f32_32x32x16_bf16(xl.v, wh1.v, acc1, 0, 0, 0);
        acc0 = __builtin_amdgcn_mfma_f32_32x32x16_bf16(xh.v, wl0.v, acc0, 0, 0, 0);
        acc1 = __builtin_amdgcn_mfma_f32_32x32x16_bf16(xh.v, wl1.v, acc1, 0, 0, 0);
    }

#pragma unroll
    for (int r = 0; r < 16; ++r) {
        const int nr = (r & 3) + 8 * (r >> 2) + 4 * hi;
        const int nd = nodeBase + nr;
        if (nd < n) {
            C[(size_t)nd * 64 + col]      = acc0[r];
            C[(size_t)nd * 64 + 32 + col] = acc1[r];
        }
    }
}

// ---------------- GAT ----------------
template <int H, int C>
__global__ void __launch_bounds__(256) alpha_kernel(const float* __restrict__ xh,
                                                    const float* __restrict__ att,
                                                    float* __restrict__ alpha, int n)
{
    int t = blockIdx.x * 256 + threadIdx.x;
    if (t >= n * H) return;
    int h = (H == 1) ? 0 : (t % H);
    int nd = (H == 1) ? t : (t / H);
    const float* row = xh + (size_t)nd * 64 + h * C;
    float s = 0.f;
#pragma unroll
    for (int c = 0; c < C; ++c) s += row[c] * att[h * C + c];
    alpha[t] = s;
}

// H=8 softmax, thread per dst row: 1 csrc read + 2 float4 alpha loads/edge.
__global__ void __launch_bounds__(256) gat_softmax8_row_kernel(
    const int* __restrict__ rs, const int* __restrict__ csrc,
    const float* __restrict__ alpha,
    float* __restrict__ amax, float* __restrict__ rinv, int n)
{
    int d = blockIdx.x * 256 + threadIdx.x;
    if (d >= n) return;
    int k0 = rs[d], k1 = rs[d + 1];
    float m[8];
#pragma unroll
    for (int h = 0; h < 8; ++h) m[h] = -INFINITY;
    for (int k = k0; k < k1; ++k) {
        const float4* ar = (const float4*)(alpha + (size_t)csrc[k] * 8);
        float4 a0 = ar[0], a1 = ar[1];
        float v[8] = {a0.x, a0.y, a0.z, a0.w, a1.x, a1.y, a1.z, a1.w};
#pragma unroll
        for (int h = 0; h < 8; ++h) {
            float a = v[h] > 0.f ? v[h] : 0.2f * v[h];
            m[h] = fmaxf(m[h], a);
        }
    }
    float sm[8];
#pragma unroll
    for (int h = 0; h < 8; ++h) sm[h] = 0.f;
    for (int k = k0; k < k1; ++k) {
        const float4* ar = (const float4*)(alpha + (size_t)csrc[k] * 8);
        float4 a0 = ar[0], a1 = ar[1];
        float v[8] = {a0.x, a0.y, a0.z, a0.w, a1.x, a1.y, a1.z, a1.w};
#pragma unroll
        for (int h = 0; h < 8; ++h) {
            float a = v[h] > 0.f ? v[h] : 0.2f * v[h];
            sm[h] += __expf(a - m[h]);
        }
    }
    float4* mo = (float4*)(amax + (size_t)d * 8);
    mo[0] = make_float4(m[0], m[1], m[2], m[3]);
    mo[1] = make_float4(m[4], m[5], m[6], m[7]);
    float4* ro = (float4*)(rinv + (size_t)d * 8);
    ro[0] = make_float4(rcpf(sm[0]), rcpf(sm[1]), rcpf(sm[2]), rcpf(sm[3]));
    ro[1] = make_float4(rcpf(sm[4]), rcpf(sm[5]), rcpf(sm[6]), rcpf(sm[7]));
}

// per (dst,h): max then sum over in-edges (CSR). Writes amax, rinv=1/sum.
template <int H>
__global__ void __launch_bounds__(256) gat_softmax_csr_kernel(
    const int* __restrict__ rs, const int* __restrict__ csrc,
    const float* __restrict__ alpha,
    float* __restrict__ amax, float* __restrict__ rinv, int n)
{
    int t = blockIdx.x * 256 + threadIdx.x;
    if (t >= n * H) return;
    int h = (H == 1) ? 0 : (t % H);
    int d = (H == 1) ? t : (t / H);
    int k0 = rs[d], k1 = rs[d + 1];
    float m = -INFINITY;
    for (int k = k0; k < k1; ++k) {
        float a = alpha[(size_t)csrc[k] * H + h];
        a = a > 0.f ? a : 0.2f * a;
        m = fmaxf(m, a);
    }
    float s = 0.f;
    for (int k = k0; k < k1; ++k) {
        float a = alpha[(size_t)csrc[k] * H + h];
        a = a > 0.f ? a : 0.2f * a;
        s += __expf(a - m);
    }
    amax[t] = m;
    rinv[t] = rcpf(s);
}

// one wave per dst node (lane = feature col). acc = xh[d]+bias + sum coef*xh[s].
template <int H, bool FILTER>
__global__ void __launch_bounds__(256) gat_gather_kernel(
    const int* __restrict__ rs, const int* __restrict__ csrc,
    const float* __restrict__ cesc,
    const float* __restrict__ xh, const float* __restrict__ alpha,
    const float* __restrict__ amax, const float* __restrict__ rinv,
    const float* __restrict__ bias, float* __restrict__ out, int n)
{
    int j = threadIdx.x & 63;
    int d = blockIdx.x * 4 + (threadIdx.x >> 6);
    if (d >= n) return;
    int h = (H == 8) ? (j >> 3) : 0;
    float m = amax[(size_t)d * H + h];
    float ri = rinv[(size_t)d * H + h];
    float acc = xh[(size_t)d * 64 + j] + bias[j];
    int k1 = rs[d + 1];
#pragma unroll 2
    for (int k = rs[d]; k < k1; ++k) {
        int s = csrc[k];
        float a = alpha[(size_t)s * H + h];
        a = a > 0.f ? a : 0.2f * a;
        float coef = __expf(a - m) * ri + cesc[k];
        acc += xh[(size_t)s * 64 + j] * coef;
    }
    if (FILTER && !__builtin_isfinite(acc)) acc = 0.f;
    out[(size_t)d * 64 + j] = acc;
}

// ---------------- GCN gather (norm + bias + leaky_relu fused) ----------------
__global__ void __launch_bounds__(256) gcn_gather_kernel(
    const int* __restrict__ rs, const int* __restrict__ csrc,
    const float* __restrict__ xw, const float* __restrict__ dinv,
    const float* __restrict__ bias, float* __restrict__ out, int n)
{
    int j = threadIdx.x & 63;
    int d = blockIdx.x * 4 + (threadIdx.x >> 6);
    if (d >= n) return;
    float di = dinv[d];
    float acc = xw[(size_t)d * 64 + j] * di * di + bias[j];
    int k1 = rs[d + 1];
#pragma unroll 2
    for (int k = rs[d]; k < k1; ++k) {
        int s = csrc[k];
        acc += xw[(size_t)s * 64 + j] * (dinv[s] * di);
    }
    out[(size_t)d * 64 + j] = acc > 0.f ? acc : 0.01f * acc;  // leaky_relu(0.01)
}

// ---------------- classifier (fused 320->32->16->4; 43.5KB static LDS) ---------
__global__ void __launch_bounds__(256) cls_kernel(
    const float* __restrict__ x, const float* __restrict__ nodeF,
    const float* __restrict__ xg,
    const float* __restrict__ W1, const float* __restrict__ b1,
    const float* __restrict__ W2, const float* __restrict__ b2,
    const float* __restrict__ W3, const float* __restrict__ b3,
    float* __restrict__ outp, int n)
{
    __shared__ float sW1[320 * 32];
    __shared__ float sW2[32 * 16];
    __shared__ float sW3[16 * 4];
    __shared__ float sb1[32], sb2[16], sb3[4];
    int tid = threadIdx.x;
    for (int i = tid; i < 320 * 32; i += 256) sW1[i] = W1[i];
    for (int i = tid; i < 512; i += 256) sW2[i] = W2[i];
    if (tid < 64) sW3[tid] = W3[tid];
    if (tid < 32) sb1[tid] = b1[tid];
    if (tid < 16) sb2[tid] = b2[tid];
    if (tid < 4)  sb3[tid] = b3[tid];
    __syncthreads();
    int nd = blockIdx.x * 256 + tid;
    if (nd >= n) return;

    float a1[32];
#pragma unroll
    for (int j = 0; j < 32; ++j) a1[j] = sb1[j];
    const float4* xr = (const float4*)(x + (size_t)nd * 240);
#pragma unroll 1
    for (int k4 = 0; k4 < 60; ++k4) {
        float4 v = xr[k4];
        const float* wr = sW1 + k4 * 128;
#pragma unroll
        for (int j = 0; j < 32; ++j)
            a1[j] += v.x * wr[j] + v.y * wr[32 + j] + v.z * wr[64 + j] + v.w * wr[96 + j];
    }
    const float4* nf = (const float4*)(nodeF + (size_t)nd * 16);
#pragma unroll 1
    for (int k4 = 60; k4 < 64; ++k4) {
        float4 v = nf[k4 - 60];
        const float* wr = sW1 + k4 * 128;
#pragma unroll
        for (int j = 0; j < 32; ++j)
            a1[j] += v.x * wr[j] + v.y * wr[32 + j] + v.z * wr[64 + j] + v.w * wr[96 + j];
    }
    const float4* p2 = (const float4*)(xg + (size_t)nd * 64);
#pragma unroll 1
    for (int k4 = 0; k4 < 16; ++k4) {
        float4 v = p2[k4];
        const float* wr = sW1 + 8192 + k4 * 128;  // rows 256 + 4*k4
#pragma unroll
        for (int j = 0; j < 32; ++j)
            a1[j] += v.x * wr[j] + v.y * wr[32 + j] + v.z * wr[64 + j] + v.w * wr[96 + j];
    }
#pragma unroll
    for (int j = 0; j < 32; ++j) { float v = a1[j]; a1[j] = v > 0.f ? v : 0.01f * v; }

    float a2[16];
#pragma unroll
    for (int j = 0; j < 16; ++j) a2[j] = sb2[j];
#pragma unroll
    for (int k = 0; k < 32; ++k) {
        float v = a1[k];
        const float* wr = sW2 + k * 16;
#pragma unroll
        for (int j = 0; j < 16; ++j) a2[j] += v * wr[j];
    }
#pragma unroll
    for (int j = 0; j < 16; ++j) { float v = a2[j]; a2[j] = v > 0.f ? v : 0.01f * v; }

    float a3[4] = {sb3[0], sb3[1], sb3[2], sb3[3]};
#pragma unroll
    for (int k = 0; k < 16; ++k) {
        float v = a2[k];
        const float* wr = sW3 + k * 4;
        a3[0] += v * wr[0]; a3[1] += v * wr[1]; a3[2] += v * wr[2]; a3[3] += v * wr[3];
    }
    float4 o = make_float4(a3[0], a3[1], a3[2], a3[3]);
    *(float4*)(outp + (size_t)nd * 4) = o;
}

// ---------------- launcher ----------------
static inline unsigned nblk(size_t t) { return (unsigned)((t + 255) / 256); }

extern "C" void kernel_launch(void* const* d_in, const int* in_sizes, int n_in,
                              void* d_out, int out_size, void* d_ws, size_t ws_size,
                              hipStream_t stream)
{
    const float* x     = (const float*)d_in[0];
    const float* eseq  = (const float*)d_in[1];
    const float* nseq  = (const float*)d_in[2];
    const float* Wih   = (const float*)d_in[3];
    const float* Whh   = (const float*)d_in[4];
    const float* lb    = (const float*)d_in[5];
    const float* dnnW  = (const float*)d_in[6];
    const float* dnnb  = (const float*)d_in[7];
    const float* g1W   = (const float*)d_in[8];
    const float* g1att = (const float*)d_in[9];
    const float* g1b   = (const float*)d_in[10];
    const float* g2W   = (const float*)d_in[11];
    const float* g2att = (const float*)d_in[12];
    const float* g2b   = (const float*)d_in[13];
    const float* gc1W  = (const float*)d_in[14];
    const float* gc1b  = (const float*)d_in[15];
    const float* gc2W  = (const float*)d_in[16];
    const float* gc2b  = (const float*)d_in[17];
    const float* c1W   = (const float*)d_in[18];
    const float* c1b   = (const float*)d_in[19];
    const float* c2W   = (const float*)d_in[20];
    const float* c2b   = (const float*)d_in[21];
    const float* c3W   = (const float*)d_in[22];
    const float* c3b   = (const float*)d_in[23];
    const int* eidx  = (const int*)d_in[24];
    const int* elen  = (const int*)d_in[25];
    const int* nlen  = (const int*)d_in[26];

    const int N = NN;
    const int E = EE;
    const int* srcp = eidx;
    const int* dstp = eidx + E;

    // device-global scratch
    float *nodeF, *esc, *P1, *P2, *alpha, *amax, *rinv, *dinv, *cesc;
    int *cnt, *rs, *cur, *csrc, *permN, *permE;
    hipGetSymbolAddress((void**)&nodeF, HIP_SYMBOL(g_nodeF));
    hipGetSymbolAddress((void**)&esc,   HIP_SYMBOL(g_esc));
    hipGetSymbolAddress((void**)&P1,    HIP_SYMBOL(g_P1));
    hipGetSymbolAddress((void**)&P2,    HIP_SYMBOL(g_P2));
    hipGetSymbolAddress((void**)&alpha, HIP_SYMBOL(g_alpha));
    hipGetSymbolAddress((void**)&amax,  HIP_SYMBOL(g_amax));
    hipGetSymbolAddress((void**)&rinv,  HIP_SYMBOL(g_rinv));
    hipGetSymbolAddress((void**)&dinv,  HIP_SYMBOL(g_dinv));
    hipGetSymbolAddress((void**)&cnt,   HIP_SYMBOL(g_cnt));
    hipGetSymbolAddress((void**)&rs,    HIP_SYMBOL(g_rs));
    hipGetSymbolAddress((void**)&cur,   HIP_SYMBOL(g_cur));
    hipGetSymbolAddress((void**)&csrc,  HIP_SYMBOL(g_csrc));
    hipGetSymbolAddress((void**)&cesc,  HIP_SYMBOL(g_cesc));
    hipGetSymbolAddress((void**)&permN, HIP_SYMBOL(g_permN));
    hipGetSymbolAddress((void**)&permE, HIP_SYMBOL(g_permE));

    float* out0   = (float*)d_out;             // [N,4]
    float* outGcn = out0 + (size_t)N * 4;      // [N,64]
    float* outGat = outGcn + (size_t)N * 64;   // [N,64]

    // ---- length bucketing (also zeroes cnt for CSR) ----
    zero_cnt_kernel<<<nblk(N), 256, 0, stream>>>(cnt, N);
    bucket_hist_kernel<<<nblk(NN + EE), 256, 0, stream>>>(nlen, elen);
    bucket_scan_kernel<<<1, 64, 0, stream>>>();
    bucket_scatter_kernel<<<nblk(NN + EE), 256, 0, stream>>>(nlen, elen);

    // ---- temporal branches (node + edge fused; 32 seqs/wave, bf16 MFMA) ----
    const int nNodeBlk = (N + 127) / 128;        // 391
    const int nEdgeBlk = (E + 127) / 128;        // 3125
    lstm_fused_kernel<<<nNodeBlk + nEdgeBlk, 256, 0, stream>>>(
        nseq, nlen, eseq, elen, Wih, Whh, lb, dnnW, dnnb, permN, permE,
        nodeF, esc, nNodeBlk);

    // ---- CSR build (graph fixed per launch; also yields GCN degrees) ----
    count_kernel<<<nblk(E), 256, 0, stream>>>(dstp, cnt, E);
    scan_kernel<<<1, 1024, 0, stream>>>(cnt, rs, cur, N, E);
    fill_kernel<<<nblk(E), 256, 0, stream>>>(srcp, dstp, esc, cur, csrc, cesc, E);
    dinv_kernel<<<nblk(N), 256, 0, stream>>>(cnt, dinv, N);

    const unsigned gemmBlk = (N + 127) / 128;

    // ---- GAT layer 1 (H=8, C=8): P1 = xh1, P2 = gat1 out ----
    gemmX_mfma_kernel<<<gemmBlk, 256, 0, stream>>>(x, nodeF, g1W, P1, N);
    alpha_kernel<8, 8><<<nblk((size_t)N * 8), 256, 0, stream>>>(P1, g1att, alpha, N);
    gat_softmax8_row_kernel<<<nblk(N), 256, 0, stream>>>(rs, csrc, alpha, amax, rinv, N);
    gat_gather_kernel<8, false><<<(N + 3) / 4, 256, 0, stream>>>(
        rs, csrc, cesc, P1, alpha, amax, rinv, g1b, P2, N);

    // ---- GAT layer 2 (H=1, C=64): P1 = xh2, output -> outGat ----
    gemm64_mfma_kernel<<<gemmBlk, 256, 0, stream>>>(P2, g2W, P1, N);
    alpha_kernel<1, 64><<<nblk(N), 256, 0, stream>>>(P1, g2att, alpha, N);
    gat_softmax_csr_kernel<1><<<nblk(N), 256, 0, stream>>>(rs, csrc, alpha, amax, rinv, N);
    gat_gather_kernel<1, true><<<(N + 3) / 4, 256, 0, stream>>>(
        rs, csrc, cesc, P1, alpha, amax, rinv, g2b, outGat, N);

    // ---- GCN layer 1: P1 = xw1, P2 = lrelu(gcn1) ----
    gemmX_mfma_kernel<<<gemmBlk, 256, 0, stream>>>(x, nodeF, gc1W, P1, N);
    gcn_gather_kernel<<<(N + 3) / 4, 256, 0, stream>>>(rs, csrc, P1, dinv, gc1b, P2, N);

    // ---- GCN layer 2: P1 = xw2, output -> outGcn (x_gcn, lrelu fused) ----
    gemm64_mfma_kernel<<<gemmBlk, 256, 0, stream>>>(P2, gc2W, P1, N);
    gcn_gather_kernel<<<(N + 3) / 4, 256, 0, stream>>>(rs, csrc, P1, dinv, gc2b, outGcn, N);

    // ---- classifier (reads x_gcn from d_out) ----
    cls_kernel<<<nblk(N), 256, 0, stream>>>(x, nodeF, outGcn, c1W, c1b, c2W, c2b, c3W, c3b, out0, N);
}

// Round 5
// 628.878 us; speedup vs baseline: 2.4210x; 1.2015x over previous
//
#include <hip/hip_runtime.h>
#include <hip/hip_bf16.h>

// TTAGN: LSTM(edge,node) -> GAT x2 + GCN x2 -> classifier.
// Inputs fp32, internal fp32, OUTPUT fp32.
// d_out = concat(out[N,4], x_gcn[N,64], x_gat[N,64]) as fp32.
// Scratch in __device__ globals.
//
// R15: hierarchical CSR scan. R14's single-block scan_kernel was 133us at
// 0.15% occupancy (thread0 serially walking 1024 partials + 49 strided
// serial loads/thread). Now: scan1 (196 blk tree-reduce) -> scan2 (1 blk
// Hillis-Steele over 196 sums) -> scan3 (local H-S scan + offset, writes
// rs/cur and FUSES dinv). ~20us total, dinv_kernel launch dropped.
// MFMA GEMMs (R14), MFMA LSTM + bucketing (R12/13) unchanged.

typedef unsigned int u32;

#define NN 50000
#define EE 400000

__device__ float g_nodeF[NN * 16];
__device__ float g_esc[EE];
__device__ float g_P1[NN * 64];
__device__ float g_P2[NN * 64];
__device__ float g_alpha[NN * 8];
__device__ float g_amax[NN * 8];
__device__ float g_rinv[NN * 8];
__device__ float g_dinv[NN];
__device__ int   g_cnt[NN];
__device__ int   g_rs[NN + 1];
__device__ int   g_cur[NN];
__device__ int   g_csrc[EE];
__device__ float g_cesc[EE];
__device__ int   g_bhist[32];   // [0..15] node bins (bin=16-len), [16..31] edge
__device__ int   g_bbase[32];   // exclusive bases -> rolling cursors
__device__ int   g_permN[NN];
__device__ int   g_permE[EE];
__device__ int   g_bsum[256];   // per-block sums for hierarchical scan
__device__ int   g_boff[256];   // exclusive block offsets

__device__ __forceinline__ float rcpf(float x) { return __builtin_amdgcn_rcpf(x); }
__device__ __forceinline__ float sigf(float x) { return rcpf(1.0f + __expf(-x)); }
__device__ __forceinline__ float tanh_fast(float x) {
    return 1.0f - 2.0f * rcpf(__expf(2.0f * x) + 1.0f);
}

// ---------------- bf16 MFMA helpers (split precision) ----------------
typedef short short8 __attribute__((ext_vector_type(8)));
typedef float f32x16 __attribute__((ext_vector_type(16)));

union S8U { short8 v; unsigned u[4]; };

// pack two floats as bf16 pair (truncation; lo-chains compensate the error)
__device__ __forceinline__ unsigned pk_hi(float a, float b) {
    return (__float_as_uint(a) >> 16) | (__float_as_uint(b) & 0xFFFF0000u);
}
__device__ __forceinline__ float bftrunc(float a) {
    return __uint_as_float(__float_as_uint(a) & 0xFFFF0000u);
}
__device__ __forceinline__ float lo_res(float a) { return a - bftrunc(a); }
__device__ __forceinline__ unsigned sx32(unsigned v) {
    return (unsigned)__shfl_xor((int)v, 32, 64);
}

// ---------------- length bucketing (counting sort, descending) -------------
__global__ void __launch_bounds__(256) bucket_hist_kernel(
    const int* __restrict__ nlen, const int* __restrict__ elen)
{
    __shared__ int hb[32];
    int t = threadIdx.x;
    if (t < 32) hb[t] = 0;
    __syncthreads();
    int i = blockIdx.x * 256 + t;
    int bin = -1;
    if (i < NN + EE) {
        bin = (i < NN) ? (16 - nlen[i]) : (32 - elen[i - NN]);
    }
    if (bin >= 0) atomicAdd(&hb[bin], 1);
    __syncthreads();
    if (t < 32 && hb[t] > 0) atomicAdd(&g_bhist[t], hb[t]);
}

__global__ void __launch_bounds__(64) bucket_scan_kernel()
{
    if (threadIdx.x == 0) {
        int acc = 0;
        for (int b = 0; b < 16; ++b) { g_bbase[b] = acc; acc += g_bhist[b]; }
        acc = 0;
        for (int b = 16; b < 32; ++b) { g_bbase[b] = acc; acc += g_bhist[b]; }
    }
}

__global__ void __launch_bounds__(256) bucket_scatter_kernel(
    const int* __restrict__ nlen, const int* __restrict__ elen)
{
    __shared__ int hb[32];
    int t = threadIdx.x;
    if (t < 32) hb[t] = 0;
    __syncthreads();
    int i = blockIdx.x * 256 + t;
    int bin = -1, idx = 0;
    if (i < NN + EE) {
        if (i < NN) { idx = i; bin = 16 - nlen[i]; }
        else        { idx = i - NN; bin = 32 - elen[i - NN]; }
    }
    if (bin >= 0) atomicAdd(&hb[bin], 1);
    __syncthreads();
    if (t < 32) {
        int c = hb[t];
        hb[t] = c > 0 ? atomicAdd(&g_bbase[t], c) : 0;
    }
    __syncthreads();
    if (bin >= 0) {
        int pos = atomicAdd(&hb[bin], 1);
        if (i < NN) g_permN[pos] = idx; else g_permE[pos] = idx;
    }
}

// One wave = 32 sequences (lanes l and l+32 share seq col=l&31).
// Lane (col,hi) owns units U[j] = (j&3) + 8*(j>>2) + 4*hi, j=0..7, of its seq.
// Block = 256 threads = 4 independent waves = 128 seqs (perm-bucketed).
__global__ void __launch_bounds__(256, 3) lstm_fused_kernel(
    const float* __restrict__ nseq, const int* __restrict__ nlen,
    const float* __restrict__ eseq, const int* __restrict__ elen,
    const float* __restrict__ Wih, const float* __restrict__ Whh,
    const float* __restrict__ bias,
    const float* __restrict__ dnnW, const float* __restrict__ dnnb,
    const int* __restrict__ permN, const int* __restrict__ permE,
    float* __restrict__ nodeF, float* __restrict__ esc, int nNodeBlk)
{
    const int lane = threadIdx.x & 63;
    const int col  = lane & 31;
    const int hi   = lane >> 5;
    const bool isLo = (hi == 0);
    const int wave = threadIdx.x >> 6;

    const bool edgeMode = (int)blockIdx.x >= nNodeBlk;
    const float* seq = edgeMode ? eseq : nseq;
    const int*  lens = edgeMode ? elen : nlen;
    const int*  perm = edgeMode ? permE : permN;
    const int limit  = edgeMode ? EE : NN;
    const int bbase  = edgeMode ? ((int)blockIdx.x - nNodeBlk) : (int)blockIdx.x;
    const int g  = bbase * 128 + wave * 32 + col;
    const int gc = g < limit ? g : limit - 1;
    const int s  = perm[gc];                 // actual sequence index
    const bool valid = g < limit;

    // ---- A fragments. Layout: lane(row=col [+32 tile1], k=8*hi+j, j=0..7).
    const int row0 = col, row1 = col + 32;
    const int ko = hi * 8;
    S8U ahh0, ahh1, ahl0, ahl1, ax0, ax1;
    {
        const float* w0 = Whh + row0 * 16 + ko;
        const float* w1 = Whh + row1 * 16 + ko;
#pragma unroll
        for (int r = 0; r < 4; ++r) {
            float a0 = w0[2 * r], b0 = w0[2 * r + 1];
            float a1 = w1[2 * r], b1 = w1[2 * r + 1];
            ahh0.u[r] = pk_hi(a0, b0);
            ahh1.u[r] = pk_hi(a1, b1);
            ahl0.u[r] = pk_hi(lo_res(a0), lo_res(b0));
            ahl1.u[r] = pk_hi(lo_res(a1), lo_res(b1));
        }
        // x-chain A (k slots, lo lanes only; hi lanes all-zero):
        // k0,k1=Wih_hi ; k2=bias_hi ; k3,k4=Wih_hi (for x_lo) ;
        // k5,k6=Wih_lo ; k7=bias_lo
#pragma unroll
        for (int r = 0; r < 4; ++r) { ax0.u[r] = 0u; ax1.u[r] = 0u; }
        if (isLo) {
            float wa0 = Wih[row0 * 2], wb0 = Wih[row0 * 2 + 1], bb0 = bias[row0];
            float wa1 = Wih[row1 * 2], wb1 = Wih[row1 * 2 + 1], bb1 = bias[row1];
            ax0.u[0] = pk_hi(wa0, wb0);
            ax0.u[1] = pk_hi(bb0, wa0);
            ax0.u[2] = pk_hi(wb0, lo_res(wa0));
            ax0.u[3] = pk_hi(lo_res(wb0), lo_res(bb0));
            ax1.u[0] = pk_hi(wa1, wb1);
            ax1.u[1] = pk_hi(bb1, wa1);
            ax1.u[2] = pk_hi(wb1, lo_res(wa1));
            ax1.u[3] = pk_hi(lo_res(wb1), lo_res(bb1));
        }
    }

    const f32x16 zc = {0.f, 0.f, 0.f, 0.f, 0.f, 0.f, 0.f, 0.f,
                       0.f, 0.f, 0.f, 0.f, 0.f, 0.f, 0.f, 0.f};
    const unsigned bxmask = isLo ? 0xFFFFFFFFu : 0u;
    const unsigned one_bf = 0x3F80u;  // bf16(1.0) in low half

    float cst[8], hlast[8];
#pragma unroll
    for (int j = 0; j < 8; ++j) { cst[j] = 0.f; hlast[j] = 0.f; }
    unsigned ph[4], pl[4];  // packed h (hi/lo), own units
#pragma unroll
    for (int r = 0; r < 4; ++r) { ph[r] = 0u; pl[r] = 0u; }

    const float4* sp = (const float4*)seq + (size_t)s * 8;  // 32 floats/seq
    const int lenm1 = lens[s] - 1;                          // in [0,15]
    // wave-max length -> float4 iterations needed (bucketed => ~uniform)
    int lm = lenm1;
#pragma unroll
    for (int off = 32; off >= 1; off >>= 1) {
        int o = __shfl_xor(lm, off, 64);
        lm = lm > o ? lm : o;
    }
    const int nIter = (lm >> 1) + 1;   // in [1,8]

    float4 q = sp[0];
#pragma unroll 1
    for (int i = 0; i < nIter; ++i) {
        float4 qn = sp[(i + 1) & 7];  // prefetch (wraps; always in-bounds)
#pragma unroll
        for (int hf = 0; hf < 2; ++hf) {
            const int t = 2 * i + hf;
            const float x0 = hf ? q.z : q.x;
            const float x1 = hf ? q.w : q.y;

            // B h-fragments: B[k=8*hi+j][col]; exchange halves via shfl.
            S8U bhh, bhl, bx;
            {
                unsigned t0 = sx32(ph[0]), t1 = sx32(ph[1]);
                unsigned t2 = sx32(ph[2]), t3 = sx32(ph[3]);
                bhh.u[0] = isLo ? ph[0] : t2;
                bhh.u[1] = isLo ? ph[1] : t3;
                bhh.u[2] = isLo ? t0 : ph[2];
                bhh.u[3] = isLo ? t1 : ph[3];
                unsigned s0 = sx32(pl[0]), s1 = sx32(pl[1]);
                unsigned s2 = sx32(pl[2]), s3 = sx32(pl[3]);
                bhl.u[0] = isLo ? pl[0] : s2;
                bhl.u[1] = isLo ? pl[1] : s3;
                bhl.u[2] = isLo ? s0 : pl[2];
                bhl.u[3] = isLo ? s1 : pl[3];
            }
            // B x-fragment: k0,k1=x_hi ; k2=1 ; k3,k4=x_lo ; k5,k6=x_hi ; k7=1
            {
                float xl0 = lo_res(x0), xl1 = lo_res(x1);
                bx.u[0] = pk_hi(x0, x1) & bxmask;
                bx.u[1] = (one_bf | (__float_as_uint(xl0) & 0xFFFF0000u)) & bxmask;
                bx.u[2] = pk_hi(xl1, x0) & bxmask;
                bx.u[3] = ((__float_as_uint(x1) >> 16) | (one_bf << 16)) & bxmask;
            }

            f32x16 d0 = __builtin_amdgcn_mfma_f32_32x32x16_bf16(ax0.v, bx.v, zc, 0, 0, 0);
            f32x16 d1 = __builtin_amdgcn_mfma_f32_32x32x16_bf16(ax1.v, bx.v, zc, 0, 0, 0);
            d0 = __builtin_amdgcn_mfma_f32_32x32x16_bf16(ahh0.v, bhh.v, d0, 0, 0, 0);
            d1 = __builtin_amdgcn_mfma_f32_32x32x16_bf16(ahh1.v, bhh.v, d1, 0, 0, 0);
            d0 = __builtin_amdgcn_mfma_f32_32x32x16_bf16(ahl0.v, bhh.v, d0, 0, 0, 0);
            d1 = __builtin_amdgcn_mfma_f32_32x32x16_bf16(ahl1.v, bhh.v, d1, 0, 0, 0);
            d0 = __builtin_amdgcn_mfma_f32_32x32x16_bf16(ahh0.v, bhl.v, d0, 0, 0, 0);
            d1 = __builtin_amdgcn_mfma_f32_32x32x16_bf16(ahh1.v, bhl.v, d1, 0, 0, 0);

            // d0[j]=i_U[j], d0[8+j]=f_U[j], d1[j]=g_U[j], d1[8+j]=o_U[j]
            float hh[8];
#pragma unroll
            for (int j = 0; j < 8; ++j) {
                float ip = d0[j], fp = d0[8 + j], gp = d1[j], op = d1[8 + j];
                float cu = sigf(fp) * cst[j] + sigf(ip) * tanh_fast(gp);
                cst[j] = cu;
                hh[j] = sigf(op) * tanh_fast(cu);
            }
            const bool selm = (t == lenm1);
#pragma unroll
            for (int j = 0; j < 8; ++j) hlast[j] = selm ? hh[j] : hlast[j];
            // repack h (hi + lo residual)
#pragma unroll
            for (int r = 0; r < 4; ++r) {
                float a = hh[2 * r], b = hh[2 * r + 1];
                ph[r] = pk_hi(a, b);
                pl[r] = pk_hi(lo_res(a), lo_res(b));
            }
        }
        q = qn;
    }

    if (edgeMode) {
        // esc[s] = dot(h16, dnnW) + dnnb ; lane holds units {0..3,8..11}+4*hi
        float4 dA = *(const float4*)(dnnW + hi * 4);
        float4 dB = *(const float4*)(dnnW + hi * 4 + 8);
        float part = hlast[0] * dA.x + hlast[1] * dA.y + hlast[2] * dA.z + hlast[3] * dA.w
                   + hlast[4] * dB.x + hlast[5] * dB.y + hlast[6] * dB.z + hlast[7] * dB.w;
        float tot = part + __shfl_xor(part, 32, 64);
        if (isLo && valid) esc[s] = tot + dnnb[0];
    } else {
        if (valid) {
            float* dst = nodeF + (size_t)s * 16 + hi * 4;
            *(float4*)(dst)     = make_float4(hlast[0], hlast[1], hlast[2], hlast[3]);
            *(float4*)(dst + 8) = make_float4(hlast[4], hlast[5], hlast[6], hlast[7]);
        }
    }
}

// ---------------- CSR build ----------------
__global__ void __launch_bounds__(256) zero_cnt_kernel(int* cnt, int n)
{
    int t = blockIdx.x * 256 + threadIdx.x;
    if (t < n) cnt[t] = 0;
    if (blockIdx.x == 0 && threadIdx.x < 32) g_bhist[threadIdx.x] = 0;
}
__global__ void __launch_bounds__(256) count_kernel(const int* __restrict__ dst,
                                                    int* cnt, int E)
{
    int e = blockIdx.x * 256 + threadIdx.x;
    if (e < E) atomicAdd(&cnt[dst[e]], 1);
}

// hierarchical scan, stage 1: per-block (256-wide) tree reduction.
__global__ void __launch_bounds__(256) scan1_kernel(const int* __restrict__ cnt, int n)
{
    __shared__ int s[256];
    int t = threadIdx.x;
    int i = blockIdx.x * 256 + t;
    s[t] = (i < n) ? cnt[i] : 0;
    __syncthreads();
#pragma unroll
    for (int off = 128; off >= 1; off >>= 1) {
        if (t < off) s[t] += s[t + off];
        __syncthreads();
    }
    if (t == 0) g_bsum[blockIdx.x] = s[0];
}

// stage 2: single block Hillis-Steele exclusive scan over nb block sums.
__global__ void __launch_bounds__(256) scan2_kernel(int nb)
{
    __shared__ int s[256];
    int t = threadIdx.x;
    int v = (t < nb) ? g_bsum[t] : 0;
    s[t] = v;
    __syncthreads();
#pragma unroll
    for (int off = 1; off < 256; off <<= 1) {
        int add = (t >= off) ? s[t - off] : 0;
        __syncthreads();
        s[t] += add;
        __syncthreads();
    }
    if (t < nb) g_boff[t] = s[t] - v;   // exclusive
}

// stage 3: local Hillis-Steele exclusive scan + block offset; writes rs, cur,
// and fused dinv.
__global__ void __launch_bounds__(256) scan3_kernel(
    const int* __restrict__ cnt, int* __restrict__ rs, int* __restrict__ cur,
    float* __restrict__ dinv, int n, int E)
{
    __shared__ int s[256];
    int t = threadIdx.x;
    int i = blockIdx.x * 256 + t;
    int v = (i < n) ? cnt[i] : 0;
    s[t] = v;
    __syncthreads();
#pragma unroll
    for (int off = 1; off < 256; off <<= 1) {
        int add = (t >= off) ? s[t - off] : 0;
        __syncthreads();
        s[t] += add;
        __syncthreads();
    }
    if (i < n) {
        int excl = s[t] - v + g_boff[blockIdx.x];
        rs[i] = excl;
        cur[i] = excl;
        dinv[i] = rsqrtf((float)v + 1.0f);
    }
    if (i == 0) rs[n] = E;
}

__global__ void __launch_bounds__(256) fill_kernel(const int* __restrict__ src,
                                                   const int* __restrict__ dst,
                                                   const float* __restrict__ esc,
                                                   int* __restrict__ cur,
                                                   int* __restrict__ csrc,
                                                   float* __restrict__ cesc, int E)
{
    int e = blockIdx.x * 256 + threadIdx.x;
    if (e >= E) return;
    int pos = atomicAdd(&cur[dst[e]], 1);
    csrc[pos] = src[e];
    cesc[pos] = esc[e];
}

// ---- MFMA GEMM: C[n,64] = [x(240)|nodeF(16)] @ W[256,64] ----
// Block: 4 waves x 32 nodes = 128 nodes; each wave does 32 nodes x 64 cols.
// W packed once to LDS as bf16 hi/lo pairs (64 KB). Split-bf16 3-chain.
__global__ void __launch_bounds__(256, 2) gemmX_mfma_kernel(
    const float* __restrict__ x, const float* __restrict__ nodeF,
    const float* __restrict__ W, float* __restrict__ C, int n)
{
    __shared__ unsigned sWhi[128 * 64];  // pk(W[2k][c], W[2k+1][c])
    __shared__ unsigned sWlo[128 * 64];
    const int tid = threadIdx.x;
    for (int i = tid; i < 128 * 64; i += 256) {
        const int kk2 = i >> 6, c = i & 63;
        float a = W[kk2 * 128 + c];
        float b = W[kk2 * 128 + 64 + c];
        sWhi[i] = pk_hi(a, b);
        sWlo[i] = pk_hi(lo_res(a), lo_res(b));
    }
    __syncthreads();

    const int lane = tid & 63;
    const int col  = lane & 31;
    const int hi   = lane >> 5;
    const int wv   = tid >> 6;
    const int nodeBase = blockIdx.x * 128 + wv * 32;
    const int nodeL = nodeBase + col;
    const int nc = nodeL < n ? nodeL : n - 1;

    const f32x16 zc = {0.f, 0.f, 0.f, 0.f, 0.f, 0.f, 0.f, 0.f,
                       0.f, 0.f, 0.f, 0.f, 0.f, 0.f, 0.f, 0.f};
    f32x16 acc0 = zc, acc1 = zc;
    const float* xrow = x + (size_t)nc * 240;
    const float* frow = nodeF + (size_t)nc * 16;

#pragma unroll 1
    for (int ch = 0; ch < 16; ++ch) {
        const float* src = (ch < 15) ? (xrow + ch * 16 + hi * 8) : (frow + hi * 8);
        float4 v0 = *(const float4*)src;
        float4 v1 = *(const float4*)(src + 4);
        S8U xh, xl;
        xh.u[0] = pk_hi(v0.x, v0.y);
        xh.u[1] = pk_hi(v0.z, v0.w);
        xh.u[2] = pk_hi(v1.x, v1.y);
        xh.u[3] = pk_hi(v1.z, v1.w);
        xl.u[0] = pk_hi(lo_res(v0.x), lo_res(v0.y));
        xl.u[1] = pk_hi(lo_res(v0.z), lo_res(v0.w));
        xl.u[2] = pk_hi(lo_res(v1.x), lo_res(v1.y));
        xl.u[3] = pk_hi(lo_res(v1.z), lo_res(v1.w));

        const int rbase = (ch * 8 + hi * 4) * 64 + col;
        S8U wh0, wl0, wh1, wl1;
#pragma unroll
        for (int r = 0; r < 4; ++r) {
            wh0.u[r] = sWhi[rbase + r * 64];
            wl0.u[r] = sWlo[rbase + r * 64];
            wh1.u[r] = sWhi[rbase + r * 64 + 32];
            wl1.u[r] = sWlo[rbase + r * 64 + 32];
        }
        acc0 = __builtin_amdgcn_mfma_f32_32x32x16_bf16(xh.v, wh0.v, acc0, 0, 0, 0);
        acc1 = __builtin_amdgcn_mfma_f32_32x32x16_bf16(xh.v, wh1.v, acc1, 0, 0, 0);
        acc0 = __builtin_amdgcn_mfma_f32_32x32x16_bf16(xl.v, wh0.v, acc0, 0, 0, 0);
        acc1 = __builtin_amdgcn_mfma_f32_32x32x16_bf16(xl.v, wh1.v, acc1, 0, 0, 0);
        acc0 = __builtin_amdgcn_mfma_f32_32x32x16_bf16(xh.v, wl0.v, acc0, 0, 0, 0);
        acc1 = __builtin_amdgcn_mfma_f32_32x32x16_bf16(xh.v, wl1.v, acc1, 0, 0, 0);
    }

#pragma unroll
    for (int r = 0; r < 16; ++r) {
        const int nr = (r & 3) + 8 * (r >> 2) + 4 * hi;
        const int nd = nodeBase + nr;
        if (nd < n) {
            C[(size_t)nd * 64 + col]      = acc0[r];
            C[(size_t)nd * 64 + 32 + col] = acc1[r];
        }
    }
}

// ---- MFMA GEMM: C[n,64] = A[n,64] @ W[64,64] (K=64, 4 chunks) ----
__global__ void __launch_bounds__(256, 2) gemm64_mfma_kernel(
    const float* __restrict__ A, const float* __restrict__ W,
    float* __restrict__ C, int n)
{
    __shared__ unsigned sWhi[32 * 64];
    __shared__ unsigned sWlo[32 * 64];
    const int tid = threadIdx.x;
    for (int i = tid; i < 32 * 64; i += 256) {
        const int kk2 = i >> 6, c = i & 63;
        float a = W[kk2 * 128 + c];
        float b = W[kk2 * 128 + 64 + c];
        sWhi[i] = pk_hi(a, b);
        sWlo[i] = pk_hi(lo_res(a), lo_res(b));
    }
    __syncthreads();

    const int lane = tid & 63;
    const int col  = lane & 31;
    const int hi   = lane >> 5;
    const int wv   = tid >> 6;
    const int nodeBase = blockIdx.x * 128 + wv * 32;
    const int nodeL = nodeBase + col;
    const int nc = nodeL < n ? nodeL : n - 1;

    const f32x16 zc = {0.f, 0.f, 0.f, 0.f, 0.f, 0.f, 0.f, 0.f,
                       0.f, 0.f, 0.f, 0.f, 0.f, 0.f, 0.f, 0.f};
    f32x16 acc0 = zc, acc1 = zc;
    const float* arow = A + (size_t)nc * 64;

#pragma unroll
    for (int ch = 0; ch < 4; ++ch) {
        const float* src = arow + ch * 16 + hi * 8;
        float4 v0 = *(const float4*)src;
        float4 v1 = *(const float4*)(src + 4);
        S8U xh, xl;
        xh.u[0] = pk_hi(v0.x, v0.y);
        xh.u[1] = pk_hi(v0.z, v0.w);
        xh.u[2] = pk_hi(v1.x, v1.y);
        xh.u[3] = pk_hi(v1.z, v1.w);
        xl.u[0] = pk_hi(lo_res(v0.x), lo_res(v0.y));
        xl.u[1] = pk_hi(lo_res(v0.z), lo_res(v0.w));
        xl.u[2] = pk_hi(lo_res(v1.x), lo_res(v1.y));
        xl.u[3] = pk_hi(lo_res(v1.z), lo_res(v1.w));

        const int rbase = (ch * 8 + hi * 4) * 64 + col;
        S8U wh0, wl0, wh1, wl1;
#pragma unroll
        for (int r = 0; r < 4; ++r) {
            wh0.u[r] = sWhi[rbase + r * 64];
            wl0.u[r] = sWlo[rbase + r * 64];
            wh1.u[r] = sWhi[rbase + r * 64 + 32];
            wl1.u[r] = sWlo[rbase + r * 64 + 32];
        }
        acc0 = __builtin_amdgcn_mfma_f32_32x32x16_bf16(xh.v, wh0.v, acc0, 0, 0, 0);
        acc1 = __builtin_amdgcn_mfma_f32_32x32x16_bf16(xh.v, wh1.v, acc1, 0, 0, 0);
        acc0 = __builtin_amdgcn_mfma_f32_32x32x16_bf16(xl.v, wh0.v, acc0, 0, 0, 0);
        acc1 = __builtin_amdgcn_mfma_f32_32x32x16_bf16(xl.v, wh1.v, acc1, 0, 0, 0);
        acc0 = __builtin_amdgcn_mfma_f32_32x32x16_bf16(xh.v, wl0.v, acc0, 0, 0, 0);
        acc1 = __builtin_amdgcn_mfma_f32_32x32x16_bf16(xh.v, wl1.v, acc1, 0, 0, 0);
    }

#pragma unroll
    for (int r = 0; r < 16; ++r) {
        const int nr = (r & 3) + 8 * (r >> 2) + 4 * hi;
        const int nd = nodeBase + nr;
        if (nd < n) {
            C[(size_t)nd * 64 + col]      = acc0[r];
            C[(size_t)nd * 64 + 32 + col] = acc1[r];
        }
    }
}

// ---------------- GAT ----------------
template <int H, int C>
__global__ void __launch_bounds__(256) alpha_kernel(const float* __restrict__ xh,
                                                    const float* __restrict__ att,
                                                    float* __restrict__ alpha, int n)
{
    int t = blockIdx.x * 256 + threadIdx.x;
    if (t >= n * H) return;
    int h = (H == 1) ? 0 : (t % H);
    int nd = (H == 1) ? t : (t / H);
    const float* row = xh + (size_t)nd * 64 + h * C;
    float s = 0.f;
#pragma unroll
    for (int c = 0; c < C; ++c) s += row[c] * att[h * C + c];
    alpha[t] = s;
}

// H=8 softmax, thread per dst row: 1 csrc read + 2 float4 alpha loads/edge.
__global__ void __launch_bounds__(256) gat_softmax8_row_kernel(
    const int* __restrict__ rs, const int* __restrict__ csrc,
    const float* __restrict__ alpha,
    float* __restrict__ amax, float* __restrict__ rinv, int n)
{
    int d = blockIdx.x * 256 + threadIdx.x;
    if (d >= n) return;
    int k0 = rs[d], k1 = rs[d + 1];
    float m[8];
#pragma unroll
    for (int h = 0; h < 8; ++h) m[h] = -INFINITY;
    for (int k = k0; k < k1; ++k) {
        const float4* ar = (const float4*)(alpha + (size_t)csrc[k] * 8);
        float4 a0 = ar[0], a1 = ar[1];
        float v[8] = {a0.x, a0.y, a0.z, a0.w, a1.x, a1.y, a1.z, a1.w};
#pragma unroll
        for (int h = 0; h < 8; ++h) {
            float a = v[h] > 0.f ? v[h] : 0.2f * v[h];
            m[h] = fmaxf(m[h], a);
        }
    }
    float sm[8];
#pragma unroll
    for (int h = 0; h < 8; ++h) sm[h] = 0.f;
    for (int k = k0; k < k1; ++k) {
        const float4* ar = (const float4*)(alpha + (size_t)csrc[k] * 8);
        float4 a0 = ar[0], a1 = ar[1];
        float v[8] = {a0.x, a0.y, a0.z, a0.w, a1.x, a1.y, a1.z, a1.w};
#pragma unroll
        for (int h = 0; h < 8; ++h) {
            float a = v[h] > 0.f ? v[h] : 0.2f * v[h];
            sm[h] += __expf(a - m[h]);
        }
    }
    float4* mo = (float4*)(amax + (size_t)d * 8);
    mo[0] = make_float4(m[0], m[1], m[2], m[3]);
    mo[1] = make_float4(m[4], m[5], m[6], m[7]);
    float4* ro = (float4*)(rinv + (size_t)d * 8);
    ro[0] = make_float4(rcpf(sm[0]), rcpf(sm[1]), rcpf(sm[2]), rcpf(sm[3]));
    ro[1] = make_float4(rcpf(sm[4]), rcpf(sm[5]), rcpf(sm[6]), rcpf(sm[7]));
}

// per (dst,h): max then sum over in-edges (CSR). Writes amax, rinv=1/sum.
template <int H>
__global__ void __launch_bounds__(256) gat_softmax_csr_kernel(
    const int* __restrict__ rs, const int* __restrict__ csrc,
    const float* __restrict__ alpha,
    float* __restrict__ amax, float* __restrict__ rinv, int n)
{
    int t = blockIdx.x * 256 + threadIdx.x;
    if (t >= n * H) return;
    int h = (H == 1) ? 0 : (t % H);
    int d = (H == 1) ? t : (t / H);
    int k0 = rs[d], k1 = rs[d + 1];
    float m = -INFINITY;
    for (int k = k0; k < k1; ++k) {
        float a = alpha[(size_t)csrc[k] * H + h];
        a = a > 0.f ? a : 0.2f * a;
        m = fmaxf(m, a);
    }
    float s = 0.f;
    for (int k = k0; k < k1; ++k) {
        float a = alpha[(size_t)csrc[k] * H + h];
        a = a > 0.f ? a : 0.2f * a;
        s += __expf(a - m);
    }
    amax[t] = m;
    rinv[t] = rcpf(s);
}

// one wave per dst node (lane = feature col). acc = xh[d]+bias + sum coef*xh[s].
template <int H, bool FILTER>
__global__ void __launch_bounds__(256) gat_gather_kernel(
    const int* __restrict__ rs, const int* __restrict__ csrc,
    const float* __restrict__ cesc,
    const float* __restrict__ xh, const float* __restrict__ alpha,
    const float* __restrict__ amax, const float* __restrict__ rinv,
    const float* __restrict__ bias, float* __restrict__ out, int n)
{
    int j = threadIdx.x & 63;
    int d = blockIdx.x * 4 + (threadIdx.x >> 6);
    if (d >= n) return;
    int h = (H == 8) ? (j >> 3) : 0;
    float m = amax[(size_t)d * H + h];
    float ri = rinv[(size_t)d * H + h];
    float acc = xh[(size_t)d * 64 + j] + bias[j];
    int k1 = rs[d + 1];
#pragma unroll 2
    for (int k = rs[d]; k < k1; ++k) {
        int s = csrc[k];
        float a = alpha[(size_t)s * H + h];
        a = a > 0.f ? a : 0.2f * a;
        float coef = __expf(a - m) * ri + cesc[k];
        acc += xh[(size_t)s * 64 + j] * coef;
    }
    if (FILTER && !__builtin_isfinite(acc)) acc = 0.f;
    out[(size_t)d * 64 + j] = acc;
}

// ---------------- GCN gather (norm + bias + leaky_relu fused) ----------------
__global__ void __launch_bounds__(256) gcn_gather_kernel(
    const int* __restrict__ rs, const int* __restrict__ csrc,
    const float* __restrict__ xw, const float* __restrict__ dinv,
    const float* __restrict__ bias, float* __restrict__ out, int n)
{
    int j = threadIdx.x & 63;
    int d = blockIdx.x * 4 + (threadIdx.x >> 6);
    if (d >= n) return;
    float di = dinv[d];
    float acc = xw[(size_t)d * 64 + j] * di * di + bias[j];
    int k1 = rs[d + 1];
#pragma unroll 2
    for (int k = rs[d]; k < k1; ++k) {
        int s = csrc[k];
        acc += xw[(size_t)s * 64 + j] * (dinv[s] * di);
    }
    out[(size_t)d * 64 + j] = acc > 0.f ? acc : 0.01f * acc;  // leaky_relu(0.01)
}

// ---------------- classifier (fused 320->32->16->4; 43.5KB static LDS) ---------
__global__ void __launch_bounds__(256) cls_kernel(
    const float* __restrict__ x, const float* __restrict__ nodeF,
    const float* __restrict__ xg,
    const float* __restrict__ W1, const float* __restrict__ b1,
    const float* __restrict__ W2, const float* __restrict__ b2,
    const float* __restrict__ W3, const float* __restrict__ b3,
    float* __restrict__ outp, int n)
{
    __shared__ float sW1[320 * 32];
    __shared__ float sW2[32 * 16];
    __shared__ float sW3[16 * 4];
    __shared__ float sb1[32], sb2[16], sb3[4];
    int tid = threadIdx.x;
    for (int i = tid; i < 320 * 32; i += 256) sW1[i] = W1[i];
    for (int i = tid; i < 512; i += 256) sW2[i] = W2[i];
    if (tid < 64) sW3[tid] = W3[tid];
    if (tid < 32) sb1[tid] = b1[tid];
    if (tid < 16) sb2[tid] = b2[tid];
    if (tid < 4)  sb3[tid] = b3[tid];
    __syncthreads();
    int nd = blockIdx.x * 256 + tid;
    if (nd >= n) return;

    float a1[32];
#pragma unroll
    for (int j = 0; j < 32; ++j) a1[j] = sb1[j];
    const float4* xr = (const float4*)(x + (size_t)nd * 240);
#pragma unroll 1
    for (int k4 = 0; k4 < 60; ++k4) {
        float4 v = xr[k4];
        const float* wr = sW1 + k4 * 128;
#pragma unroll
        for (int j = 0; j < 32; ++j)
            a1[j] += v.x * wr[j] + v.y * wr[32 + j] + v.z * wr[64 + j] + v.w * wr[96 + j];
    }
    const float4* nf = (const float4*)(nodeF + (size_t)nd * 16);
#pragma unroll 1
    for (int k4 = 60; k4 < 64; ++k4) {
        float4 v = nf[k4 - 60];
        const float* wr = sW1 + k4 * 128;
#pragma unroll
        for (int j = 0; j < 32; ++j)
            a1[j] += v.x * wr[j] + v.y * wr[32 + j] + v.z * wr[64 + j] + v.w * wr[96 + j];
    }
    const float4* p2 = (const float4*)(xg + (size_t)nd * 64);
#pragma unroll 1
    for (int k4 = 0; k4 < 16; ++k4) {
        float4 v = p2[k4];
        const float* wr = sW1 + 8192 + k4 * 128;  // rows 256 + 4*k4
#pragma unroll
        for (int j = 0; j < 32; ++j)
            a1[j] += v.x * wr[j] + v.y * wr[32 + j] + v.z * wr[64 + j] + v.w * wr[96 + j];
    }
#pragma unroll
    for (int j = 0; j < 32; ++j) { float v = a1[j]; a1[j] = v > 0.f ? v : 0.01f * v; }

    float a2[16];
#pragma unroll
    for (int j = 0; j < 16; ++j) a2[j] = sb2[j];
#pragma unroll
    for (int k = 0; k < 32; ++k) {
        float v = a1[k];
        const float* wr = sW2 + k * 16;
#pragma unroll
        for (int j = 0; j < 16; ++j) a2[j] += v * wr[j];
    }
#pragma unroll
    for (int j = 0; j < 16; ++j) { float v = a2[j]; a2[j] = v > 0.f ? v : 0.01f * v; }

    float a3[4] = {sb3[0], sb3[1], sb3[2], sb3[3]};
#pragma unroll
    for (int k = 0; k < 16; ++k) {
        float v = a2[k];
        const float* wr = sW3 + k * 4;
        a3[0] += v * wr[0]; a3[1] += v * wr[1]; a3[2] += v * wr[2]; a3[3] += v * wr[3];
    }
    float4 o = make_float4(a3[0], a3[1], a3[2], a3[3]);
    *(float4*)(outp + (size_t)nd * 4) = o;
}

// ---------------- launcher ----------------
static inline unsigned nblk(size_t t) { return (unsigned)((t + 255) / 256); }

extern "C" void kernel_launch(void* const* d_in, const int* in_sizes, int n_in,
                              void* d_out, int out_size, void* d_ws, size_t ws_size,
                              hipStream_t stream)
{
    const float* x     = (const float*)d_in[0];
    const float* eseq  = (const float*)d_in[1];
    const float* nseq  = (const float*)d_in[2];
    const float* Wih   = (const float*)d_in[3];
    const float* Whh   = (const float*)d_in[4];
    const float* lb    = (const float*)d_in[5];
    const float* dnnW  = (const float*)d_in[6];
    const float* dnnb  = (const float*)d_in[7];
    const float* g1W   = (const float*)d_in[8];
    const float* g1att = (const float*)d_in[9];
    const float* g1b   = (const float*)d_in[10];
    const float* g2W   = (const float*)d_in[11];
    const float* g2att = (const float*)d_in[12];
    const float* g2b   = (const float*)d_in[13];
    const float* gc1W  = (const float*)d_in[14];
    const float* gc1b  = (const float*)d_in[15];
    const float* gc2W  = (const float*)d_in[16];
    const float* gc2b  = (const float*)d_in[17];
    const float* c1W   = (const float*)d_in[18];
    const float* c1b   = (const float*)d_in[19];
    const float* c2W   = (const float*)d_in[20];
    const float* c2b   = (const float*)d_in[21];
    const float* c3W   = (const float*)d_in[22];
    const float* c3b   = (const float*)d_in[23];
    const int* eidx  = (const int*)d_in[24];
    const int* elen  = (const int*)d_in[25];
    const int* nlen  = (const int*)d_in[26];

    const int N = NN;
    const int E = EE;
    const int* srcp = eidx;
    const int* dstp = eidx + E;

    // device-global scratch
    float *nodeF, *esc, *P1, *P2, *alpha, *amax, *rinv, *dinv, *cesc;
    int *cnt, *rs, *cur, *csrc, *permN, *permE;
    hipGetSymbolAddress((void**)&nodeF, HIP_SYMBOL(g_nodeF));
    hipGetSymbolAddress((void**)&esc,   HIP_SYMBOL(g_esc));
    hipGetSymbolAddress((void**)&P1,    HIP_SYMBOL(g_P1));
    hipGetSymbolAddress((void**)&P2,    HIP_SYMBOL(g_P2));
    hipGetSymbolAddress((void**)&alpha, HIP_SYMBOL(g_alpha));
    hipGetSymbolAddress((void**)&amax,  HIP_SYMBOL(g_amax));
    hipGetSymbolAddress((void**)&rinv,  HIP_SYMBOL(g_rinv));
    hipGetSymbolAddress((void**)&dinv,  HIP_SYMBOL(g_dinv));
    hipGetSymbolAddress((void**)&cnt,   HIP_SYMBOL(g_cnt));
    hipGetSymbolAddress((void**)&rs,    HIP_SYMBOL(g_rs));
    hipGetSymbolAddress((void**)&cur,   HIP_SYMBOL(g_cur));
    hipGetSymbolAddress((void**)&csrc,  HIP_SYMBOL(g_csrc));
    hipGetSymbolAddress((void**)&cesc,  HIP_SYMBOL(g_cesc));
    hipGetSymbolAddress((void**)&permN, HIP_SYMBOL(g_permN));
    hipGetSymbolAddress((void**)&permE, HIP_SYMBOL(g_permE));

    float* out0   = (float*)d_out;             // [N,4]
    float* outGcn = out0 + (size_t)N * 4;      // [N,64]
    float* outGat = outGcn + (size_t)N * 64;   // [N,64]

    // ---- length bucketing (also zeroes cnt for CSR) ----
    zero_cnt_kernel<<<nblk(N), 256, 0, stream>>>(cnt, N);
    bucket_hist_kernel<<<nblk(NN + EE), 256, 0, stream>>>(nlen, elen);
    bucket_scan_kernel<<<1, 64, 0, stream>>>();
    bucket_scatter_kernel<<<nblk(NN + EE), 256, 0, stream>>>(nlen, elen);

    // ---- temporal branches (node + edge fused; 32 seqs/wave, bf16 MFMA) ----
    const int nNodeBlk = (N + 127) / 128;        // 391
    const int nEdgeBlk = (E + 127) / 128;        // 3125
    lstm_fused_kernel<<<nNodeBlk + nEdgeBlk, 256, 0, stream>>>(
        nseq, nlen, eseq, elen, Wih, Whh, lb, dnnW, dnnb, permN, permE,
        nodeF, esc, nNodeBlk);

    // ---- CSR build (hierarchical scan; dinv fused into scan3) ----
    const unsigned scanBlk = nblk(N);   // 196
    count_kernel<<<nblk(E), 256, 0, stream>>>(dstp, cnt, E);
    scan1_kernel<<<scanBlk, 256, 0, stream>>>(cnt, N);
    scan2_kernel<<<1, 256, 0, stream>>>((int)scanBlk);
    scan3_kernel<<<scanBlk, 256, 0, stream>>>(cnt, rs, cur, dinv, N, E);
    fill_kernel<<<nblk(E), 256, 0, stream>>>(srcp, dstp, esc, cur, csrc, cesc, E);

    const unsigned gemmBlk = (N + 127) / 128;

    // ---- GAT layer 1 (H=8, C=8): P1 = xh1, P2 = gat1 out ----
    gemmX_mfma_kernel<<<gemmBlk, 256, 0, stream>>>(x, nodeF, g1W, P1, N);
    alpha_kernel<8, 8><<<nblk((size_t)N * 8), 256, 0, stream>>>(P1, g1att, alpha, N);
    gat_softmax8_row_kernel<<<nblk(N), 256, 0, stream>>>(rs, csrc, alpha, amax, rinv, N);
    gat_gather_kernel<8, false><<<(N + 3) / 4, 256, 0, stream>>>(
        rs, csrc, cesc, P1, alpha, amax, rinv, g1b, P2, N);

    // ---- GAT layer 2 (H=1, C=64): P1 = xh2, output -> outGat ----
    gemm64_mfma_kernel<<<gemmBlk, 256, 0, stream>>>(P2, g2W, P1, N);
    alpha_kernel<1, 64><<<nblk(N), 256, 0, stream>>>(P1, g2att, alpha, N);
    gat_softmax_csr_kernel<1><<<nblk(N), 256, 0, stream>>>(rs, csrc, alpha, amax, rinv, N);
    gat_gather_kernel<1, true><<<(N + 3) / 4, 256, 0, stream>>>(
        rs, csrc, cesc, P1, alpha, amax, rinv, g2b, outGat, N);

    // ---- GCN layer 1: P1 = xw1, P2 = lrelu(gcn1) ----
    gemmX_mfma_kernel<<<gemmBlk, 256, 0, stream>>>(x, nodeF, gc1W, P1, N);
    gcn_gather_kernel<<<(N + 3) / 4, 256, 0, stream>>>(rs, csrc, P1, dinv, gc1b, P2, N);

    // ---- GCN layer 2: P1 = xw2, output -> outGcn (x_gcn, lrelu fused) ----
    gemm64_mfma_kernel<<<gemmBlk, 256, 0, stream>>>(P2, gc2W, P1, N);
    gcn_gather_kernel<<<(N + 3) / 4, 256, 0, stream>>>(rs, csrc, P1, dinv, gc2b, outGcn, N);

    // ---- classifier (reads x_gcn from d_out) ----
    cls_kernel<<<nblk(N), 256, 0, stream>>>(x, nodeF, outGcn, c1W, c1b, c2W, c2b, c3W, c3b, out0, N);
}

// Round 7
// 560.950 us; speedup vs baseline: 2.7142x; 1.1211x over previous
//
#include <hip/hip_runtime.h>
#include <hip/hip_bf16.h>

// TTAGN: LSTM(edge,node) -> GAT x2 + GCN x2 -> classifier.
// Inputs fp32, internal fp32, OUTPUT fp32.
// d_out = concat(out[N,4], x_gcn[N,64], x_gat[N,64]) as fp32.
// Scratch in __device__ globals.
//
// R17 == R16 resubmit (previous round died on container acquisition, not
// on the kernel: no compile/run ever happened).
// R16: fused graph layers. Each layer's {gat softmax, gat gather, gcn
// gather} collapses into ONE wave-per-dst kernel: phase1 = online
// softmax stats (H=8: lane=edge*8+head, butterfly-merge over edge lanes;
// H=1: 64-edge stride, full butterfly), phase2 = single CSR walk reading
// both xh (gat) and xw (gcn) rows per edge. Kills amax/rinv buffers, 2
// softmax kernels, halves csrc traffic, doubles gather-loop MLP.
// Also: count fused into bucket_hist; scan2 fused into scan3 (each block
// re-scans the 196 block sums locally). 23 -> 17 launches.
// LSTM (R12/13) + MFMA GEMMs (R14) + hierarchical scan (R15) unchanged.

typedef unsigned int u32;

#define NN 50000
#define EE 400000

__device__ float g_nodeF[NN * 16];
__device__ float g_esc[EE];
__device__ float g_P1[NN * 64];
__device__ float g_P2[NN * 64];
__device__ float g_P3[NN * 64];
__device__ float g_P4[NN * 64];
__device__ float g_alpha[NN * 8];
__device__ float g_dinv[NN];
__device__ int   g_cnt[NN];
__device__ int   g_rs[NN + 1];
__device__ int   g_cur[NN];
__device__ int   g_csrc[EE];
__device__ float g_cesc[EE];
__device__ int   g_bhist[32];   // [0..15] node bins (bin=16-len), [16..31] edge
__device__ int   g_bbase[32];   // exclusive bases -> rolling cursors
__device__ int   g_permN[NN];
__device__ int   g_permE[EE];
__device__ int   g_bsum[256];   // per-block sums for hierarchical scan

__device__ __forceinline__ float rcpf(float x) { return __builtin_amdgcn_rcpf(x); }
__device__ __forceinline__ float sigf(float x) { return rcpf(1.0f + __expf(-x)); }
__device__ __forceinline__ float tanh_fast(float x) {
    return 1.0f - 2.0f * rcpf(__expf(2.0f * x) + 1.0f);
}

// ---------------- bf16 MFMA helpers (split precision) ----------------
typedef short short8 __attribute__((ext_vector_type(8)));
typedef float f32x16 __attribute__((ext_vector_type(16)));

union S8U { short8 v; unsigned u[4]; };

// pack two floats as bf16 pair (truncation; lo-chains compensate the error)
__device__ __forceinline__ unsigned pk_hi(float a, float b) {
    return (__float_as_uint(a) >> 16) | (__float_as_uint(b) & 0xFFFF0000u);
}
__device__ __forceinline__ float bftrunc(float a) {
    return __uint_as_float(__float_as_uint(a) & 0xFFFF0000u);
}
__device__ __forceinline__ float lo_res(float a) { return a - bftrunc(a); }
__device__ __forceinline__ unsigned sx32(unsigned v) {
    return (unsigned)__shfl_xor((int)v, 32, 64);
}

// ---------------- length bucketing (counting sort, descending) -------------
// also fused: CSR degree count (cnt) over dstp.
__global__ void __launch_bounds__(256) bucket_hist_kernel(
    const int* __restrict__ nlen, const int* __restrict__ elen,
    const int* __restrict__ dstp, int* __restrict__ cnt)
{
    __shared__ int hb[32];
    int t = threadIdx.x;
    if (t < 32) hb[t] = 0;
    __syncthreads();
    int i = blockIdx.x * 256 + t;
    int bin = -1;
    if (i < NN + EE) {
        bin = (i < NN) ? (16 - nlen[i]) : (32 - elen[i - NN]);
    }
    if (bin >= 0) atomicAdd(&hb[bin], 1);
    if (i < EE) atomicAdd(&cnt[dstp[i]], 1);
    __syncthreads();
    if (t < 32 && hb[t] > 0) atomicAdd(&g_bhist[t], hb[t]);
}

__global__ void __launch_bounds__(64) bucket_scan_kernel()
{
    if (threadIdx.x == 0) {
        int acc = 0;
        for (int b = 0; b < 16; ++b) { g_bbase[b] = acc; acc += g_bhist[b]; }
        acc = 0;
        for (int b = 16; b < 32; ++b) { g_bbase[b] = acc; acc += g_bhist[b]; }
    }
}

__global__ void __launch_bounds__(256) bucket_scatter_kernel(
    const int* __restrict__ nlen, const int* __restrict__ elen)
{
    __shared__ int hb[32];
    int t = threadIdx.x;
    if (t < 32) hb[t] = 0;
    __syncthreads();
    int i = blockIdx.x * 256 + t;
    int bin = -1, idx = 0;
    if (i < NN + EE) {
        if (i < NN) { idx = i; bin = 16 - nlen[i]; }
        else        { idx = i - NN; bin = 32 - elen[i - NN]; }
    }
    if (bin >= 0) atomicAdd(&hb[bin], 1);
    __syncthreads();
    if (t < 32) {
        int c = hb[t];
        hb[t] = c > 0 ? atomicAdd(&g_bbase[t], c) : 0;
    }
    __syncthreads();
    if (bin >= 0) {
        int pos = atomicAdd(&hb[bin], 1);
        if (i < NN) g_permN[pos] = idx; else g_permE[pos] = idx;
    }
}

// One wave = 32 sequences (lanes l and l+32 share seq col=l&31).
// Lane (col,hi) owns units U[j] = (j&3) + 8*(j>>2) + 4*hi, j=0..7, of its seq.
// Block = 256 threads = 4 independent waves = 128 seqs (perm-bucketed).
__global__ void __launch_bounds__(256, 3) lstm_fused_kernel(
    const float* __restrict__ nseq, const int* __restrict__ nlen,
    const float* __restrict__ eseq, const int* __restrict__ elen,
    const float* __restrict__ Wih, const float* __restrict__ Whh,
    const float* __restrict__ bias,
    const float* __restrict__ dnnW, const float* __restrict__ dnnb,
    const int* __restrict__ permN, const int* __restrict__ permE,
    float* __restrict__ nodeF, float* __restrict__ esc, int nNodeBlk)
{
    const int lane = threadIdx.x & 63;
    const int col  = lane & 31;
    const int hi   = lane >> 5;
    const bool isLo = (hi == 0);
    const int wave = threadIdx.x >> 6;

    const bool edgeMode = (int)blockIdx.x >= nNodeBlk;
    const float* seq = edgeMode ? eseq : nseq;
    const int*  lens = edgeMode ? elen : nlen;
    const int*  perm = edgeMode ? permE : permN;
    const int limit  = edgeMode ? EE : NN;
    const int bbase  = edgeMode ? ((int)blockIdx.x - nNodeBlk) : (int)blockIdx.x;
    const int g  = bbase * 128 + wave * 32 + col;
    const int gc = g < limit ? g : limit - 1;
    const int s  = perm[gc];                 // actual sequence index
    const bool valid = g < limit;

    // ---- A fragments. Layout: lane(row=col [+32 tile1], k=8*hi+j, j=0..7).
    const int row0 = col, row1 = col + 32;
    const int ko = hi * 8;
    S8U ahh0, ahh1, ahl0, ahl1, ax0, ax1;
    {
        const float* w0 = Whh + row0 * 16 + ko;
        const float* w1 = Whh + row1 * 16 + ko;
#pragma unroll
        for (int r = 0; r < 4; ++r) {
            float a0 = w0[2 * r], b0 = w0[2 * r + 1];
            float a1 = w1[2 * r], b1 = w1[2 * r + 1];
            ahh0.u[r] = pk_hi(a0, b0);
            ahh1.u[r] = pk_hi(a1, b1);
            ahl0.u[r] = pk_hi(lo_res(a0), lo_res(b0));
            ahl1.u[r] = pk_hi(lo_res(a1), lo_res(b1));
        }
        // x-chain A (k slots, lo lanes only; hi lanes all-zero):
        // k0,k1=Wih_hi ; k2=bias_hi ; k3,k4=Wih_hi (for x_lo) ;
        // k5,k6=Wih_lo ; k7=bias_lo
#pragma unroll
        for (int r = 0; r < 4; ++r) { ax0.u[r] = 0u; ax1.u[r] = 0u; }
        if (isLo) {
            float wa0 = Wih[row0 * 2], wb0 = Wih[row0 * 2 + 1], bb0 = bias[row0];
            float wa1 = Wih[row1 * 2], wb1 = Wih[row1 * 2 + 1], bb1 = bias[row1];
            ax0.u[0] = pk_hi(wa0, wb0);
            ax0.u[1] = pk_hi(bb0, wa0);
            ax0.u[2] = pk_hi(wb0, lo_res(wa0));
            ax0.u[3] = pk_hi(lo_res(wb0), lo_res(bb0));
            ax1.u[0] = pk_hi(wa1, wb1);
            ax1.u[1] = pk_hi(bb1, wa1);
            ax1.u[2] = pk_hi(wb1, lo_res(wa1));
            ax1.u[3] = pk_hi(lo_res(wb1), lo_res(bb1));
        }
    }

    const f32x16 zc = {0.f, 0.f, 0.f, 0.f, 0.f, 0.f, 0.f, 0.f,
                       0.f, 0.f, 0.f, 0.f, 0.f, 0.f, 0.f, 0.f};
    const unsigned bxmask = isLo ? 0xFFFFFFFFu : 0u;
    const unsigned one_bf = 0x3F80u;  // bf16(1.0) in low half

    float cst[8], hlast[8];
#pragma unroll
    for (int j = 0; j < 8; ++j) { cst[j] = 0.f; hlast[j] = 0.f; }
    unsigned ph[4], pl[4];  // packed h (hi/lo), own units
#pragma unroll
    for (int r = 0; r < 4; ++r) { ph[r] = 0u; pl[r] = 0u; }

    const float4* sp = (const float4*)seq + (size_t)s * 8;  // 32 floats/seq
    const int lenm1 = lens[s] - 1;                          // in [0,15]
    // wave-max length -> float4 iterations needed (bucketed => ~uniform)
    int lm = lenm1;
#pragma unroll
    for (int off = 32; off >= 1; off >>= 1) {
        int o = __shfl_xor(lm, off, 64);
        lm = lm > o ? lm : o;
    }
    const int nIter = (lm >> 1) + 1;   // in [1,8]

    float4 q = sp[0];
#pragma unroll 1
    for (int i = 0; i < nIter; ++i) {
        float4 qn = sp[(i + 1) & 7];  // prefetch (wraps; always in-bounds)
#pragma unroll
        for (int hf = 0; hf < 2; ++hf) {
            const int t = 2 * i + hf;
            const float x0 = hf ? q.z : q.x;
            const float x1 = hf ? q.w : q.y;

            // B h-fragments: B[k=8*hi+j][col]; exchange halves via shfl.
            S8U bhh, bhl, bx;
            {
                unsigned t0 = sx32(ph[0]), t1 = sx32(ph[1]);
                unsigned t2 = sx32(ph[2]), t3 = sx32(ph[3]);
                bhh.u[0] = isLo ? ph[0] : t2;
                bhh.u[1] = isLo ? ph[1] : t3;
                bhh.u[2] = isLo ? t0 : ph[2];
                bhh.u[3] = isLo ? t1 : ph[3];
                unsigned s0 = sx32(pl[0]), s1 = sx32(pl[1]);
                unsigned s2 = sx32(pl[2]), s3 = sx32(pl[3]);
                bhl.u[0] = isLo ? pl[0] : s2;
                bhl.u[1] = isLo ? pl[1] : s3;
                bhl.u[2] = isLo ? s0 : pl[2];
                bhl.u[3] = isLo ? s1 : pl[3];
            }
            // B x-fragment: k0,k1=x_hi ; k2=1 ; k3,k4=x_lo ; k5,k6=x_hi ; k7=1
            {
                float xl0 = lo_res(x0), xl1 = lo_res(x1);
                bx.u[0] = pk_hi(x0, x1) & bxmask;
                bx.u[1] = (one_bf | (__float_as_uint(xl0) & 0xFFFF0000u)) & bxmask;
                bx.u[2] = pk_hi(xl1, x0) & bxmask;
                bx.u[3] = ((__float_as_uint(x1) >> 16) | (one_bf << 16)) & bxmask;
            }

            f32x16 d0 = __builtin_amdgcn_mfma_f32_32x32x16_bf16(ax0.v, bx.v, zc, 0, 0, 0);
            f32x16 d1 = __builtin_amdgcn_mfma_f32_32x32x16_bf16(ax1.v, bx.v, zc, 0, 0, 0);
            d0 = __builtin_amdgcn_mfma_f32_32x32x16_bf16(ahh0.v, bhh.v, d0, 0, 0, 0);
            d1 = __builtin_amdgcn_mfma_f32_32x32x16_bf16(ahh1.v, bhh.v, d1, 0, 0, 0);
            d0 = __builtin_amdgcn_mfma_f32_32x32x16_bf16(ahl0.v, bhh.v, d0, 0, 0, 0);
            d1 = __builtin_amdgcn_mfma_f32_32x32x16_bf16(ahl1.v, bhh.v, d1, 0, 0, 0);
            d0 = __builtin_amdgcn_mfma_f32_32x32x16_bf16(ahh0.v, bhl.v, d0, 0, 0, 0);
            d1 = __builtin_amdgcn_mfma_f32_32x32x16_bf16(ahh1.v, bhl.v, d1, 0, 0, 0);

            // d0[j]=i_U[j], d0[8+j]=f_U[j], d1[j]=g_U[j], d1[8+j]=o_U[j]
            float hh[8];
#pragma unroll
            for (int j = 0; j < 8; ++j) {
                float ip = d0[j], fp = d0[8 + j], gp = d1[j], op = d1[8 + j];
                float cu = sigf(fp) * cst[j] + sigf(ip) * tanh_fast(gp);
                cst[j] = cu;
                hh[j] = sigf(op) * tanh_fast(cu);
            }
            const bool selm = (t == lenm1);
#pragma unroll
            for (int j = 0; j < 8; ++j) hlast[j] = selm ? hh[j] : hlast[j];
            // repack h (hi + lo residual)
#pragma unroll
            for (int r = 0; r < 4; ++r) {
                float a = hh[2 * r], b = hh[2 * r + 1];
                ph[r] = pk_hi(a, b);
                pl[r] = pk_hi(lo_res(a), lo_res(b));
            }
        }
        q = qn;
    }

    if (edgeMode) {
        // esc[s] = dot(h16, dnnW) + dnnb ; lane holds units {0..3,8..11}+4*hi
        float4 dA = *(const float4*)(dnnW + hi * 4);
        float4 dB = *(const float4*)(dnnW + hi * 4 + 8);
        float part = hlast[0] * dA.x + hlast[1] * dA.y + hlast[2] * dA.z + hlast[3] * dA.w
                   + hlast[4] * dB.x + hlast[5] * dB.y + hlast[6] * dB.z + hlast[7] * dB.w;
        float tot = part + __shfl_xor(part, 32, 64);
        if (isLo && valid) esc[s] = tot + dnnb[0];
    } else {
        if (valid) {
            float* dst = nodeF + (size_t)s * 16 + hi * 4;
            *(float4*)(dst)     = make_float4(hlast[0], hlast[1], hlast[2], hlast[3]);
            *(float4*)(dst + 8) = make_float4(hlast[4], hlast[5], hlast[6], hlast[7]);
        }
    }
}

// ---------------- CSR build ----------------
__global__ void __launch_bounds__(256) zero_cnt_kernel(int* cnt, int n)
{
    int t = blockIdx.x * 256 + threadIdx.x;
    if (t < n) cnt[t] = 0;
    if (blockIdx.x == 0 && threadIdx.x < 32) g_bhist[threadIdx.x] = 0;
}

// hierarchical scan, stage 1: per-block (256-wide) tree reduction.
__global__ void __launch_bounds__(256) scan1_kernel(const int* __restrict__ cnt, int n)
{
    __shared__ int s[256];
    int t = threadIdx.x;
    int i = blockIdx.x * 256 + t;
    s[t] = (i < n) ? cnt[i] : 0;
    __syncthreads();
#pragma unroll
    for (int off = 128; off >= 1; off >>= 1) {
        if (t < off) s[t] += s[t + off];
        __syncthreads();
    }
    if (t == 0) g_bsum[blockIdx.x] = s[0];
}

// stage 2+3 fused: every block re-scans the nb block sums locally (1KB LDS,
// 8 H-S steps), then does its local exclusive scan; writes rs, cur, dinv.
__global__ void __launch_bounds__(256) scan3_kernel(
    const int* __restrict__ cnt, int* __restrict__ rs, int* __restrict__ cur,
    float* __restrict__ dinv, int n, int E, int nb)
{
    __shared__ int sb[256];
    __shared__ int s[256];
    int t = threadIdx.x;
    sb[t] = (t < nb) ? g_bsum[t] : 0;
    __syncthreads();
#pragma unroll
    for (int off = 1; off < 256; off <<= 1) {
        int add = (t >= off) ? sb[t - off] : 0;
        __syncthreads();
        sb[t] += add;
        __syncthreads();
    }
    const int boff = (blockIdx.x == 0) ? 0 : sb[blockIdx.x - 1];

    int i = blockIdx.x * 256 + t;
    int v = (i < n) ? cnt[i] : 0;
    s[t] = v;
    __syncthreads();
#pragma unroll
    for (int off = 1; off < 256; off <<= 1) {
        int add = (t >= off) ? s[t - off] : 0;
        __syncthreads();
        s[t] += add;
        __syncthreads();
    }
    if (i < n) {
        int excl = s[t] - v + boff;
        rs[i] = excl;
        cur[i] = excl;
        dinv[i] = rsqrtf((float)v + 1.0f);
    }
    if (i == 0) rs[n] = E;
}

__global__ void __launch_bounds__(256) fill_kernel(const int* __restrict__ src,
                                                   const int* __restrict__ dst,
                                                   const float* __restrict__ esc,
                                                   int* __restrict__ cur,
                                                   int* __restrict__ csrc,
                                                   float* __restrict__ cesc, int E)
{
    int e = blockIdx.x * 256 + threadIdx.x;
    if (e >= E) return;
    int pos = atomicAdd(&cur[dst[e]], 1);
    csrc[pos] = src[e];
    cesc[pos] = esc[e];
}

// ---- MFMA GEMM: C[n,64] = [x(240)|nodeF(16)] @ W[256,64] ----
// Block: 4 waves x 32 nodes = 128 nodes; each wave does 32 nodes x 64 cols.
// W packed once to LDS as bf16 hi/lo pairs (64 KB). Split-bf16 3-chain.
__global__ void __launch_bounds__(256, 2) gemmX_mfma_kernel(
    const float* __restrict__ x, const float* __restrict__ nodeF,
    const float* __restrict__ W, float* __restrict__ C, int n)
{
    __shared__ unsigned sWhi[128 * 64];  // pk(W[2k][c], W[2k+1][c])
    __shared__ unsigned sWlo[128 * 64];
    const int tid = threadIdx.x;
    for (int i = tid; i < 128 * 64; i += 256) {
        const int kk2 = i >> 6, c = i & 63;
        float a = W[kk2 * 128 + c];
        float b = W[kk2 * 128 + 64 + c];
        sWhi[i] = pk_hi(a, b);
        sWlo[i] = pk_hi(lo_res(a), lo_res(b));
    }
    __syncthreads();

    const int lane = tid & 63;
    const int col  = lane & 31;
    const int hi   = lane >> 5;
    const int wv   = tid >> 6;
    const int nodeBase = blockIdx.x * 128 + wv * 32;
    const int nodeL = nodeBase + col;
    const int nc = nodeL < n ? nodeL : n - 1;

    const f32x16 zc = {0.f, 0.f, 0.f, 0.f, 0.f, 0.f, 0.f, 0.f,
                       0.f, 0.f, 0.f, 0.f, 0.f, 0.f, 0.f, 0.f};
    f32x16 acc0 = zc, acc1 = zc;
    const float* xrow = x + (size_t)nc * 240;
    const float* frow = nodeF + (size_t)nc * 16;

#pragma unroll 1
    for (int ch = 0; ch < 16; ++ch) {
        const float* src = (ch < 15) ? (xrow + ch * 16 + hi * 8) : (frow + hi * 8);
        float4 v0 = *(const float4*)src;
        float4 v1 = *(const float4*)(src + 4);
        S8U xh, xl;
        xh.u[0] = pk_hi(v0.x, v0.y);
        xh.u[1] = pk_hi(v0.z, v0.w);
        xh.u[2] = pk_hi(v1.x, v1.y);
        xh.u[3] = pk_hi(v1.z, v1.w);
        xl.u[0] = pk_hi(lo_res(v0.x), lo_res(v0.y));
        xl.u[1] = pk_hi(lo_res(v0.z), lo_res(v0.w));
        xl.u[2] = pk_hi(lo_res(v1.x), lo_res(v1.y));
        xl.u[3] = pk_hi(lo_res(v1.z), lo_res(v1.w));

        const int rbase = (ch * 8 + hi * 4) * 64 + col;
        S8U wh0, wl0, wh1, wl1;
#pragma unroll
        for (int r = 0; r < 4; ++r) {
            wh0.u[r] = sWhi[rbase + r * 64];
            wl0.u[r] = sWlo[rbase + r * 64];
            wh1.u[r] = sWhi[rbase + r * 64 + 32];
            wl1.u[r] = sWlo[rbase + r * 64 + 32];
        }
        acc0 = __builtin_amdgcn_mfma_f32_32x32x16_bf16(xh.v, wh0.v, acc0, 0, 0, 0);
        acc1 = __builtin_amdgcn_mfma_f32_32x32x16_bf16(xh.v, wh1.v, acc1, 0, 0, 0);
        acc0 = __builtin_amdgcn_mfma_f32_32x32x16_bf16(xl.v, wh0.v, acc0, 0, 0, 0);
        acc1 = __builtin_amdgcn_mfma_f32_32x32x16_bf16(xl.v, wh1.v, acc1, 0, 0, 0);
        acc0 = __builtin_amdgcn_mfma_f32_32x32x16_bf16(xh.v, wl0.v, acc0, 0, 0, 0);
        acc1 = __builtin_amdgcn_mfma_f32_32x32x16_bf16(xh.v, wl1.v, acc1, 0, 0, 0);
    }

#pragma unroll
    for (int r = 0; r < 16; ++r) {
        const int nr = (r & 3) + 8 * (r >> 2) + 4 * hi;
        const int nd = nodeBase + nr;
        if (nd < n) {
            C[(size_t)nd * 64 + col]      = acc0[r];
            C[(size_t)nd * 64 + 32 + col] = acc1[r];
        }
    }
}

// ---- MFMA GEMM: C[n,64] = A[n,64] @ W[64,64] (K=64, 4 chunks) ----
__global__ void __launch_bounds__(256, 2) gemm64_mfma_kernel(
    const float* __restrict__ A, const float* __restrict__ W,
    float* __restrict__ C, int n)
{
    __shared__ unsigned sWhi[32 * 64];
    __shared__ unsigned sWlo[32 * 64];
    const int tid = threadIdx.x;
    for (int i = tid; i < 32 * 64; i += 256) {
        const int kk2 = i >> 6, c = i & 63;
        float a = W[kk2 * 128 + c];
        float b = W[kk2 * 128 + 64 + c];
        sWhi[i] = pk_hi(a, b);
        sWlo[i] = pk_hi(lo_res(a), lo_res(b));
    }
    __syncthreads();

    const int lane = tid & 63;
    const int col  = lane & 31;
    const int hi   = lane >> 5;
    const int wv   = tid >> 6;
    const int nodeBase = blockIdx.x * 128 + wv * 32;
    const int nodeL = nodeBase + col;
    const int nc = nodeL < n ? nodeL : n - 1;

    const f32x16 zc = {0.f, 0.f, 0.f, 0.f, 0.f, 0.f, 0.f, 0.f,
                       0.f, 0.f, 0.f, 0.f, 0.f, 0.f, 0.f, 0.f};
    f32x16 acc0 = zc, acc1 = zc;
    const float* arow = A + (size_t)nc * 64;

#pragma unroll
    for (int ch = 0; ch < 4; ++ch) {
        const float* src = arow + ch * 16 + hi * 8;
        float4 v0 = *(const float4*)src;
        float4 v1 = *(const float4*)(src + 4);
        S8U xh, xl;
        xh.u[0] = pk_hi(v0.x, v0.y);
        xh.u[1] = pk_hi(v0.z, v0.w);
        xh.u[2] = pk_hi(v1.x, v1.y);
        xh.u[3] = pk_hi(v1.z, v1.w);
        xl.u[0] = pk_hi(lo_res(v0.x), lo_res(v0.y));
        xl.u[1] = pk_hi(lo_res(v0.z), lo_res(v0.w));
        xl.u[2] = pk_hi(lo_res(v1.x), lo_res(v1.y));
        xl.u[3] = pk_hi(lo_res(v1.z), lo_res(v1.w));

        const int rbase = (ch * 8 + hi * 4) * 64 + col;
        S8U wh0, wl0, wh1, wl1;
#pragma unroll
        for (int r = 0; r < 4; ++r) {
            wh0.u[r] = sWhi[rbase + r * 64];
            wl0.u[r] = sWlo[rbase + r * 64];
            wh1.u[r] = sWhi[rbase + r * 64 + 32];
            wl1.u[r] = sWlo[rbase + r * 64 + 32];
        }
        acc0 = __builtin_amdgcn_mfma_f32_32x32x16_bf16(xh.v, wh0.v, acc0, 0, 0, 0);
        acc1 = __builtin_amdgcn_mfma_f32_32x32x16_bf16(xh.v, wh1.v, acc1, 0, 0, 0);
        acc0 = __builtin_amdgcn_mfma_f32_32x32x16_bf16(xl.v, wh0.v, acc0, 0, 0, 0);
        acc1 = __builtin_amdgcn_mfma_f32_32x32x16_bf16(xl.v, wh1.v, acc1, 0, 0, 0);
        acc0 = __builtin_amdgcn_mfma_f32_32x32x16_bf16(xh.v, wl0.v, acc0, 0, 0, 0);
        acc1 = __builtin_amdgcn_mfma_f32_32x32x16_bf16(xh.v, wl1.v, acc1, 0, 0, 0);
    }

#pragma unroll
    for (int r = 0; r < 16; ++r) {
        const int nr = (r & 3) + 8 * (r >> 2) + 4 * hi;
        const int nd = nodeBase + nr;
        if (nd < n) {
            C[(size_t)nd * 64 + col]      = acc0[r];
            C[(size_t)nd * 64 + 32 + col] = acc1[r];
        }
    }
}

// ---------------- GAT alpha ----------------
template <int H, int C>
__global__ void __launch_bounds__(256) alpha_kernel(const float* __restrict__ xh,
                                                    const float* __restrict__ att,
                                                    float* __restrict__ alpha, int n)
{
    int t = blockIdx.x * 256 + threadIdx.x;
    if (t >= n * H) return;
    int h = (H == 1) ? 0 : (t % H);
    int nd = (H == 1) ? t : (t / H);
    const float* row = xh + (size_t)nd * 64 + h * C;
    float s = 0.f;
#pragma unroll
    for (int c = 0; c < C; ++c) s += row[c] * att[h * C + c];
    alpha[t] = s;
}

// ---- fused per-layer graph kernel: online softmax + GAT gather + GCN gather.
// Wave per dst (4 waves/block). Phase 1: online (m,s) over in-edges
// (H=8: lane=e*8+h, butterfly over e; H=1: 64-edge stride, full butterfly).
// Phase 2: one CSR walk accumulating both GAT (coef*xh) and GCN (norm*xw).
template <int H, bool FILTER>
__global__ void __launch_bounds__(256) fused_gather_kernel(
    const int* __restrict__ rs, const int* __restrict__ csrc,
    const float* __restrict__ cesc, const float* __restrict__ alpha,
    const float* __restrict__ xh, const float* __restrict__ xw,
    const float* __restrict__ dinv,
    const float* __restrict__ gbias, const float* __restrict__ cbias,
    float* __restrict__ gout, float* __restrict__ cout, int n)
{
    const int j = threadIdx.x & 63;
    const int d = blockIdx.x * 4 + (threadIdx.x >> 6);
    if (d >= n) return;               // wave-uniform: whole wave exits together
    const int k0 = rs[d], k1 = rs[d + 1];

    float m = -INFINITY, ssum = 0.f;
    if (H == 8) {
        const int e = j >> 3, h = j & 7;
        const int nb = (k1 - k0 + 7) >> 3;
        for (int b = 0; b < nb; ++b) {
            int k = k0 + b * 8 + e;
            if (k < k1) {
                float a = alpha[(size_t)csrc[k] * 8 + h];
                a = a > 0.f ? a : 0.2f * a;
                float mn = fmaxf(m, a);
                ssum = ssum * __expf(m - mn) + __expf(a - mn);
                m = mn;
            }
        }
#pragma unroll
        for (int msk = 8; msk <= 32; msk <<= 1) {
            float mo = __shfl_xor(m, msk, 64);
            float so = __shfl_xor(ssum, msk, 64);
            float mn = fmaxf(m, mo);
            float f1 = (m == -INFINITY) ? 0.f : __expf(m - mn);
            float f2 = (mo == -INFINITY) ? 0.f : __expf(mo - mn);
            ssum = ssum * f1 + so * f2;
            m = mn;
        }
    } else {
        const int nb = (k1 - k0 + 63) >> 6;
        for (int b = 0; b < nb; ++b) {
            int k = k0 + b * 64 + j;
            if (k < k1) {
                float a = alpha[csrc[k]];
                a = a > 0.f ? a : 0.2f * a;
                float mn = fmaxf(m, a);
                ssum = ssum * __expf(m - mn) + __expf(a - mn);
                m = mn;
            }
        }
#pragma unroll
        for (int msk = 1; msk <= 32; msk <<= 1) {
            float mo = __shfl_xor(m, msk, 64);
            float so = __shfl_xor(ssum, msk, 64);
            float mn = fmaxf(m, mo);
            float f1 = (m == -INFINITY) ? 0.f : __expf(m - mn);
            float f2 = (mo == -INFINITY) ? 0.f : __expf(mo - mn);
            ssum = ssum * f1 + so * f2;
            m = mn;
        }
    }
    const int h2 = (H == 8) ? (j >> 3) : 0;
    float mh, ri;
    if (H == 8) {
        mh = __shfl(m, h2, 64);       // lane h2 (e=0 group) holds head h2
        ri = rcpf(__shfl(ssum, h2, 64));
    } else {
        mh = m;
        ri = rcpf(ssum);
    }

    // phase 2: accumulate both branches in one CSR walk
    const float di = dinv[d];
    float ag = xh[(size_t)d * 64 + j] + gbias[j];
    float ac = xw[(size_t)d * 64 + j] * di * di + cbias[j];
#pragma unroll 2
    for (int k = k0; k < k1; ++k) {
        int s = csrc[k];
        float a = alpha[(size_t)s * H + h2];
        a = a > 0.f ? a : 0.2f * a;
        float coef = __expf(a - mh) * ri + cesc[k];
        ag += xh[(size_t)s * 64 + j] * coef;
        ac += xw[(size_t)s * 64 + j] * (dinv[s] * di);
    }
    if (FILTER && !__builtin_isfinite(ag)) ag = 0.f;
    gout[(size_t)d * 64 + j] = ag;
    cout[(size_t)d * 64 + j] = ac > 0.f ? ac : 0.01f * ac;  // leaky_relu(0.01)
}

// ---------------- classifier (fused 320->32->16->4; 43.5KB static LDS) ---------
__global__ void __launch_bounds__(256) cls_kernel(
    const float* __restrict__ x, const float* __restrict__ nodeF,
    const float* __restrict__ xg,
    const float* __restrict__ W1, const float* __restrict__ b1,
    const float* __restrict__ W2, const float* __restrict__ b2,
    const float* __restrict__ W3, const float* __restrict__ b3,
    float* __restrict__ outp, int n)
{
    __shared__ float sW1[320 * 32];
    __shared__ float sW2[32 * 16];
    __shared__ float sW3[16 * 4];
    __shared__ float sb1[32], sb2[16], sb3[4];
    int tid = threadIdx.x;
    for (int i = tid; i < 320 * 32; i += 256) sW1[i] = W1[i];
    for (int i = tid; i < 512; i += 256) sW2[i] = W2[i];
    if (tid < 64) sW3[tid] = W3[tid];
    if (tid < 32) sb1[tid] = b1[tid];
    if (tid < 16) sb2[tid] = b2[tid];
    if (tid < 4)  sb3[tid] = b3[tid];
    __syncthreads();
    int nd = blockIdx.x * 256 + tid;
    if (nd >= n) return;

    float a1[32];
#pragma unroll
    for (int j = 0; j < 32; ++j) a1[j] = sb1[j];
    const float4* xr = (const float4*)(x + (size_t)nd * 240);
#pragma unroll 1
    for (int k4 = 0; k4 < 60; ++k4) {
        float4 v = xr[k4];
        const float* wr = sW1 + k4 * 128;
#pragma unroll
        for (int j = 0; j < 32; ++j)
            a1[j] += v.x * wr[j] + v.y * wr[32 + j] + v.z * wr[64 + j] + v.w * wr[96 + j];
    }
    const float4* nf = (const float4*)(nodeF + (size_t)nd * 16);
#pragma unroll 1
    for (int k4 = 60; k4 < 64; ++k4) {
        float4 v = nf[k4 - 60];
        const float* wr = sW1 + k4 * 128;
#pragma unroll
        for (int j = 0; j < 32; ++j)
            a1[j] += v.x * wr[j] + v.y * wr[32 + j] + v.z * wr[64 + j] + v.w * wr[96 + j];
    }
    const float4* p2 = (const float4*)(xg + (size_t)nd * 64);
#pragma unroll 1
    for (int k4 = 0; k4 < 16; ++k4) {
        float4 v = p2[k4];
        const float* wr = sW1 + 8192 + k4 * 128;  // rows 256 + 4*k4
#pragma unroll
        for (int j = 0; j < 32; ++j)
            a1[j] += v.x * wr[j] + v.y * wr[32 + j] + v.z * wr[64 + j] + v.w * wr[96 + j];
    }
#pragma unroll
    for (int j = 0; j < 32; ++j) { float v = a1[j]; a1[j] = v > 0.f ? v : 0.01f * v; }

    float a2[16];
#pragma unroll
    for (int j = 0; j < 16; ++j) a2[j] = sb2[j];
#pragma unroll
    for (int k = 0; k < 32; ++k) {
        float v = a1[k];
        const float* wr = sW2 + k * 16;
#pragma unroll
        for (int j = 0; j < 16; ++j) a2[j] += v * wr[j];
    }
#pragma unroll
    for (int j = 0; j < 16; ++j) { float v = a2[j]; a2[j] = v > 0.f ? v : 0.01f * v; }

    float a3[4] = {sb3[0], sb3[1], sb3[2], sb3[3]};
#pragma unroll
    for (int k = 0; k < 16; ++k) {
        float v = a2[k];
        const float* wr = sW3 + k * 4;
        a3[0] += v * wr[0]; a3[1] += v * wr[1]; a3[2] += v * wr[2]; a3[3] += v * wr[3];
    }
    float4 o = make_float4(a3[0], a3[1], a3[2], a3[3]);
    *(float4*)(outp + (size_t)nd * 4) = o;
}

// ---------------- launcher ----------------
static inline unsigned nblk(size_t t) { return (unsigned)((t + 255) / 256); }

extern "C" void kernel_launch(void* const* d_in, const int* in_sizes, int n_in,
                              void* d_out, int out_size, void* d_ws, size_t ws_size,
                              hipStream_t stream)
{
    const float* x     = (const float*)d_in[0];
    const float* eseq  = (const float*)d_in[1];
    const float* nseq  = (const float*)d_in[2];
    const float* Wih   = (const float*)d_in[3];
    const float* Whh   = (const float*)d_in[4];
    const float* lb    = (const float*)d_in[5];
    const float* dnnW  = (const float*)d_in[6];
    const float* dnnb  = (const float*)d_in[7];
    const float* g1W   = (const float*)d_in[8];
    const float* g1att = (const float*)d_in[9];
    const float* g1b   = (const float*)d_in[10];
    const float* g2W   = (const float*)d_in[11];
    const float* g2att = (const float*)d_in[12];
    const float* g2b   = (const float*)d_in[13];
    const float* gc1W  = (const float*)d_in[14];
    const float* gc1b  = (const float*)d_in[15];
    const float* gc2W  = (const float*)d_in[16];
    const float* gc2b  = (const float*)d_in[17];
    const float* c1W   = (const float*)d_in[18];
    const float* c1b   = (const float*)d_in[19];
    const float* c2W   = (const float*)d_in[20];
    const float* c2b   = (const float*)d_in[21];
    const float* c3W   = (const float*)d_in[22];
    const float* c3b   = (const float*)d_in[23];
    const int* eidx  = (const int*)d_in[24];
    const int* elen  = (const int*)d_in[25];
    const int* nlen  = (const int*)d_in[26];

    const int N = NN;
    const int E = EE;
    const int* srcp = eidx;
    const int* dstp = eidx + E;

    // device-global scratch
    float *nodeF, *esc, *P1, *P2, *P3, *P4, *alpha, *dinv, *cesc;
    int *cnt, *rs, *cur, *csrc, *permN, *permE;
    hipGetSymbolAddress((void**)&nodeF, HIP_SYMBOL(g_nodeF));
    hipGetSymbolAddress((void**)&esc,   HIP_SYMBOL(g_esc));
    hipGetSymbolAddress((void**)&P1,    HIP_SYMBOL(g_P1));
    hipGetSymbolAddress((void**)&P2,    HIP_SYMBOL(g_P2));
    hipGetSymbolAddress((void**)&P3,    HIP_SYMBOL(g_P3));
    hipGetSymbolAddress((void**)&P4,    HIP_SYMBOL(g_P4));
    hipGetSymbolAddress((void**)&alpha, HIP_SYMBOL(g_alpha));
    hipGetSymbolAddress((void**)&dinv,  HIP_SYMBOL(g_dinv));
    hipGetSymbolAddress((void**)&cnt,   HIP_SYMBOL(g_cnt));
    hipGetSymbolAddress((void**)&rs,    HIP_SYMBOL(g_rs));
    hipGetSymbolAddress((void**)&cur,   HIP_SYMBOL(g_cur));
    hipGetSymbolAddress((void**)&csrc,  HIP_SYMBOL(g_csrc));
    hipGetSymbolAddress((void**)&cesc,  HIP_SYMBOL(g_cesc));
    hipGetSymbolAddress((void**)&permN, HIP_SYMBOL(g_permN));
    hipGetSymbolAddress((void**)&permE, HIP_SYMBOL(g_permE));

    float* out0   = (float*)d_out;             // [N,4]
    float* outGcn = out0 + (size_t)N * 4;      // [N,64]
    float* outGat = outGcn + (size_t)N * 64;   // [N,64]

    // ---- bucketing + CSR degree count (fused) ----
    zero_cnt_kernel<<<nblk(N), 256, 0, stream>>>(cnt, N);
    bucket_hist_kernel<<<nblk(NN + EE), 256, 0, stream>>>(nlen, elen, dstp, cnt);
    bucket_scan_kernel<<<1, 64, 0, stream>>>();
    bucket_scatter_kernel<<<nblk(NN + EE), 256, 0, stream>>>(nlen, elen);

    // ---- temporal branches (node + edge fused; 32 seqs/wave, bf16 MFMA) ----
    const int nNodeBlk = (N + 127) / 128;        // 391
    const int nEdgeBlk = (E + 127) / 128;        // 3125
    lstm_fused_kernel<<<nNodeBlk + nEdgeBlk, 256, 0, stream>>>(
        nseq, nlen, eseq, elen, Wih, Whh, lb, dnnW, dnnb, permN, permE,
        nodeF, esc, nNodeBlk);

    // ---- CSR build (hierarchical scan, stage2 fused into stage3) ----
    const unsigned scanBlk = nblk(N);   // 196
    scan1_kernel<<<scanBlk, 256, 0, stream>>>(cnt, N);
    scan3_kernel<<<scanBlk, 256, 0, stream>>>(cnt, rs, cur, dinv, N, E, (int)scanBlk);
    fill_kernel<<<nblk(E), 256, 0, stream>>>(srcp, dstp, esc, cur, csrc, cesc, E);

    const unsigned gemmBlk = (N + 127) / 128;

    // ---- layer 1: xh1 -> P1 (GAT), xw1 -> P3 (GCN); fused gather -> P2, P4 --
    gemmX_mfma_kernel<<<gemmBlk, 256, 0, stream>>>(x, nodeF, g1W, P1, N);
    gemmX_mfma_kernel<<<gemmBlk, 256, 0, stream>>>(x, nodeF, gc1W, P3, N);
    alpha_kernel<8, 8><<<nblk((size_t)N * 8), 256, 0, stream>>>(P1, g1att, alpha, N);
    fused_gather_kernel<8, false><<<(N + 3) / 4, 256, 0, stream>>>(
        rs, csrc, cesc, alpha, P1, P3, dinv, g1b, gc1b, P2, P4, N);

    // ---- layer 2: xh2 -> P1, xw2 -> P3; fused gather -> outGat, outGcn ----
    gemm64_mfma_kernel<<<gemmBlk, 256, 0, stream>>>(P2, g2W, P1, N);
    gemm64_mfma_kernel<<<gemmBlk, 256, 0, stream>>>(P4, gc2W, P3, N);
    alpha_kernel<1, 64><<<nblk(N), 256, 0, stream>>>(P1, g2att, alpha, N);
    fused_gather_kernel<1, true><<<(N + 3) / 4, 256, 0, stream>>>(
        rs, csrc, cesc, alpha, P1, P3, dinv, g2b, gc2b, outGat, outGcn, N);

    // ---- classifier (reads x_gcn from d_out) ----
    cls_kernel<<<nblk(N), 256, 0, stream>>>(x, nodeF, outGcn, c1W, c1b, c2W, c2b, c3W, c3b, out0, N);
}

// Round 8
// 551.370 us; speedup vs baseline: 2.7613x; 1.0174x over previous
//
#include <hip/hip_runtime.h>
#include <hip/hip_bf16.h>

// TTAGN: LSTM(edge,node) -> GAT x2 + GCN x2 -> classifier.
// Inputs fp32, internal fp32, OUTPUT fp32.
// d_out = concat(out[N,4], x_gcn[N,64], x_gat[N,64]) as fp32.
// Scratch in __device__ globals.
//
// R18: (a) LSTM exp2-folding: log2e (i,f,o) / 2*log2e (g) folded into the
// Whh/Wih/bias fragments; activations use __builtin_amdgcn_exp2f directly
// (saves the v_mul inside every __expf; ~15% of the VALU stream at
// VALUBusy 76%). Algebraically identical.
// (b) gemmX_dual: both layer-1 GEMMs (g1W, gc1W) in ONE kernel -- shared
// x reads (48MB read once) + shared bf16 packing; K-phased LDS 64KB.
// alpha8 fused into the epilogue (8-lane shfl reduce vs att[col]).
// (c) gemm64_dual: both layer-2 GEMMs in one launch (32KB LDS), alpha1
// epilogue (32-lane reduce). alpha_kernel launches eliminated; 17 -> 13.
// LSTM structure (R12/13), fused gathers (R16), scans (R15) unchanged.

typedef unsigned int u32;

#define NN 50000
#define EE 400000

__device__ float g_nodeF[NN * 16];
__device__ float g_esc[EE];
__device__ float g_P1[NN * 64];
__device__ float g_P2[NN * 64];
__device__ float g_P3[NN * 64];
__device__ float g_P4[NN * 64];
__device__ float g_alpha[NN * 8];
__device__ float g_dinv[NN];
__device__ int   g_cnt[NN];
__device__ int   g_rs[NN + 1];
__device__ int   g_cur[NN];
__device__ int   g_csrc[EE];
__device__ float g_cesc[EE];
__device__ int   g_bhist[32];   // [0..15] node bins (bin=16-len), [16..31] edge
__device__ int   g_bbase[32];   // exclusive bases -> rolling cursors
__device__ int   g_permN[NN];
__device__ int   g_permE[EE];
__device__ int   g_bsum[256];   // per-block sums for hierarchical scan

__device__ __forceinline__ float rcpf(float x) { return __builtin_amdgcn_rcpf(x); }
__device__ __forceinline__ float ex2(float x)  { return __builtin_amdgcn_exp2f(x); }
__device__ __forceinline__ float sigf(float x) { return rcpf(1.0f + __expf(-x)); }

// ---------------- bf16 MFMA helpers (split precision) ----------------
typedef short short8 __attribute__((ext_vector_type(8)));
typedef float f32x16 __attribute__((ext_vector_type(16)));

union S8U { short8 v; unsigned u[4]; };

// pack two floats as bf16 pair (truncation; lo-chains compensate the error)
__device__ __forceinline__ unsigned pk_hi(float a, float b) {
    return (__float_as_uint(a) >> 16) | (__float_as_uint(b) & 0xFFFF0000u);
}
__device__ __forceinline__ float bftrunc(float a) {
    return __uint_as_float(__float_as_uint(a) & 0xFFFF0000u);
}
__device__ __forceinline__ float lo_res(float a) { return a - bftrunc(a); }
__device__ __forceinline__ unsigned sx32(unsigned v) {
    return (unsigned)__shfl_xor((int)v, 32, 64);
}

// ---------------- length bucketing (counting sort, descending) -------------
// also fused: CSR degree count (cnt) over dstp.
__global__ void __launch_bounds__(256) bucket_hist_kernel(
    const int* __restrict__ nlen, const int* __restrict__ elen,
    const int* __restrict__ dstp, int* __restrict__ cnt)
{
    __shared__ int hb[32];
    int t = threadIdx.x;
    if (t < 32) hb[t] = 0;
    __syncthreads();
    int i = blockIdx.x * 256 + t;
    int bin = -1;
    if (i < NN + EE) {
        bin = (i < NN) ? (16 - nlen[i]) : (32 - elen[i - NN]);
    }
    if (bin >= 0) atomicAdd(&hb[bin], 1);
    if (i < EE) atomicAdd(&cnt[dstp[i]], 1);
    __syncthreads();
    if (t < 32 && hb[t] > 0) atomicAdd(&g_bhist[t], hb[t]);
}

__global__ void __launch_bounds__(64) bucket_scan_kernel()
{
    if (threadIdx.x == 0) {
        int acc = 0;
        for (int b = 0; b < 16; ++b) { g_bbase[b] = acc; acc += g_bhist[b]; }
        acc = 0;
        for (int b = 16; b < 32; ++b) { g_bbase[b] = acc; acc += g_bhist[b]; }
    }
}

__global__ void __launch_bounds__(256) bucket_scatter_kernel(
    const int* __restrict__ nlen, const int* __restrict__ elen)
{
    __shared__ int hb[32];
    int t = threadIdx.x;
    if (t < 32) hb[t] = 0;
    __syncthreads();
    int i = blockIdx.x * 256 + t;
    int bin = -1, idx = 0;
    if (i < NN + EE) {
        if (i < NN) { idx = i; bin = 16 - nlen[i]; }
        else        { idx = i - NN; bin = 32 - elen[i - NN]; }
    }
    if (bin >= 0) atomicAdd(&hb[bin], 1);
    __syncthreads();
    if (t < 32) {
        int c = hb[t];
        hb[t] = c > 0 ? atomicAdd(&g_bbase[t], c) : 0;
    }
    __syncthreads();
    if (bin >= 0) {
        int pos = atomicAdd(&hb[bin], 1);
        if (i < NN) g_permN[pos] = idx; else g_permE[pos] = idx;
    }
}

// One wave = 32 sequences (lanes l and l+32 share seq col=l&31).
// Lane (col,hi) owns units U[j] = (j&3) + 8*(j>>2) + 4*hi, j=0..7, of its seq.
// Block = 256 threads = 4 independent waves = 128 seqs (perm-bucketed).
// Gates are PRE-SCALED: rows i,f,o by log2e, g rows by 2*log2e (folded into
// A fragments) so activations use exp2 directly.
__global__ void __launch_bounds__(256, 3) lstm_fused_kernel(
    const float* __restrict__ nseq, const int* __restrict__ nlen,
    const float* __restrict__ eseq, const int* __restrict__ elen,
    const float* __restrict__ Wih, const float* __restrict__ Whh,
    const float* __restrict__ bias,
    const float* __restrict__ dnnW, const float* __restrict__ dnnb,
    const int* __restrict__ permN, const int* __restrict__ permE,
    float* __restrict__ nodeF, float* __restrict__ esc, int nNodeBlk)
{
    const int lane = threadIdx.x & 63;
    const int col  = lane & 31;
    const int hi   = lane >> 5;
    const bool isLo = (hi == 0);
    const int wave = threadIdx.x >> 6;

    const bool edgeMode = (int)blockIdx.x >= nNodeBlk;
    const float* seq = edgeMode ? eseq : nseq;
    const int*  lens = edgeMode ? elen : nlen;
    const int*  perm = edgeMode ? permE : permN;
    const int limit  = edgeMode ? EE : NN;
    const int bbase  = edgeMode ? ((int)blockIdx.x - nNodeBlk) : (int)blockIdx.x;
    const int g  = bbase * 128 + wave * 32 + col;
    const int gc = g < limit ? g : limit - 1;
    const int s  = perm[gc];                 // actual sequence index
    const bool valid = g < limit;

    // ---- A fragments. Layout: lane(row=col [+32 tile1], k=8*hi+j, j=0..7).
    const float LOG2E = 1.44269504f;
    const int row0 = col, row1 = col + 32;
    const float s0 = LOG2E;                          // rows 0-31: i,f (sigmoid)
    const float s1 = (row1 < 48) ? 2.0f * LOG2E : LOG2E;  // g: 2log2e; o: log2e
    const int ko = hi * 8;
    S8U ahh0, ahh1, ahl0, ahl1, ax0, ax1;
    {
        const float* w0 = Whh + row0 * 16 + ko;
        const float* w1 = Whh + row1 * 16 + ko;
#pragma unroll
        for (int r = 0; r < 4; ++r) {
            float a0 = w0[2 * r] * s0, b0 = w0[2 * r + 1] * s0;
            float a1 = w1[2 * r] * s1, b1 = w1[2 * r + 1] * s1;
            ahh0.u[r] = pk_hi(a0, b0);
            ahh1.u[r] = pk_hi(a1, b1);
            ahl0.u[r] = pk_hi(lo_res(a0), lo_res(b0));
            ahl1.u[r] = pk_hi(lo_res(a1), lo_res(b1));
        }
        // x-chain A (k slots, lo lanes only; hi lanes all-zero):
        // k0,k1=Wih_hi ; k2=bias_hi ; k3,k4=Wih_hi (for x_lo) ;
        // k5,k6=Wih_lo ; k7=bias_lo      (all pre-scaled)
#pragma unroll
        for (int r = 0; r < 4; ++r) { ax0.u[r] = 0u; ax1.u[r] = 0u; }
        if (isLo) {
            float wa0 = Wih[row0 * 2] * s0, wb0 = Wih[row0 * 2 + 1] * s0, bb0 = bias[row0] * s0;
            float wa1 = Wih[row1 * 2] * s1, wb1 = Wih[row1 * 2 + 1] * s1, bb1 = bias[row1] * s1;
            ax0.u[0] = pk_hi(wa0, wb0);
            ax0.u[1] = pk_hi(bb0, wa0);
            ax0.u[2] = pk_hi(wb0, lo_res(wa0));
            ax0.u[3] = pk_hi(lo_res(wb0), lo_res(bb0));
            ax1.u[0] = pk_hi(wa1, wb1);
            ax1.u[1] = pk_hi(bb1, wa1);
            ax1.u[2] = pk_hi(wb1, lo_res(wa1));
            ax1.u[3] = pk_hi(lo_res(wb1), lo_res(bb1));
        }
    }

    const f32x16 zc = {0.f, 0.f, 0.f, 0.f, 0.f, 0.f, 0.f, 0.f,
                       0.f, 0.f, 0.f, 0.f, 0.f, 0.f, 0.f, 0.f};
    const unsigned bxmask = isLo ? 0xFFFFFFFFu : 0u;
    const unsigned one_bf = 0x3F80u;  // bf16(1.0) in low half

    float cst[8], hlast[8];
#pragma unroll
    for (int j = 0; j < 8; ++j) { cst[j] = 0.f; hlast[j] = 0.f; }
    unsigned ph[4], pl[4];  // packed h (hi/lo), own units
#pragma unroll
    for (int r = 0; r < 4; ++r) { ph[r] = 0u; pl[r] = 0u; }

    const float4* sp = (const float4*)seq + (size_t)s * 8;  // 32 floats/seq
    const int lenm1 = lens[s] - 1;                          // in [0,15]
    // wave-max length -> float4 iterations needed (bucketed => ~uniform)
    int lm = lenm1;
#pragma unroll
    for (int off = 32; off >= 1; off >>= 1) {
        int o = __shfl_xor(lm, off, 64);
        lm = lm > o ? lm : o;
    }
    const int nIter = (lm >> 1) + 1;   // in [1,8]

    float4 q = sp[0];
#pragma unroll 1
    for (int i = 0; i < nIter; ++i) {
        float4 qn = sp[(i + 1) & 7];  // prefetch (wraps; always in-bounds)
#pragma unroll
        for (int hf = 0; hf < 2; ++hf) {
            const int t = 2 * i + hf;
            const float x0 = hf ? q.z : q.x;
            const float x1 = hf ? q.w : q.y;

            // B h-fragments: B[k=8*hi+j][col]; exchange halves via shfl.
            S8U bhh, bhl, bx;
            {
                unsigned t0 = sx32(ph[0]), t1 = sx32(ph[1]);
                unsigned t2 = sx32(ph[2]), t3 = sx32(ph[3]);
                bhh.u[0] = isLo ? ph[0] : t2;
                bhh.u[1] = isLo ? ph[1] : t3;
                bhh.u[2] = isLo ? t0 : ph[2];
                bhh.u[3] = isLo ? t1 : ph[3];
                unsigned s0u = sx32(pl[0]), s1u = sx32(pl[1]);
                unsigned s2u = sx32(pl[2]), s3u = sx32(pl[3]);
                bhl.u[0] = isLo ? pl[0] : s2u;
                bhl.u[1] = isLo ? pl[1] : s3u;
                bhl.u[2] = isLo ? s0u : pl[2];
                bhl.u[3] = isLo ? s1u : pl[3];
            }
            // B x-fragment: k0,k1=x_hi ; k2=1 ; k3,k4=x_lo ; k5,k6=x_hi ; k7=1
            {
                float xl0 = lo_res(x0), xl1 = lo_res(x1);
                bx.u[0] = pk_hi(x0, x1) & bxmask;
                bx.u[1] = (one_bf | (__float_as_uint(xl0) & 0xFFFF0000u)) & bxmask;
                bx.u[2] = pk_hi(xl1, x0) & bxmask;
                bx.u[3] = ((__float_as_uint(x1) >> 16) | (one_bf << 16)) & bxmask;
            }

            f32x16 d0 = __builtin_amdgcn_mfma_f32_32x32x16_bf16(ax0.v, bx.v, zc, 0, 0, 0);
            f32x16 d1 = __builtin_amdgcn_mfma_f32_32x32x16_bf16(ax1.v, bx.v, zc, 0, 0, 0);
            d0 = __builtin_amdgcn_mfma_f32_32x32x16_bf16(ahh0.v, bhh.v, d0, 0, 0, 0);
            d1 = __builtin_amdgcn_mfma_f32_32x32x16_bf16(ahh1.v, bhh.v, d1, 0, 0, 0);
            d0 = __builtin_amdgcn_mfma_f32_32x32x16_bf16(ahl0.v, bhh.v, d0, 0, 0, 0);
            d1 = __builtin_amdgcn_mfma_f32_32x32x16_bf16(ahl1.v, bhh.v, d1, 0, 0, 0);
            d0 = __builtin_amdgcn_mfma_f32_32x32x16_bf16(ahh0.v, bhl.v, d0, 0, 0, 0);
            d1 = __builtin_amdgcn_mfma_f32_32x32x16_bf16(ahh1.v, bhl.v, d1, 0, 0, 0);

            // d0[j]=i_s, d0[8+j]=f_s, d1[j]=g_s(2log2e), d1[8+j]=o_s (scaled)
            float hh[8];
#pragma unroll
            for (int j = 0; j < 8; ++j) {
                float ip = d0[j], fp = d0[8 + j], gp = d1[j], op = d1[8 + j];
                float sig_i = rcpf(1.0f + ex2(-ip));
                float sig_f = rcpf(1.0f + ex2(-fp));
                float th_g  = 1.0f - 2.0f * rcpf(ex2(gp) + 1.0f);
                float cu = sig_f * cst[j] + sig_i * th_g;
                cst[j] = cu;
                float th_c = 1.0f - 2.0f * rcpf(ex2(cu * 2.88539008f) + 1.0f);
                hh[j] = rcpf(1.0f + ex2(-op)) * th_c;
            }
            const bool selm = (t == lenm1);
#pragma unroll
            for (int j = 0; j < 8; ++j) hlast[j] = selm ? hh[j] : hlast[j];
            // repack h (hi + lo residual)
#pragma unroll
            for (int r = 0; r < 4; ++r) {
                float a = hh[2 * r], b = hh[2 * r + 1];
                ph[r] = pk_hi(a, b);
                pl[r] = pk_hi(lo_res(a), lo_res(b));
            }
        }
        q = qn;
    }

    if (edgeMode) {
        // esc[s] = dot(h16, dnnW) + dnnb ; lane holds units {0..3,8..11}+4*hi
        float4 dA = *(const float4*)(dnnW + hi * 4);
        float4 dB = *(const float4*)(dnnW + hi * 4 + 8);
        float part = hlast[0] * dA.x + hlast[1] * dA.y + hlast[2] * dA.z + hlast[3] * dA.w
                   + hlast[4] * dB.x + hlast[5] * dB.y + hlast[6] * dB.z + hlast[7] * dB.w;
        float tot = part + __shfl_xor(part, 32, 64);
        if (isLo && valid) esc[s] = tot + dnnb[0];
    } else {
        if (valid) {
            float* dst = nodeF + (size_t)s * 16 + hi * 4;
            *(float4*)(dst)     = make_float4(hlast[0], hlast[1], hlast[2], hlast[3]);
            *(float4*)(dst + 8) = make_float4(hlast[4], hlast[5], hlast[6], hlast[7]);
        }
    }
}

// ---------------- CSR build ----------------
__global__ void __launch_bounds__(256) zero_cnt_kernel(int* cnt, int n)
{
    int t = blockIdx.x * 256 + threadIdx.x;
    if (t < n) cnt[t] = 0;
    if (blockIdx.x == 0 && threadIdx.x < 32) g_bhist[threadIdx.x] = 0;
}

// hierarchical scan, stage 1: per-block (256-wide) tree reduction.
__global__ void __launch_bounds__(256) scan1_kernel(const int* __restrict__ cnt, int n)
{
    __shared__ int s[256];
    int t = threadIdx.x;
    int i = blockIdx.x * 256 + t;
    s[t] = (i < n) ? cnt[i] : 0;
    __syncthreads();
#pragma unroll
    for (int off = 128; off >= 1; off >>= 1) {
        if (t < off) s[t] += s[t + off];
        __syncthreads();
    }
    if (t == 0) g_bsum[blockIdx.x] = s[0];
}

// stage 2+3 fused: every block re-scans the nb block sums locally (1KB LDS,
// 8 H-S steps), then does its local exclusive scan; writes rs, cur, dinv.
__global__ void __launch_bounds__(256) scan3_kernel(
    const int* __restrict__ cnt, int* __restrict__ rs, int* __restrict__ cur,
    float* __restrict__ dinv, int n, int E, int nb)
{
    __shared__ int sb[256];
    __shared__ int s[256];
    int t = threadIdx.x;
    sb[t] = (t < nb) ? g_bsum[t] : 0;
    __syncthreads();
#pragma unroll
    for (int off = 1; off < 256; off <<= 1) {
        int add = (t >= off) ? sb[t - off] : 0;
        __syncthreads();
        sb[t] += add;
        __syncthreads();
    }
    const int boff = (blockIdx.x == 0) ? 0 : sb[blockIdx.x - 1];

    int i = blockIdx.x * 256 + t;
    int v = (i < n) ? cnt[i] : 0;
    s[t] = v;
    __syncthreads();
#pragma unroll
    for (int off = 1; off < 256; off <<= 1) {
        int add = (t >= off) ? s[t - off] : 0;
        __syncthreads();
        s[t] += add;
        __syncthreads();
    }
    if (i < n) {
        int excl = s[t] - v + boff;
        rs[i] = excl;
        cur[i] = excl;
        dinv[i] = rsqrtf((float)v + 1.0f);
    }
    if (i == 0) rs[n] = E;
}

__global__ void __launch_bounds__(256) fill_kernel(const int* __restrict__ src,
                                                   const int* __restrict__ dst,
                                                   const float* __restrict__ esc,
                                                   int* __restrict__ cur,
                                                   int* __restrict__ csrc,
                                                   float* __restrict__ cesc, int E)
{
    int e = blockIdx.x * 256 + threadIdx.x;
    if (e >= E) return;
    int pos = atomicAdd(&cur[dst[e]], 1);
    csrc[pos] = src[e];
    cesc[pos] = esc[e];
}

// ---- DUAL MFMA GEMM: Pg/Pc[n,64] = [x(240)|nodeF(16)] @ {Wg,Wc}[256,64] ----
// Shared x reads + packing; K-phased LDS: 2 phases x [mat][hi/lo][64x64]=64KB.
// alpha8 epilogue from the GAT accumulators (8-lane shfl reduce vs att[col]).
__global__ void __launch_bounds__(256, 2) gemmX_dual_kernel(
    const float* __restrict__ x, const float* __restrict__ nodeF,
    const float* __restrict__ Wg, const float* __restrict__ Wc,
    const float* __restrict__ att,
    float* __restrict__ Pg, float* __restrict__ Pc,
    float* __restrict__ alpha, int n)
{
    __shared__ unsigned sW[2][2][64 * 64];  // [mat][hi|lo][kk2*64+c] : 64 KB
    const int tid = threadIdx.x;
    const int lane = tid & 63;
    const int col  = lane & 31;
    const int hi   = lane >> 5;
    const int wv   = tid >> 6;
    const int nodeBase = blockIdx.x * 128 + wv * 32;
    const int nodeL = nodeBase + col;
    const int nc = nodeL < n ? nodeL : n - 1;
    const float* xrow = x + (size_t)nc * 240;
    const float* frow = nodeF + (size_t)nc * 16;
    const float attv0 = att[col];        // head col>>3   (cols 0-31)
    const float attv1 = att[32 + col];   // head 4+(col>>3) (cols 32-63)

    const f32x16 zc = {0.f, 0.f, 0.f, 0.f, 0.f, 0.f, 0.f, 0.f,
                       0.f, 0.f, 0.f, 0.f, 0.f, 0.f, 0.f, 0.f};
    f32x16 ag0 = zc, ag1 = zc, ac0 = zc, ac1 = zc;

#pragma unroll 1
    for (int p = 0; p < 2; ++p) {
        if (p) __syncthreads();   // drain readers before re-staging
        for (int i = tid; i < 2 * 64 * 64; i += 256) {
            const int mat = i >> 12;
            const int jj  = i & 4095;
            const int kk2 = jj >> 6, c = jj & 63;
            const float* W = mat ? Wc : Wg;
            float a = W[(p * 64 + kk2) * 128 + c];
            float b = W[(p * 64 + kk2) * 128 + 64 + c];
            sW[mat][0][jj] = pk_hi(a, b);
            sW[mat][1][jj] = pk_hi(lo_res(a), lo_res(b));
        }
        __syncthreads();
#pragma unroll 1
        for (int ch = 0; ch < 8; ++ch) {
            const int gch = p * 8 + ch;
            const float* src = (gch < 15) ? (xrow + gch * 16 + hi * 8) : (frow + hi * 8);
            float4 v0 = *(const float4*)src;
            float4 v1 = *(const float4*)(src + 4);
            S8U xh, xl;
            xh.u[0] = pk_hi(v0.x, v0.y);
            xh.u[1] = pk_hi(v0.z, v0.w);
            xh.u[2] = pk_hi(v1.x, v1.y);
            xh.u[3] = pk_hi(v1.z, v1.w);
            xl.u[0] = pk_hi(lo_res(v0.x), lo_res(v0.y));
            xl.u[1] = pk_hi(lo_res(v0.z), lo_res(v0.w));
            xl.u[2] = pk_hi(lo_res(v1.x), lo_res(v1.y));
            xl.u[3] = pk_hi(lo_res(v1.z), lo_res(v1.w));

            const int rbase = (ch * 8 + hi * 4) * 64 + col;
            S8U gh0, gl0, gh1, gl1, ch0, cl0, ch1, cl1;
#pragma unroll
            for (int r = 0; r < 4; ++r) {
                gh0.u[r] = sW[0][0][rbase + r * 64];
                gl0.u[r] = sW[0][1][rbase + r * 64];
                gh1.u[r] = sW[0][0][rbase + r * 64 + 32];
                gl1.u[r] = sW[0][1][rbase + r * 64 + 32];
                ch0.u[r] = sW[1][0][rbase + r * 64];
                cl0.u[r] = sW[1][1][rbase + r * 64];
                ch1.u[r] = sW[1][0][rbase + r * 64 + 32];
                cl1.u[r] = sW[1][1][rbase + r * 64 + 32];
            }
            ag0 = __builtin_amdgcn_mfma_f32_32x32x16_bf16(xh.v, gh0.v, ag0, 0, 0, 0);
            ag1 = __builtin_amdgcn_mfma_f32_32x32x16_bf16(xh.v, gh1.v, ag1, 0, 0, 0);
            ag0 = __builtin_amdgcn_mfma_f32_32x32x16_bf16(xl.v, gh0.v, ag0, 0, 0, 0);
            ag1 = __builtin_amdgcn_mfma_f32_32x32x16_bf16(xl.v, gh1.v, ag1, 0, 0, 0);
            ag0 = __builtin_amdgcn_mfma_f32_32x32x16_bf16(xh.v, gl0.v, ag0, 0, 0, 0);
            ag1 = __builtin_amdgcn_mfma_f32_32x32x16_bf16(xh.v, gl1.v, ag1, 0, 0, 0);
            ac0 = __builtin_amdgcn_mfma_f32_32x32x16_bf16(xh.v, ch0.v, ac0, 0, 0, 0);
            ac1 = __builtin_amdgcn_mfma_f32_32x32x16_bf16(xh.v, ch1.v, ac1, 0, 0, 0);
            ac0 = __builtin_amdgcn_mfma_f32_32x32x16_bf16(xl.v, ch0.v, ac0, 0, 0, 0);
            ac1 = __builtin_amdgcn_mfma_f32_32x32x16_bf16(xl.v, ch1.v, ac1, 0, 0, 0);
            ac0 = __builtin_amdgcn_mfma_f32_32x32x16_bf16(xh.v, cl0.v, ac0, 0, 0, 0);
            ac1 = __builtin_amdgcn_mfma_f32_32x32x16_bf16(xh.v, cl1.v, ac1, 0, 0, 0);
        }
    }

#pragma unroll
    for (int r = 0; r < 16; ++r) {
        const int nr = (r & 3) + 8 * (r >> 2) + 4 * hi;
        const int nd = nodeBase + nr;
        const bool ok = nd < n;
        if (ok) {
            Pg[(size_t)nd * 64 + col]      = ag0[r];
            Pg[(size_t)nd * 64 + 32 + col] = ag1[r];
            Pc[(size_t)nd * 64 + col]      = ac0[r];
            Pc[(size_t)nd * 64 + 32 + col] = ac1[r];
        }
        // alpha epilogue: sum over 8-lane head groups (xor 1,2,4 keeps group+hi)
        float p0 = ag0[r] * attv0;
        float p1 = ag1[r] * attv1;
        p0 += __shfl_xor(p0, 1, 64); p0 += __shfl_xor(p0, 2, 64); p0 += __shfl_xor(p0, 4, 64);
        p1 += __shfl_xor(p1, 1, 64); p1 += __shfl_xor(p1, 2, 64); p1 += __shfl_xor(p1, 4, 64);
        if (ok && (col & 7) == 0) {
            alpha[(size_t)nd * 8 + (col >> 3)]     = p0;
            alpha[(size_t)nd * 8 + 4 + (col >> 3)] = p1;
        }
    }
}

// ---- DUAL MFMA GEMM: Pg = Ag @ Wg, Pc = Ac @ Wc (K=64); alpha1 epilogue ----
__global__ void __launch_bounds__(256, 2) gemm64_dual_kernel(
    const float* __restrict__ Ag, const float* __restrict__ Ac,
    const float* __restrict__ Wg, const float* __restrict__ Wc,
    const float* __restrict__ att,
    float* __restrict__ Pg, float* __restrict__ Pc,
    float* __restrict__ alpha, int n)
{
    __shared__ unsigned sW[2][2][32 * 64];  // 32 KB
    const int tid = threadIdx.x;
    for (int i = tid; i < 2 * 32 * 64; i += 256) {
        const int mat = i >> 11;
        const int jj  = i & 2047;
        const int kk2 = jj >> 6, c = jj & 63;
        const float* W = mat ? Wc : Wg;
        float a = W[kk2 * 128 + c];
        float b = W[kk2 * 128 + 64 + c];
        sW[mat][0][jj] = pk_hi(a, b);
        sW[mat][1][jj] = pk_hi(lo_res(a), lo_res(b));
    }
    __syncthreads();

    const int lane = tid & 63;
    const int col  = lane & 31;
    const int hi   = lane >> 5;
    const int wv   = tid >> 6;
    const int nodeBase = blockIdx.x * 128 + wv * 32;
    const int nodeL = nodeBase + col;
    const int nc = nodeL < n ? nodeL : n - 1;
    const float attv0 = att[col];
    const float attv1 = att[32 + col];

    const f32x16 zc = {0.f, 0.f, 0.f, 0.f, 0.f, 0.f, 0.f, 0.f,
                       0.f, 0.f, 0.f, 0.f, 0.f, 0.f, 0.f, 0.f};
    f32x16 bg0 = zc, bg1 = zc, bc0 = zc, bc1 = zc;

    const float* garow = Ag + (size_t)nc * 64;
    const float* carow = Ac + (size_t)nc * 64;
#pragma unroll
    for (int ch = 0; ch < 4; ++ch) {
        const int rbase = (ch * 8 + hi * 4) * 64 + col;
        S8U wh0, wl0, wh1, wl1;
        {
            const float* src = garow + ch * 16 + hi * 8;
            float4 v0 = *(const float4*)src;
            float4 v1 = *(const float4*)(src + 4);
            S8U xh, xl;
            xh.u[0] = pk_hi(v0.x, v0.y);
            xh.u[1] = pk_hi(v0.z, v0.w);
            xh.u[2] = pk_hi(v1.x, v1.y);
            xh.u[3] = pk_hi(v1.z, v1.w);
            xl.u[0] = pk_hi(lo_res(v0.x), lo_res(v0.y));
            xl.u[1] = pk_hi(lo_res(v0.z), lo_res(v0.w));
            xl.u[2] = pk_hi(lo_res(v1.x), lo_res(v1.y));
            xl.u[3] = pk_hi(lo_res(v1.z), lo_res(v1.w));
#pragma unroll
            for (int r = 0; r < 4; ++r) {
                wh0.u[r] = sW[0][0][rbase + r * 64];
                wl0.u[r] = sW[0][1][rbase + r * 64];
                wh1.u[r] = sW[0][0][rbase + r * 64 + 32];
                wl1.u[r] = sW[0][1][rbase + r * 64 + 32];
            }
            bg0 = __builtin_amdgcn_mfma_f32_32x32x16_bf16(xh.v, wh0.v, bg0, 0, 0, 0);
            bg1 = __builtin_amdgcn_mfma_f32_32x32x16_bf16(xh.v, wh1.v, bg1, 0, 0, 0);
            bg0 = __builtin_amdgcn_mfma_f32_32x32x16_bf16(xl.v, wh0.v, bg0, 0, 0, 0);
            bg1 = __builtin_amdgcn_mfma_f32_32x32x16_bf16(xl.v, wh1.v, bg1, 0, 0, 0);
            bg0 = __builtin_amdgcn_mfma_f32_32x32x16_bf16(xh.v, wl0.v, bg0, 0, 0, 0);
            bg1 = __builtin_amdgcn_mfma_f32_32x32x16_bf16(xh.v, wl1.v, bg1, 0, 0, 0);
        }
        {
            const float* src = carow + ch * 16 + hi * 8;
            float4 v0 = *(const float4*)src;
            float4 v1 = *(const float4*)(src + 4);
            S8U xh, xl;
            xh.u[0] = pk_hi(v0.x, v0.y);
            xh.u[1] = pk_hi(v0.z, v0.w);
            xh.u[2] = pk_hi(v1.x, v1.y);
            xh.u[3] = pk_hi(v1.z, v1.w);
            xl.u[0] = pk_hi(lo_res(v0.x), lo_res(v0.y));
            xl.u[1] = pk_hi(lo_res(v0.z), lo_res(v0.w));
            xl.u[2] = pk_hi(lo_res(v1.x), lo_res(v1.y));
            xl.u[3] = pk_hi(lo_res(v1.z), lo_res(v1.w));
#pragma unroll
            for (int r = 0; r < 4; ++r) {
                wh0.u[r] = sW[1][0][rbase + r * 64];
                wl0.u[r] = sW[1][1][rbase + r * 64];
                wh1.u[r] = sW[1][0][rbase + r * 64 + 32];
                wl1.u[r] = sW[1][1][rbase + r * 64 + 32];
            }
            bc0 = __builtin_amdgcn_mfma_f32_32x32x16_bf16(xh.v, wh0.v, bc0, 0, 0, 0);
            bc1 = __builtin_amdgcn_mfma_f32_32x32x16_bf16(xh.v, wh1.v, bc1, 0, 0, 0);
            bc0 = __builtin_amdgcn_mfma_f32_32x32x16_bf16(xl.v, wh0.v, bc0, 0, 0, 0);
            bc1 = __builtin_amdgcn_mfma_f32_32x32x16_bf16(xl.v, wh1.v, bc1, 0, 0, 0);
            bc0 = __builtin_amdgcn_mfma_f32_32x32x16_bf16(xh.v, wl0.v, bc0, 0, 0, 0);
            bc1 = __builtin_amdgcn_mfma_f32_32x32x16_bf16(xh.v, wl1.v, bc1, 0, 0, 0);
        }
    }

#pragma unroll
    for (int r = 0; r < 16; ++r) {
        const int nr = (r & 3) + 8 * (r >> 2) + 4 * hi;
        const int nd = nodeBase + nr;
        const bool ok = nd < n;
        if (ok) {
            Pg[(size_t)nd * 64 + col]      = bg0[r];
            Pg[(size_t)nd * 64 + 32 + col] = bg1[r];
            Pc[(size_t)nd * 64 + col]      = bc0[r];
            Pc[(size_t)nd * 64 + 32 + col] = bc1[r];
        }
        // alpha1: full 64-col dot vs att; reduce 32 lanes of same hi
        float pa = bg0[r] * attv0 + bg1[r] * attv1;
        pa += __shfl_xor(pa, 1, 64);
        pa += __shfl_xor(pa, 2, 64);
        pa += __shfl_xor(pa, 4, 64);
        pa += __shfl_xor(pa, 8, 64);
        pa += __shfl_xor(pa, 16, 64);
        if (ok && col == 0) alpha[nd] = pa;
    }
}

// ---- fused per-layer graph kernel: online softmax + GAT gather + GCN gather.
// Wave per dst (4 waves/block). Phase 1: online (m,s) over in-edges
// (H=8: lane=e*8+h, butterfly over e; H=1: 64-edge stride, full butterfly).
// Phase 2: one CSR walk accumulating both GAT (coef*xh) and GCN (norm*xw).
template <int H, bool FILTER>
__global__ void __launch_bounds__(256) fused_gather_kernel(
    const int* __restrict__ rs, const int* __restrict__ csrc,
    const float* __restrict__ cesc, const float* __restrict__ alpha,
    const float* __restrict__ xh, const float* __restrict__ xw,
    const float* __restrict__ dinv,
    const float* __restrict__ gbias, const float* __restrict__ cbias,
    float* __restrict__ gout, float* __restrict__ cout, int n)
{
    const int j = threadIdx.x & 63;
    const int d = blockIdx.x * 4 + (threadIdx.x >> 6);
    if (d >= n) return;               // wave-uniform: whole wave exits together
    const int k0 = rs[d], k1 = rs[d + 1];

    float m = -INFINITY, ssum = 0.f;
    if (H == 8) {
        const int e = j >> 3, h = j & 7;
        const int nb = (k1 - k0 + 7) >> 3;
        for (int b = 0; b < nb; ++b) {
            int k = k0 + b * 8 + e;
            if (k < k1) {
                float a = alpha[(size_t)csrc[k] * 8 + h];
                a = a > 0.f ? a : 0.2f * a;
                float mn = fmaxf(m, a);
                ssum = ssum * __expf(m - mn) + __expf(a - mn);
                m = mn;
            }
        }
#pragma unroll
        for (int msk = 8; msk <= 32; msk <<= 1) {
            float mo = __shfl_xor(m, msk, 64);
            float so = __shfl_xor(ssum, msk, 64);
            float mn = fmaxf(m, mo);
            float f1 = (m == -INFINITY) ? 0.f : __expf(m - mn);
            float f2 = (mo == -INFINITY) ? 0.f : __expf(mo - mn);
            ssum = ssum * f1 + so * f2;
            m = mn;
        }
    } else {
        const int nb = (k1 - k0 + 63) >> 6;
        for (int b = 0; b < nb; ++b) {
            int k = k0 + b * 64 + j;
            if (k < k1) {
                float a = alpha[csrc[k]];
                a = a > 0.f ? a : 0.2f * a;
                float mn = fmaxf(m, a);
                ssum = ssum * __expf(m - mn) + __expf(a - mn);
                m = mn;
            }
        }
#pragma unroll
        for (int msk = 1; msk <= 32; msk <<= 1) {
            float mo = __shfl_xor(m, msk, 64);
            float so = __shfl_xor(ssum, msk, 64);
            float mn = fmaxf(m, mo);
            float f1 = (m == -INFINITY) ? 0.f : __expf(m - mn);
            float f2 = (mo == -INFINITY) ? 0.f : __expf(mo - mn);
            ssum = ssum * f1 + so * f2;
            m = mn;
        }
    }
    const int h2 = (H == 8) ? (j >> 3) : 0;
    float mh, ri;
    if (H == 8) {
        mh = __shfl(m, h2, 64);       // lane h2 (e=0 group) holds head h2
        ri = rcpf(__shfl(ssum, h2, 64));
    } else {
        mh = m;
        ri = rcpf(ssum);
    }

    // phase 2: accumulate both branches in one CSR walk
    const float di = dinv[d];
    float ag = xh[(size_t)d * 64 + j] + gbias[j];
    float ac = xw[(size_t)d * 64 + j] * di * di + cbias[j];
#pragma unroll 2
    for (int k = k0; k < k1; ++k) {
        int s = csrc[k];
        float a = alpha[(size_t)s * H + h2];
        a = a > 0.f ? a : 0.2f * a;
        float coef = __expf(a - mh) * ri + cesc[k];
        ag += xh[(size_t)s * 64 + j] * coef;
        ac += xw[(size_t)s * 64 + j] * (dinv[s] * di);
    }
    if (FILTER && !__builtin_isfinite(ag)) ag = 0.f;
    gout[(size_t)d * 64 + j] = ag;
    cout[(size_t)d * 64 + j] = ac > 0.f ? ac : 0.01f * ac;  // leaky_relu(0.01)
}

// ---------------- classifier (fused 320->32->16->4; 43.5KB static LDS) ---------
__global__ void __launch_bounds__(256) cls_kernel(
    const float* __restrict__ x, const float* __restrict__ nodeF,
    const float* __restrict__ xg,
    const float* __restrict__ W1, const float* __restrict__ b1,
    const float* __restrict__ W2, const float* __restrict__ b2,
    const float* __restrict__ W3, const float* __restrict__ b3,
    float* __restrict__ outp, int n)
{
    __shared__ float sW1[320 * 32];
    __shared__ float sW2[32 * 16];
    __shared__ float sW3[16 * 4];
    __shared__ float sb1[32], sb2[16], sb3[4];
    int tid = threadIdx.x;
    for (int i = tid; i < 320 * 32; i += 256) sW1[i] = W1[i];
    for (int i = tid; i < 512; i += 256) sW2[i] = W2[i];
    if (tid < 64) sW3[tid] = W3[tid];
    if (tid < 32) sb1[tid] = b1[tid];
    if (tid < 16) sb2[tid] = b2[tid];
    if (tid < 4)  sb3[tid] = b3[tid];
    __syncthreads();
    int nd = blockIdx.x * 256 + tid;
    if (nd >= n) return;

    float a1[32];
#pragma unroll
    for (int j = 0; j < 32; ++j) a1[j] = sb1[j];
    const float4* xr = (const float4*)(x + (size_t)nd * 240);
#pragma unroll 1
    for (int k4 = 0; k4 < 60; ++k4) {
        float4 v = xr[k4];
        const float* wr = sW1 + k4 * 128;
#pragma unroll
        for (int j = 0; j < 32; ++j)
            a1[j] += v.x * wr[j] + v.y * wr[32 + j] + v.z * wr[64 + j] + v.w * wr[96 + j];
    }
    const float4* nf = (const float4*)(nodeF + (size_t)nd * 16);
#pragma unroll 1
    for (int k4 = 60; k4 < 64; ++k4) {
        float4 v = nf[k4 - 60];
        const float* wr = sW1 + k4 * 128;
#pragma unroll
        for (int j = 0; j < 32; ++j)
            a1[j] += v.x * wr[j] + v.y * wr[32 + j] + v.z * wr[64 + j] + v.w * wr[96 + j];
    }
    const float4* p2 = (const float4*)(xg + (size_t)nd * 64);
#pragma unroll 1
    for (int k4 = 0; k4 < 16; ++k4) {
        float4 v = p2[k4];
        const float* wr = sW1 + 8192 + k4 * 128;  // rows 256 + 4*k4
#pragma unroll
        for (int j = 0; j < 32; ++j)
            a1[j] += v.x * wr[j] + v.y * wr[32 + j] + v.z * wr[64 + j] + v.w * wr[96 + j];
    }
#pragma unroll
    for (int j = 0; j < 32; ++j) { float v = a1[j]; a1[j] = v > 0.f ? v : 0.01f * v; }

    float a2[16];
#pragma unroll
    for (int j = 0; j < 16; ++j) a2[j] = sb2[j];
#pragma unroll
    for (int k = 0; k < 32; ++k) {
        float v = a1[k];
        const float* wr = sW2 + k * 16;
#pragma unroll
        for (int j = 0; j < 16; ++j) a2[j] += v * wr[j];
    }
#pragma unroll
    for (int j = 0; j < 16; ++j) { float v = a2[j]; a2[j] = v > 0.f ? v : 0.01f * v; }

    float a3[4] = {sb3[0], sb3[1], sb3[2], sb3[3]};
#pragma unroll
    for (int k = 0; k < 16; ++k) {
        float v = a2[k];
        const float* wr = sW3 + k * 4;
        a3[0] += v * wr[0]; a3[1] += v * wr[1]; a3[2] += v * wr[2]; a3[3] += v * wr[3];
    }
    float4 o = make_float4(a3[0], a3[1], a3[2], a3[3]);
    *(float4*)(outp + (size_t)nd * 4) = o;
}

// ---------------- launcher ----------------
static inline unsigned nblk(size_t t) { return (unsigned)((t + 255) / 256); }

extern "C" void kernel_launch(void* const* d_in, const int* in_sizes, int n_in,
                              void* d_out, int out_size, void* d_ws, size_t ws_size,
                              hipStream_t stream)
{
    const float* x     = (const float*)d_in[0];
    const float* eseq  = (const float*)d_in[1];
    const float* nseq  = (const float*)d_in[2];
    const float* Wih   = (const float*)d_in[3];
    const float* Whh   = (const float*)d_in[4];
    const float* lb    = (const float*)d_in[5];
    const float* dnnW  = (const float*)d_in[6];
    const float* dnnb  = (const float*)d_in[7];
    const float* g1W   = (const float*)d_in[8];
    const float* g1att = (const float*)d_in[9];
    const float* g1b   = (const float*)d_in[10];
    const float* g2W   = (const float*)d_in[11];
    const float* g2att = (const float*)d_in[12];
    const float* g2b   = (const float*)d_in[13];
    const float* gc1W  = (const float*)d_in[14];
    const float* gc1b  = (const float*)d_in[15];
    const float* gc2W  = (const float*)d_in[16];
    const float* gc2b  = (const float*)d_in[17];
    const float* c1W   = (const float*)d_in[18];
    const float* c1b   = (const float*)d_in[19];
    const float* c2W   = (const float*)d_in[20];
    const float* c2b   = (const float*)d_in[21];
    const float* c3W   = (const float*)d_in[22];
    const float* c3b   = (const float*)d_in[23];
    const int* eidx  = (const int*)d_in[24];
    const int* elen  = (const int*)d_in[25];
    const int* nlen  = (const int*)d_in[26];

    const int N = NN;
    const int E = EE;
    const int* srcp = eidx;
    const int* dstp = eidx + E;

    // device-global scratch
    float *nodeF, *esc, *P1, *P2, *P3, *P4, *alpha, *dinv, *cesc;
    int *cnt, *rs, *cur, *csrc, *permN, *permE;
    hipGetSymbolAddress((void**)&nodeF, HIP_SYMBOL(g_nodeF));
    hipGetSymbolAddress((void**)&esc,   HIP_SYMBOL(g_esc));
    hipGetSymbolAddress((void**)&P1,    HIP_SYMBOL(g_P1));
    hipGetSymbolAddress((void**)&P2,    HIP_SYMBOL(g_P2));
    hipGetSymbolAddress((void**)&P3,    HIP_SYMBOL(g_P3));
    hipGetSymbolAddress((void**)&P4,    HIP_SYMBOL(g_P4));
    hipGetSymbolAddress((void**)&alpha, HIP_SYMBOL(g_alpha));
    hipGetSymbolAddress((void**)&dinv,  HIP_SYMBOL(g_dinv));
    hipGetSymbolAddress((void**)&cnt,   HIP_SYMBOL(g_cnt));
    hipGetSymbolAddress((void**)&rs,    HIP_SYMBOL(g_rs));
    hipGetSymbolAddress((void**)&cur,   HIP_SYMBOL(g_cur));
    hipGetSymbolAddress((void**)&csrc,  HIP_SYMBOL(g_csrc));
    hipGetSymbolAddress((void**)&cesc,  HIP_SYMBOL(g_cesc));
    hipGetSymbolAddress((void**)&permN, HIP_SYMBOL(g_permN));
    hipGetSymbolAddress((void**)&permE, HIP_SYMBOL(g_permE));

    float* out0   = (float*)d_out;             // [N,4]
    float* outGcn = out0 + (size_t)N * 4;      // [N,64]
    float* outGat = outGcn + (size_t)N * 64;   // [N,64]

    // ---- bucketing + CSR degree count (fused) ----
    zero_cnt_kernel<<<nblk(N), 256, 0, stream>>>(cnt, N);
    bucket_hist_kernel<<<nblk(NN + EE), 256, 0, stream>>>(nlen, elen, dstp, cnt);
    bucket_scan_kernel<<<1, 64, 0, stream>>>();
    bucket_scatter_kernel<<<nblk(NN + EE), 256, 0, stream>>>(nlen, elen);

    // ---- temporal branches (node + edge fused; 32 seqs/wave, bf16 MFMA) ----
    const int nNodeBlk = (N + 127) / 128;        // 391
    const int nEdgeBlk = (E + 127) / 128;        // 3125
    lstm_fused_kernel<<<nNodeBlk + nEdgeBlk, 256, 0, stream>>>(
        nseq, nlen, eseq, elen, Wih, Whh, lb, dnnW, dnnb, permN, permE,
        nodeF, esc, nNodeBlk);

    // ---- CSR build (hierarchical scan, stage2 fused into stage3) ----
    const unsigned scanBlk = nblk(N);   // 196
    scan1_kernel<<<scanBlk, 256, 0, stream>>>(cnt, N);
    scan3_kernel<<<scanBlk, 256, 0, stream>>>(cnt, rs, cur, dinv, N, E, (int)scanBlk);
    fill_kernel<<<nblk(E), 256, 0, stream>>>(srcp, dstp, esc, cur, csrc, cesc, E);

    const unsigned gemmBlk = (N + 127) / 128;

    // ---- layer 1: dual GEMM (xh1->P1, xw1->P3) + alpha8; fused gather ----
    gemmX_dual_kernel<<<gemmBlk, 256, 0, stream>>>(
        x, nodeF, g1W, gc1W, g1att, P1, P3, alpha, N);
    fused_gather_kernel<8, false><<<(N + 3) / 4, 256, 0, stream>>>(
        rs, csrc, cesc, alpha, P1, P3, dinv, g1b, gc1b, P2, P4, N);

    // ---- layer 2: dual GEMM (xh2->P1, xw2->P3) + alpha1; fused gather ----
    gemm64_dual_kernel<<<gemmBlk, 256, 0, stream>>>(
        P2, P4, g2W, gc2W, g2att, P1, P3, alpha, N);
    fused_gather_kernel<1, true><<<(N + 3) / 4, 256, 0, stream>>>(
        rs, csrc, cesc, alpha, P1, P3, dinv, g2b, gc2b, outGat, outGcn, N);

    // ---- classifier (reads x_gcn from d_out) ----
    cls_kernel<<<nblk(N), 256, 0, stream>>>(x, nodeF, outGcn, c1W, c1b, c2W, c2b, c3W, c3b, out0, N);
}